// Round 6
// baseline (2015.844 us; speedup 1.0000x reference)
//
#include <hip/hip_runtime.h>
#include <hip/hip_bf16.h>

#define NU 100000
#define NT 300000
#define NM 10000

typedef __hip_bfloat16 bf16;
typedef __attribute__((ext_vector_type(8))) short bf16x8;
typedef __attribute__((ext_vector_type(4))) float f32x4;

__device__ __forceinline__ float toF(float v) { return v; }
__device__ __forceinline__ float toF(bf16 v)  { return __bfloat162float(v); }

// ================= CSR build =================
__global__ void k_zero_i(int* __restrict__ p, int n) {
    int i = blockIdx.x * 256 + threadIdx.x;
    if (i < n) p[i] = 0;
}

__global__ void k_hist(const int* __restrict__ ei, int E, int* __restrict__ cnt) {
    int e = blockIdx.x * 256 + threadIdx.x;
    if (e < E) atomicAdd(&cnt[ei[E + e]], 1);
}

__global__ void k_scan1(const int* __restrict__ cnt, int n, int* __restrict__ bsum) {
    __shared__ int sh[256];
    int i = blockIdx.x * 256 + threadIdx.x;
    sh[threadIdx.x] = (i < n) ? cnt[i] : 0;
    __syncthreads();
    for (int o = 128; o; o >>= 1) {
        if (threadIdx.x < o) sh[threadIdx.x] += sh[threadIdx.x + o];
        __syncthreads();
    }
    if (threadIdx.x == 0) bsum[blockIdx.x] = sh[0];
}

__global__ void k_scan2(int* __restrict__ bsum, int nb) {  // 1 block
    __shared__ int sh[256];
    __shared__ int carry;
    if (threadIdx.x == 0) carry = 0;
    __syncthreads();
    for (int base = 0; base < nb; base += 256) {
        int i = base + threadIdx.x;
        int v = (i < nb) ? bsum[i] : 0;
        sh[threadIdx.x] = v;
        __syncthreads();
        for (int o = 1; o < 256; o <<= 1) {
            int t = (threadIdx.x >= o) ? sh[threadIdx.x - o] : 0;
            __syncthreads();
            sh[threadIdx.x] += t;
            __syncthreads();
        }
        if (i < nb) bsum[i] = carry + sh[threadIdx.x] - v;  // exclusive
        __syncthreads();
        if (threadIdx.x == 255) carry += sh[255];
        __syncthreads();
    }
}

__global__ void k_scan3(const int* __restrict__ cnt, int n, const int* __restrict__ bsum,
                        int* __restrict__ out) {
    __shared__ int sh[256];
    int i = blockIdx.x * 256 + threadIdx.x;
    int v = (i < n) ? cnt[i] : 0;
    sh[threadIdx.x] = v;
    __syncthreads();
    for (int o = 1; o < 256; o <<= 1) {
        int t = (threadIdx.x >= o) ? sh[threadIdx.x - o] : 0;
        __syncthreads();
        sh[threadIdx.x] += t;
        __syncthreads();
    }
    if (i <= n) out[i] = bsum[blockIdx.x] + sh[threadIdx.x] - v;
}

__global__ void k_fill(const int* __restrict__ ei, int E, const int* __restrict__ rowptr,
                       int* __restrict__ cnt, int* __restrict__ col) {
    int e = blockIdx.x * 256 + threadIdx.x;
    if (e >= E) return;
    int d = ei[E + e];
    int pos = rowptr[d] + atomicAdd(&cnt[d], 1);
    col[pos] = ei[e];
}

// ================= weight prep =================
// wa[lr*512 + k*8 + j]; j 0..3 src head j, 4..7 dst head j-4
__global__ void k_wa(const float* __restrict__ lin_w, const float* __restrict__ att_s,
                     const float* __restrict__ att_d, float* __restrict__ wa) {
    int i = blockIdx.x * 256 + threadIdx.x;
    if (i >= 2 * 7 * 64 * 8) return;
    int j = i & 7;
    int k = (i >> 3) & 63;
    int lr = i >> 9;
    int h = j & 3;
    const float* a = (j < 4 ? att_s : att_d) + lr * 64 + h * 16;
    const float* Wp = lin_w + (size_t)lr * 4096 + k * 64 + h * 16;
    float s = 0.f;
#pragma unroll
    for (int c = 0; c < 16; c++) s += Wp[c] * a[c];
    wa[i] = s;
}

// wt: per (l,r): [2][64][64] bf16, transposed (Wt[c][k]), hi + lo split
__global__ void k_wt(const float* __restrict__ lin_w, bf16* __restrict__ wt) {
    int i = blockIdx.x * 256 + threadIdx.x;
    if (i >= 14 * 4096) return;
    int lr = i >> 12;
    int kc = i & 4095;
    int k = kc >> 6, c = kc & 63;
    float v = lin_w[(size_t)lr * 4096 + k * 64 + c];
    bf16 hi = __float2bfloat16(v);
    float rem = v - __bfloat162float(hi);
    wt[(size_t)lr * 8192 + c * 64 + k] = hi;
    wt[(size_t)lr * 8192 + 4096 + c * 64 + k] = __float2bfloat16(rem);
}

// ================= input projection (fp32 VALU, runs once) =================
__global__ void k_proj(const float* __restrict__ x, const float* __restrict__ W,
                       const float* __restrict__ bias, bf16* __restrict__ out,
                       int N, int K) {
    __shared__ float Ws[64 * 64];
    __shared__ float xs[32 * 64];
    int tid = threadIdx.x;
    int r0 = blockIdx.x << 5;
    for (int i = tid; i < K * 64; i += 256) Ws[i] = W[i];
    for (int i = tid; i < 32 * K; i += 256) {
        int row = i / K, col = i - row * K;
        int n = r0 + row;
        xs[(row << 6) + col] = (n < N) ? x[(size_t)n * K + col] : 0.f;
    }
    __syncthreads();
    int c = tid & 63;
    float bv = bias[c];
    for (int rr = tid >> 6; rr < 32; rr += 4) {
        int n = r0 + rr;
        if (n >= N) return;
        float acc = bv;
#pragma unroll 16
        for (int k = 0; k < K; k++) acc = fmaf(xs[(rr << 6) + k], Ws[(k << 6) + c], acc);
        out[(size_t)n * 64 + c] = __float2bfloat16(acc);
    }
}

// ================= MFMA projection + fused alphas =================
__global__ void k_pmfma(const bf16* __restrict__ x, const bf16* __restrict__ wt,
                        const float* __restrict__ avs_p, const float* __restrict__ avd_p,
                        bf16* __restrict__ hs, float* __restrict__ aS, float* __restrict__ aD,
                        int N) {
    int w = threadIdx.x >> 6, lane = threadIdx.x & 63;
    int m = lane & 15, kq = lane >> 4;
    int r0 = blockIdx.x * 64 + w * 16;
    bf16x8 a0 = {}, a1 = {};
    int row = r0 + m;
    if (row < N) {
        a0 = *(const bf16x8*)(x + (size_t)row * 64 + kq * 8);
        a1 = *(const bf16x8*)(x + (size_t)row * 64 + 32 + kq * 8);
    }
#pragma unroll
    for (int nt = 0; nt < 4; nt++) {
        const bf16* wb  = wt + (nt * 16 + m) * 64 + kq * 8;
        const bf16* wbl = wb + 4096;
        bf16x8 bh0 = *(const bf16x8*)(wb);
        bf16x8 bh1 = *(const bf16x8*)(wb + 32);
        bf16x8 bl0 = *(const bf16x8*)(wbl);
        bf16x8 bl1 = *(const bf16x8*)(wbl + 32);
        f32x4 acc = {};
        acc = __builtin_amdgcn_mfma_f32_16x16x32_bf16(a0, bh0, acc, 0, 0, 0);
        acc = __builtin_amdgcn_mfma_f32_16x16x32_bf16(a0, bl0, acc, 0, 0, 0);
        acc = __builtin_amdgcn_mfma_f32_16x16x32_bf16(a1, bh1, acc, 0, 0, 0);
        acc = __builtin_amdgcn_mfma_f32_16x16x32_bf16(a1, bl1, acc, 0, 0, 0);
        float avsv = avs_p ? avs_p[nt * 16 + m] : 0.f;
        float avdv = avd_p ? avd_p[nt * 16 + m] : 0.f;
#pragma unroll
        for (int i = 0; i < 4; i++) {
            int rr = r0 + kq * 4 + i;
            if (rr < N) hs[(size_t)rr * 64 + nt * 16 + m] = __float2bfloat16(acc[i]);
            if (avs_p) {
                float ps = acc[i] * avsv;
                ps += __shfl_xor(ps, 1); ps += __shfl_xor(ps, 2);
                ps += __shfl_xor(ps, 4); ps += __shfl_xor(ps, 8);
                if (m == 0 && rr < N) aS[rr * 4 + nt] = ps;
            }
            if (avd_p) {
                float pd = acc[i] * avdv;
                pd += __shfl_xor(pd, 1); pd += __shfl_xor(pd, 2);
                pd += __shfl_xor(pd, 4); pd += __shfl_xor(pd, 8);
                if (m == 0 && rr < N) aD[rr * 4 + nt] = pd;
            }
        }
    }
}

// ================= alpha_dst GEMV (cross-type relations only) =================
__global__ void k_alpha(const bf16* __restrict__ x, const float* __restrict__ wa,
                        float* __restrict__ aD, int N) {
    __shared__ float xs[32 * 64];
    __shared__ float was[512];
    int tid = threadIdx.x;
    int r0 = blockIdx.x << 5;
    was[tid] = wa[tid];
    was[tid + 256] = wa[tid + 256];
    for (int i = tid; i < 2048; i += 256) {
        int row = i >> 6, col = i & 63;
        int n = r0 + row;
        xs[i] = (n < N) ? toF(x[(size_t)n * 64 + col]) : 0.f;
    }
    __syncthreads();
    int row = tid >> 3, j = tid & 7;
    int n = r0 + row;
    if (n >= N || j < 4) return;
    float acc = 0.f;
#pragma unroll
    for (int k = 0; k < 64; k++) acc = fmaf(xs[(row << 6) + k], was[(k << 3) + j], acc);
    aD[n * 4 + (j - 4)] = acc;
}

// ================= softmax weights: one thread per (node, head) =================
__global__ void k_smw(const int* __restrict__ rp, const int* __restrict__ col,
                      const float* __restrict__ aS, const float* __restrict__ aD,
                      float* __restrict__ alw, int Nd) {
    int t = blockIdx.x * 256 + threadIdx.x;
    if (t >= Nd * 4) return;
    int node = t >> 2, h = t & 3;
    int b = rp[node], e = rp[node + 1];
    if (b == e) return;
    float ad = aD[node * 4 + h];
    float mx = -INFINITY;
    for (int i = b; i < e; i++) {
        float a = aS[col[i] * 4 + h] + ad;
        a = (a >= 0.f) ? a : 0.2f * a;
        mx = fmaxf(mx, a);
    }
    float dn = 0.f;
    for (int i = b; i < e; i++) {
        float a = aS[col[i] * 4 + h] + ad;
        a = (a >= 0.f) ? a : 0.2f * a;
        float ex = __expf(a - mx);
        dn += ex;
        alw[(size_t)i * 4 + h] = ex;
    }
    float r = 1.f / (dn + 1e-16f);
    for (int i = b; i < e; i++) alw[(size_t)i * 4 + h] *= r;
}

// ================= aggregation: wave per node, no shuffles =================
__device__ __forceinline__ float agg_rel(const int* __restrict__ col, const float* __restrict__ w,
                                         const bf16* __restrict__ hs, int b, int e,
                                         int lane, int hcl, float acc) {
    for (int i = b; i < e; i += 4) {
        int n4 = e - i;  // wave-uniform
        int sj0 = col[i];
        float wj0 = w[(size_t)i * 4 + hcl];
        int sj1 = 0, sj2 = 0, sj3 = 0;
        float wj1 = 0.f, wj2 = 0.f, wj3 = 0.f;
        if (n4 > 1) { sj1 = col[i + 1]; wj1 = w[(size_t)(i + 1) * 4 + hcl]; }
        if (n4 > 2) { sj2 = col[i + 2]; wj2 = w[(size_t)(i + 2) * 4 + hcl]; }
        if (n4 > 3) { sj3 = col[i + 3]; wj3 = w[(size_t)(i + 3) * 4 + hcl]; }
        float h0 = toF(hs[(size_t)sj0 * 64 + lane]);
        float h1 = toF(hs[(size_t)sj1 * 64 + lane]);
        float h2 = toF(hs[(size_t)sj2 * 64 + lane]);
        float h3 = toF(hs[(size_t)sj3 * 64 + lane]);
        acc = fmaf(h0, wj0, acc);
        acc = fmaf(h1, wj1, acc);
        acc = fmaf(h2, wj2, acc);
        acc = fmaf(h3, wj3, acc);
    }
    return acc;
}

__global__ void k_agg(const int* rp0, const int* c0, const float* w0, const bf16* h0,
                      const int* rp1, const int* c1, const float* w1, const bf16* h1,
                      const int* rp2, const int* c2, const float* w2, const bf16* h2,
                      const float* __restrict__ cb, int b0, int b1, int b2,
                      bf16* __restrict__ out, int Nd) {
    int node = blockIdx.x * 4 + (threadIdx.x >> 6);
    if (node >= Nd) return;
    int lane = threadIdx.x & 63;
    int hcl = lane >> 4;
    float acc = cb[b0 * 64 + lane];
    if (b1 >= 0) acc += cb[b1 * 64 + lane];
    if (b2 >= 0) acc += cb[b2 * 64 + lane];
    int s0 = rp0[node], e0 = rp0[node + 1];
    int s1 = 0, e1 = 0, s2 = 0, e2 = 0;
    if (rp1) { s1 = rp1[node]; e1 = rp1[node + 1]; }
    if (rp2) { s2 = rp2[node]; e2 = rp2[node + 1]; }
    acc = agg_rel(c0, w0, h0, s0, e0, lane, hcl, acc);
    if (rp1) acc = agg_rel(c1, w1, h1, s1, e1, lane, hcl, acc);
    if (rp2) acc = agg_rel(c2, w2, h2, s2, e2, lane, hcl, acc);
    out[(size_t)node * 64 + lane] = __float2bfloat16(acc > 0.f ? acc : 0.f);
}

// ================= classifier =================
__global__ void k_cls(const bf16* __restrict__ t, const float* __restrict__ w1,
                      const float* __restrict__ b1, const float* __restrict__ w2,
                      const float* __restrict__ b2, float* __restrict__ out) {
    __shared__ float w1s[64 * 32];
    __shared__ float w2s[64];
    __shared__ float b1s[32];
    __shared__ float b2s[2];
    __shared__ float ts[8 * 64];
    int tid = threadIdx.x;
    for (int i = tid; i < 2048; i += 256) w1s[i] = w1[i];
    if (tid < 64) w2s[tid] = w2[tid];
    if (tid < 32) b1s[tid] = b1[tid];
    if (tid < 2) b2s[tid] = b2[tid];
    int n0 = blockIdx.x << 3;
    for (int i = tid; i < 512; i += 256) {
        int row = i >> 6, col = i & 63;
        ts[i] = toF(t[(size_t)(n0 + row) * 64 + col]);
    }
    __syncthreads();
    int lane = tid & 31;
    int row = tid >> 5;
    float h = b1s[lane];
#pragma unroll 8
    for (int k = 0; k < 64; k++) h = fmaf(ts[(row << 6) + k], w1s[(k << 5) + lane], h);
    h = h > 0.f ? h : 0.f;
    float o0 = h * w2s[lane * 2 + 0];
    float o1 = h * w2s[lane * 2 + 1];
#pragma unroll
    for (int off = 16; off; off >>= 1) {
        o0 += __shfl_down(o0, off, 32);
        o1 += __shfl_down(o1, off, 32);
    }
    if (lane == 0) {
        int n = n0 + row;
        out[(size_t)n * 2 + 0] = o0 + b2s[0];
        out[(size_t)n * 2 + 1] = o1 + b2s[1];
    }
}

extern "C" void kernel_launch(void* const* d_in, const int* in_sizes, int n_in,
                              void* d_out, int out_size, void* d_ws, size_t ws_size,
                              hipStream_t stream) {
    (void)n_in; (void)out_size;
    const float* x_user  = (const float*)d_in[0];
    const float* x_tx    = (const float*)d_in[1];
    const float* x_merch = (const float*)d_in[2];
    const int* ei[7];
    int E[7];
    for (int r = 0; r < 7; r++) { ei[r] = (const int*)d_in[3 + r]; E[r] = in_sizes[3 + r] / 2; }
    const float* Win_user  = (const float*)d_in[10];
    const float* bin_user  = (const float*)d_in[11];
    const float* Win_tx    = (const float*)d_in[12];
    const float* bin_tx    = (const float*)d_in[13];
    const float* Win_merch = (const float*)d_in[14];
    const float* bin_merch = (const float*)d_in[15];
    const float* lin_w     = (const float*)d_in[16];
    const float* att_src   = (const float*)d_in[17];
    const float* att_dst   = (const float*)d_in[18];
    const float* conv_bias = (const float*)d_in[19];
    const float* cls_w1    = (const float*)d_in[20];
    const float* cls_b1    = (const float*)d_in[21];
    const float* cls_w2    = (const float*)d_in[22];
    const float* cls_b2    = (const float*)d_in[23];

    const int src_type[7] = {0, 1, 2, 1, 0, 2, 1};
    const int dst_type[7] = {1, 0, 1, 2, 0, 2, 1};
    const int N_of[3] = {NU, NT, NM};

    // ---- workspace layout ----
    size_t off = 0;
    auto alloc = [&](size_t bytes) { size_t q = off; off += (bytes + 255) & ~(size_t)255; return q; };
    size_t o_a[3], o_b[3], o_hs[3], o_aS[3];
    for (int tpe = 0; tpe < 3; tpe++) o_a[tpe]  = alloc((size_t)N_of[tpe] * 64 * 2);
    for (int tpe = 0; tpe < 3; tpe++) o_b[tpe]  = alloc((size_t)N_of[tpe] * 64 * 2);
    for (int tpe = 0; tpe < 3; tpe++) o_hs[tpe] = alloc((size_t)N_of[tpe] * 64 * 2);
    for (int tpe = 0; tpe < 3; tpe++) o_aS[tpe] = alloc((size_t)N_of[tpe] * 4 * 4);
    size_t o_aD[3];
    for (int jj = 0; jj < 3; jj++) o_aD[jj] = alloc((size_t)NT * 4 * 4);
    size_t o_rp[7], o_col[7], o_alw[7];
    for (int r = 0; r < 7; r++) o_rp[r]  = alloc(((size_t)N_of[dst_type[r]] + 1) * 4);
    for (int r = 0; r < 7; r++) o_col[r] = alloc((size_t)E[r] * 4);
    for (int r = 0; r < 7; r++) o_alw[r] = alloc((size_t)E[r] * 4 * 4);
    size_t o_cnt  = alloc((size_t)NT * 4);
    size_t o_bsum = alloc((size_t)4096 * 4);
    size_t o_wa   = alloc((size_t)2 * 7 * 64 * 8 * 4);
    size_t o_wt   = alloc((size_t)14 * 8192 * 2);
    if (off > ws_size) return;  // fail cleanly (absmax will read ~0.31)

    char* base = (char*)d_ws;
    bf16* A[3], *B[3], *hsS[3];
    float* aSS[3];
    for (int tpe = 0; tpe < 3; tpe++) {
        A[tpe] = (bf16*)(base + o_a[tpe]);
        B[tpe] = (bf16*)(base + o_b[tpe]);
        hsS[tpe] = (bf16*)(base + o_hs[tpe]);
        aSS[tpe] = (float*)(base + o_aS[tpe]);
    }
    float* aDS[3];
    for (int jj = 0; jj < 3; jj++) aDS[jj] = (float*)(base + o_aD[jj]);
    int* rp[7]; int* col[7]; float* alw[7];
    for (int r = 0; r < 7; r++) {
        rp[r]  = (int*)(base + o_rp[r]);
        col[r] = (int*)(base + o_col[r]);
        alw[r] = (float*)(base + o_alw[r]);
    }
    int* cnt  = (int*)(base + o_cnt);
    int* bsum = (int*)(base + o_bsum);
    float* wa = (float*)(base + o_wa);
    bf16* wt  = (bf16*)(base + o_wt);

    // ---- build CSR per relation ----
    for (int r = 0; r < 7; r++) {
        int Nd = N_of[dst_type[r]];
        int nb = (Nd + 1 + 255) / 256;
        k_zero_i<<<(Nd + 255) / 256, 256, 0, stream>>>(cnt, Nd);
        k_hist<<<(E[r] + 255) / 256, 256, 0, stream>>>(ei[r], E[r], cnt);
        k_scan1<<<nb, 256, 0, stream>>>(cnt, Nd, bsum);
        k_scan2<<<1, 256, 0, stream>>>(bsum, nb);
        k_scan3<<<nb, 256, 0, stream>>>(cnt, Nd, bsum, rp[r]);
        k_zero_i<<<(Nd + 255) / 256, 256, 0, stream>>>(cnt, Nd);
        k_fill<<<(E[r] + 255) / 256, 256, 0, stream>>>(ei[r], E[r], rp[r], cnt, col[r]);
    }

    k_wa<<<(7168 + 255) / 256, 256, 0, stream>>>(lin_w, att_src, att_dst, wa);
    k_wt<<<(14 * 4096 + 255) / 256, 256, 0, stream>>>(lin_w, wt);
    k_proj<<<(NU + 31) / 32, 256, 0, stream>>>(x_user, Win_user, bin_user, A[0], NU, 32);
    k_proj<<<(NT + 31) / 32, 256, 0, stream>>>(x_tx, Win_tx, bin_tx, A[1], NT, 64);
    k_proj<<<(NM + 31) / 32, 256, 0, stream>>>(x_merch, Win_merch, bin_merch, A[2], NM, 16);

    const int grp_dst[3]     = {1, 0, 2};
    const int grp_rels[3][3] = {{0, 2, 6}, {1, 4, -1}, {3, 5, -1}};

    for (int l = 0; l < 2; l++) {
        bf16** cur = (l == 0) ? A : B;
        bf16** nxt = (l == 0) ? B : A;
        const float* cb = conv_bias + (size_t)l * 7 * 64;
        for (int g = 0; g < 3; g++) {
            int dt = grp_dst[g];
            int Nd = N_of[dt];
            const int* grp = grp_rels[g];
            for (int jj = 0; jj < 3; jj++) {
                int r = grp[jj];
                if (r < 0) break;
                int st = src_type[r];
                int lr = l * 7 + r;
                const bf16* wtp  = wt + (size_t)lr * 8192;
                const float* avs = att_src + (size_t)lr * 64;
                const float* avd = att_dst + (size_t)lr * 64;
                const float* war = wa + (size_t)lr * 512;
                if (st == dt) {
                    k_pmfma<<<(N_of[st] + 63) / 64, 256, 0, stream>>>(
                        cur[st], wtp, avs, avd, hsS[st], aSS[st], aDS[jj], N_of[st]);
                } else {
                    k_pmfma<<<(N_of[st] + 63) / 64, 256, 0, stream>>>(
                        cur[st], wtp, avs, nullptr, hsS[st], aSS[st], nullptr, N_of[st]);
                    k_alpha<<<(Nd + 31) / 32, 256, 0, stream>>>(cur[dt], war, aDS[jj], Nd);
                }
                k_smw<<<(Nd * 4 + 255) / 256, 256, 0, stream>>>(
                    rp[r], col[r], aSS[st], aDS[jj], alw[r], Nd);
            }
            int r0 = grp[0], r1 = grp[1], r2 = grp[2];
            k_agg<<<(Nd + 3) / 4, 256, 0, stream>>>(
                rp[r0], col[r0], alw[r0], hsS[src_type[r0]],
                r1 >= 0 ? rp[r1] : nullptr, r1 >= 0 ? col[r1] : nullptr,
                r1 >= 0 ? alw[r1] : nullptr, r1 >= 0 ? hsS[src_type[r1]] : nullptr,
                r2 >= 0 ? rp[r2] : nullptr, r2 >= 0 ? col[r2] : nullptr,
                r2 >= 0 ? alw[r2] : nullptr, r2 >= 0 ? hsS[src_type[r2]] : nullptr,
                cb, r0, r1, r2, nxt[dt], Nd);
        }
    }
    k_cls<<<NT / 8, 256, 0, stream>>>(A[1], cls_w1, cls_b1, cls_w2, cls_b2, (float*)d_out);
}

// Round 7
// 1979.019 us; speedup vs baseline: 1.0186x; 1.0186x over previous
//
#include <hip/hip_runtime.h>
#include <hip/hip_bf16.h>

#define NU 100000
#define NT 300000
#define NM 10000

typedef __hip_bfloat16 bf16;
typedef __attribute__((ext_vector_type(8))) short bf16x8;
typedef __attribute__((ext_vector_type(4))) float f32x4;

__device__ __forceinline__ float toF(float v) { return v; }
__device__ __forceinline__ float toF(bf16 v)  { return __bfloat162float(v); }

struct Segs {
    const int* ei[7];
    int eoff[8];
    int noff[8];
};

// ================= fused CSR build =================
__global__ void k_zero_i(int* __restrict__ p, int n) {
    int i = blockIdx.x * 256 + threadIdx.x;
    if (i < n) p[i] = 0;
}

__global__ void k_hist_all(Segs s, int TE, int* __restrict__ cnt) {
    int g = blockIdx.x * 256 + threadIdx.x;
    if (g >= TE) return;
    int r = 0;
    while (g >= s.eoff[r + 1]) r++;
    int e = g - s.eoff[r];
    int E = s.eoff[r + 1] - s.eoff[r];
    int d = s.ei[r][E + e];
    atomicAdd(&cnt[s.noff[r] + d], 1);
}

__global__ void k_scan1(const int* __restrict__ cnt, int n, int* __restrict__ bsum) {
    __shared__ int sh[256];
    int i = blockIdx.x * 256 + threadIdx.x;
    sh[threadIdx.x] = (i < n) ? cnt[i] : 0;
    __syncthreads();
    for (int o = 128; o; o >>= 1) {
        if (threadIdx.x < o) sh[threadIdx.x] += sh[threadIdx.x + o];
        __syncthreads();
    }
    if (threadIdx.x == 0) bsum[blockIdx.x] = sh[0];
}

__global__ void k_scan2(int* __restrict__ bsum, int nb) {  // 1 block
    __shared__ int sh[256];
    __shared__ int carry;
    if (threadIdx.x == 0) carry = 0;
    __syncthreads();
    for (int base = 0; base < nb; base += 256) {
        int i = base + threadIdx.x;
        int v = (i < nb) ? bsum[i] : 0;
        sh[threadIdx.x] = v;
        __syncthreads();
        for (int o = 1; o < 256; o <<= 1) {
            int t = (threadIdx.x >= o) ? sh[threadIdx.x - o] : 0;
            __syncthreads();
            sh[threadIdx.x] += t;
            __syncthreads();
        }
        if (i < nb) bsum[i] = carry + sh[threadIdx.x] - v;  // exclusive
        __syncthreads();
        if (threadIdx.x == 255) carry += sh[255];
        __syncthreads();
    }
}

__global__ void k_scan3(const int* __restrict__ cnt, int n, const int* __restrict__ bsum,
                        int* __restrict__ out) {
    __shared__ int sh[256];
    int i = blockIdx.x * 256 + threadIdx.x;
    int v = (i < n) ? cnt[i] : 0;
    sh[threadIdx.x] = v;
    __syncthreads();
    for (int o = 1; o < 256; o <<= 1) {
        int t = (threadIdx.x >= o) ? sh[threadIdx.x - o] : 0;
        __syncthreads();
        sh[threadIdx.x] += t;
        __syncthreads();
    }
    if (i <= n) out[i] = bsum[blockIdx.x] + sh[threadIdx.x] - v;
}

__global__ void k_fill_all(Segs s, int TE, const int* __restrict__ rp_all,
                           int* __restrict__ cnt, int* __restrict__ col) {
    int g = blockIdx.x * 256 + threadIdx.x;
    if (g >= TE) return;
    int r = 0;
    while (g >= s.eoff[r + 1]) r++;
    int e = g - s.eoff[r];
    int E = s.eoff[r + 1] - s.eoff[r];
    int d = s.ei[r][E + e];
    int idx = s.noff[r] + d;
    int pos = rp_all[idx] + atomicAdd(&cnt[idx], 1);
    col[pos] = s.ei[r][e];
}

// ================= weight prep =================
// wa[lr*512 + k*8 + j]; j 0..3 src head j, 4..7 dst head j-4
__global__ void k_wa(const float* __restrict__ lin_w, const float* __restrict__ att_s,
                     const float* __restrict__ att_d, float* __restrict__ wa) {
    int i = blockIdx.x * 256 + threadIdx.x;
    if (i >= 2 * 7 * 64 * 8) return;
    int j = i & 7;
    int k = (i >> 3) & 63;
    int lr = i >> 9;
    int h = j & 3;
    const float* a = (j < 4 ? att_s : att_d) + lr * 64 + h * 16;
    const float* Wp = lin_w + (size_t)lr * 4096 + k * 64 + h * 16;
    float s = 0.f;
#pragma unroll
    for (int c = 0; c < 16; c++) s += Wp[c] * a[c];
    wa[i] = s;
}

// wt: per (l,r): [2][64][64] bf16, transposed (Wt[c][k]), hi + lo split
__global__ void k_wt(const float* __restrict__ lin_w, bf16* __restrict__ wt) {
    int i = blockIdx.x * 256 + threadIdx.x;
    if (i >= 14 * 4096) return;
    int lr = i >> 12;
    int kc = i & 4095;
    int k = kc >> 6, c = kc & 63;
    float v = lin_w[(size_t)lr * 4096 + k * 64 + c];
    bf16 hi = __float2bfloat16(v);
    float rem = v - __bfloat162float(hi);
    wt[(size_t)lr * 8192 + c * 64 + k] = hi;
    wt[(size_t)lr * 8192 + 4096 + c * 64 + k] = __float2bfloat16(rem);
}

// ================= input projection (fp32 VALU, runs once) =================
__global__ void k_proj(const float* __restrict__ x, const float* __restrict__ W,
                       const float* __restrict__ bias, bf16* __restrict__ out,
                       int N, int K) {
    __shared__ float Ws[64 * 64];
    __shared__ float xs[32 * 64];
    int tid = threadIdx.x;
    int r0 = blockIdx.x << 5;
    for (int i = tid; i < K * 64; i += 256) Ws[i] = W[i];
    for (int i = tid; i < 32 * K; i += 256) {
        int row = i / K, col = i - row * K;
        int n = r0 + row;
        xs[(row << 6) + col] = (n < N) ? x[(size_t)n * K + col] : 0.f;
    }
    __syncthreads();
    int c = tid & 63;
    float bv = bias[c];
    for (int rr = tid >> 6; rr < 32; rr += 4) {
        int n = r0 + rr;
        if (n >= N) return;
        float acc = bv;
#pragma unroll 16
        for (int k = 0; k < K; k++) acc = fmaf(xs[(rr << 6) + k], Ws[(k << 6) + c], acc);
        out[(size_t)n * 64 + c] = __float2bfloat16(acc);
    }
}

// ================= MFMA projection + fused alphas =================
__global__ void k_pmfma(const bf16* __restrict__ x, const bf16* __restrict__ wt,
                        const float* __restrict__ avs_p, const float* __restrict__ avd_p,
                        bf16* __restrict__ hs, float* __restrict__ aS, float* __restrict__ aD,
                        int N) {
    int w = threadIdx.x >> 6, lane = threadIdx.x & 63;
    int m = lane & 15, kq = lane >> 4;
    int r0 = blockIdx.x * 64 + w * 16;
    bf16x8 a0 = {}, a1 = {};
    int row = r0 + m;
    if (row < N) {
        a0 = *(const bf16x8*)(x + (size_t)row * 64 + kq * 8);
        a1 = *(const bf16x8*)(x + (size_t)row * 64 + 32 + kq * 8);
    }
#pragma unroll
    for (int nt = 0; nt < 4; nt++) {
        const bf16* wb  = wt + (nt * 16 + m) * 64 + kq * 8;
        const bf16* wbl = wb + 4096;
        bf16x8 bh0 = *(const bf16x8*)(wb);
        bf16x8 bh1 = *(const bf16x8*)(wb + 32);
        bf16x8 bl0 = *(const bf16x8*)(wbl);
        bf16x8 bl1 = *(const bf16x8*)(wbl + 32);
        f32x4 acc = {};
        acc = __builtin_amdgcn_mfma_f32_16x16x32_bf16(a0, bh0, acc, 0, 0, 0);
        acc = __builtin_amdgcn_mfma_f32_16x16x32_bf16(a0, bl0, acc, 0, 0, 0);
        acc = __builtin_amdgcn_mfma_f32_16x16x32_bf16(a1, bh1, acc, 0, 0, 0);
        acc = __builtin_amdgcn_mfma_f32_16x16x32_bf16(a1, bl1, acc, 0, 0, 0);
        float avsv = avs_p ? avs_p[nt * 16 + m] : 0.f;
        float avdv = avd_p ? avd_p[nt * 16 + m] : 0.f;
#pragma unroll
        for (int i = 0; i < 4; i++) {
            int rr = r0 + kq * 4 + i;
            if (rr < N) hs[(size_t)rr * 64 + nt * 16 + m] = __float2bfloat16(acc[i]);
            if (avs_p) {
                float ps = acc[i] * avsv;
                ps += __shfl_xor(ps, 1); ps += __shfl_xor(ps, 2);
                ps += __shfl_xor(ps, 4); ps += __shfl_xor(ps, 8);
                if (m == 0 && rr < N) aS[rr * 4 + nt] = ps;
            }
            if (avd_p) {
                float pd = acc[i] * avdv;
                pd += __shfl_xor(pd, 1); pd += __shfl_xor(pd, 2);
                pd += __shfl_xor(pd, 4); pd += __shfl_xor(pd, 8);
                if (m == 0 && rr < N) aD[rr * 4 + nt] = pd;
            }
        }
    }
}

// ================= batched dst-alpha GEMV (up to 2 cross relations) =================
__global__ void k_alpha2(const bf16* __restrict__ x, const float* __restrict__ waA,
                         const float* __restrict__ waB, float* __restrict__ aDA,
                         float* __restrict__ aDB, int N) {
    __shared__ float xs[32 * 64];
    __shared__ float wsA[256], wsB[256];
    int tid = threadIdx.x;
    {
        int k = tid >> 2, h = tid & 3;
        wsA[tid] = waA[(k << 3) + 4 + h];
        wsB[tid] = waB ? waB[(k << 3) + 4 + h] : 0.f;
    }
    int r0 = blockIdx.x << 5;
    for (int i = tid; i < 2048; i += 256) {
        int row = i >> 6, c = i & 63;
        int n = r0 + row;
        xs[i] = (n < N) ? toF(x[(size_t)n * 64 + c]) : 0.f;
    }
    __syncthreads();
    int row = tid >> 3, j = tid & 7;
    int n = r0 + row;
    if (n >= N) return;
    int h = j & 3;
    bool sB = j >= 4;
    if (sB && !waB) return;
    const float* ws = sB ? wsB : wsA;
    float acc = 0.f;
#pragma unroll
    for (int k = 0; k < 64; k++) acc = fmaf(xs[(row << 6) + k], ws[(k << 2) + h], acc);
    (sB ? aDB : aDA)[n * 4 + h] = acc;
}

// ================= softmax (no max-sub, post-normalized): thread per (node,head,rel) ===
// writes ex to alw; overwrites aD[node*4+h] with 1/(sum+eps)
__global__ void k_smw3(const int* rpA, const float* aSA, float* aDA,
                       const int* rpB, const float* aSB, float* aDB,
                       const int* rpC, const float* aSC, float* aDC,
                       const int* __restrict__ col, float* __restrict__ alw,
                       int Nd, int nrel) {
    int t = blockIdx.x * 256 + threadIdx.x;
    int per = Nd * 4;
    if (t >= per * nrel) return;
    int r = t / per;
    int v = t - r * per;
    const int* rp = (r == 0) ? rpA : (r == 1) ? rpB : rpC;
    const float* aS = (r == 0) ? aSA : (r == 1) ? aSB : aSC;
    float* aD = (r == 0) ? aDA : (r == 1) ? aDB : aDC;
    int node = v >> 2, h = v & 3;
    int b = rp[node], e = rp[node + 1];
    float ad = aD[node * 4 + h];
    float dn = 0.f;
    for (int i = b; i < e; i++) {
        float a = aS[col[i] * 4 + h] + ad;
        a = (a >= 0.f) ? a : 0.2f * a;
        float ex = __expf(a);
        alw[(size_t)i * 4 + h] = ex;
        dn += ex;
    }
    aD[node * 4 + h] = 1.f / (dn + 1e-16f);
}

// ================= aggregation: wave per 4 nodes (4-way MLP), lane = channel =========
__device__ __forceinline__ void agg4(const int* __restrict__ rp, const float* __restrict__ rdn,
                                     const bf16* __restrict__ hs, const int* __restrict__ col,
                                     const float* __restrict__ alw,
                                     int n0, int Nd, int lane, int hcl,
                                     float& a0, float& a1, float& a2, float& a3) {
    int b0 = rp[n0], e0 = rp[n0 + 1];
    int b1 = 0, e1 = 0, b2 = 0, e2 = 0, b3 = 0, e3 = 0;
    if (n0 + 1 < Nd) { b1 = rp[n0 + 1]; e1 = rp[n0 + 2]; }
    if (n0 + 2 < Nd) { b2 = rp[n0 + 2]; e2 = rp[n0 + 3]; }
    if (n0 + 3 < Nd) { b3 = rp[n0 + 3]; e3 = rp[n0 + 4]; }
    int d0 = e0 - b0, d1 = e1 - b1, d2 = e2 - b2, d3 = e3 - b3;
    int dm = max(max(d0, d1), max(d2, d3));
    float s0 = 0.f, s1 = 0.f, s2 = 0.f, s3 = 0.f;
    for (int it = 0; it < dm; it++) {
        if (it < d0) { int sj = col[b0 + it]; float wj = alw[(size_t)(b0 + it) * 4 + hcl];
                       s0 = fmaf(toF(hs[(size_t)sj * 64 + lane]), wj, s0); }
        if (it < d1) { int sj = col[b1 + it]; float wj = alw[(size_t)(b1 + it) * 4 + hcl];
                       s1 = fmaf(toF(hs[(size_t)sj * 64 + lane]), wj, s1); }
        if (it < d2) { int sj = col[b2 + it]; float wj = alw[(size_t)(b2 + it) * 4 + hcl];
                       s2 = fmaf(toF(hs[(size_t)sj * 64 + lane]), wj, s2); }
        if (it < d3) { int sj = col[b3 + it]; float wj = alw[(size_t)(b3 + it) * 4 + hcl];
                       s3 = fmaf(toF(hs[(size_t)sj * 64 + lane]), wj, s3); }
    }
    a0 = fmaf(s0, rdn[(size_t)n0 * 4 + hcl], a0);
    if (n0 + 1 < Nd) a1 = fmaf(s1, rdn[(size_t)(n0 + 1) * 4 + hcl], a1);
    if (n0 + 2 < Nd) a2 = fmaf(s2, rdn[(size_t)(n0 + 2) * 4 + hcl], a2);
    if (n0 + 3 < Nd) a3 = fmaf(s3, rdn[(size_t)(n0 + 3) * 4 + hcl], a3);
}

__global__ void k_agg(const int* rp0, const float* rdn0, const bf16* h0,
                      const int* rp1, const float* rdn1, const bf16* h1,
                      const int* rp2, const float* rdn2, const bf16* h2,
                      const int* __restrict__ col, const float* __restrict__ alw,
                      const float* __restrict__ cb, int b0i, int b1i, int b2i,
                      bf16* __restrict__ out, int Nd) {
    int wv = threadIdx.x >> 6;
    int n0 = (blockIdx.x * 4 + wv) * 4;
    if (n0 >= Nd) return;
    int lane = threadIdx.x & 63;
    int hcl = lane >> 4;
    float bias = cb[b0i * 64 + lane];
    if (b1i >= 0) bias += cb[b1i * 64 + lane];
    if (b2i >= 0) bias += cb[b2i * 64 + lane];
    float a0 = bias, a1 = bias, a2 = bias, a3 = bias;
    agg4(rp0, rdn0, h0, col, alw, n0, Nd, lane, hcl, a0, a1, a2, a3);
    if (rp1) agg4(rp1, rdn1, h1, col, alw, n0, Nd, lane, hcl, a0, a1, a2, a3);
    if (rp2) agg4(rp2, rdn2, h2, col, alw, n0, Nd, lane, hcl, a0, a1, a2, a3);
    out[(size_t)n0 * 64 + lane] = __float2bfloat16(a0 > 0.f ? a0 : 0.f);
    if (n0 + 1 < Nd) out[(size_t)(n0 + 1) * 64 + lane] = __float2bfloat16(a1 > 0.f ? a1 : 0.f);
    if (n0 + 2 < Nd) out[(size_t)(n0 + 2) * 64 + lane] = __float2bfloat16(a2 > 0.f ? a2 : 0.f);
    if (n0 + 3 < Nd) out[(size_t)(n0 + 3) * 64 + lane] = __float2bfloat16(a3 > 0.f ? a3 : 0.f);
}

// ================= classifier =================
__global__ void k_cls(const bf16* __restrict__ t, const float* __restrict__ w1,
                      const float* __restrict__ b1, const float* __restrict__ w2,
                      const float* __restrict__ b2, float* __restrict__ out) {
    __shared__ float w1s[64 * 32];
    __shared__ float w2s[64];
    __shared__ float b1s[32];
    __shared__ float b2s[2];
    __shared__ float ts[8 * 64];
    int tid = threadIdx.x;
    for (int i = tid; i < 2048; i += 256) w1s[i] = w1[i];
    if (tid < 64) w2s[tid] = w2[tid];
    if (tid < 32) b1s[tid] = b1[tid];
    if (tid < 2) b2s[tid] = b2[tid];
    int n0 = blockIdx.x << 3;
    for (int i = tid; i < 512; i += 256) {
        int row = i >> 6, col = i & 63;
        ts[i] = toF(t[(size_t)(n0 + row) * 64 + col]);
    }
    __syncthreads();
    int lane = tid & 31;
    int row = tid >> 5;
    float h = b1s[lane];
#pragma unroll 8
    for (int k = 0; k < 64; k++) h = fmaf(ts[(row << 6) + k], w1s[(k << 5) + lane], h);
    h = h > 0.f ? h : 0.f;
    float o0 = h * w2s[lane * 2 + 0];
    float o1 = h * w2s[lane * 2 + 1];
#pragma unroll
    for (int off = 16; off; off >>= 1) {
        o0 += __shfl_down(o0, off, 32);
        o1 += __shfl_down(o1, off, 32);
    }
    if (lane == 0) {
        int n = n0 + row;
        out[(size_t)n * 2 + 0] = o0 + b2s[0];
        out[(size_t)n * 2 + 1] = o1 + b2s[1];
    }
}

extern "C" void kernel_launch(void* const* d_in, const int* in_sizes, int n_in,
                              void* d_out, int out_size, void* d_ws, size_t ws_size,
                              hipStream_t stream) {
    (void)n_in; (void)out_size;
    const float* x_user  = (const float*)d_in[0];
    const float* x_tx    = (const float*)d_in[1];
    const float* x_merch = (const float*)d_in[2];
    const int* ei[7];
    int E[7];
    for (int r = 0; r < 7; r++) { ei[r] = (const int*)d_in[3 + r]; E[r] = in_sizes[3 + r] / 2; }
    const float* Win_user  = (const float*)d_in[10];
    const float* bin_user  = (const float*)d_in[11];
    const float* Win_tx    = (const float*)d_in[12];
    const float* bin_tx    = (const float*)d_in[13];
    const float* Win_merch = (const float*)d_in[14];
    const float* bin_merch = (const float*)d_in[15];
    const float* lin_w     = (const float*)d_in[16];
    const float* att_src   = (const float*)d_in[17];
    const float* att_dst   = (const float*)d_in[18];
    const float* conv_bias = (const float*)d_in[19];
    const float* cls_w1    = (const float*)d_in[20];
    const float* cls_b1    = (const float*)d_in[21];
    const float* cls_w2    = (const float*)d_in[22];
    const float* cls_b2    = (const float*)d_in[23];

    const int src_type[7] = {0, 1, 2, 1, 0, 2, 1};
    const int dst_type[7] = {1, 0, 1, 2, 0, 2, 1};
    const int N_of[3] = {NU, NT, NM};

    // segment offsets
    Segs segs;
    int TE = 0, TN = 0;
    for (int r = 0; r < 7; r++) {
        segs.ei[r] = ei[r];
        segs.eoff[r] = TE; TE += E[r];
        segs.noff[r] = TN; TN += N_of[dst_type[r]];
    }
    segs.eoff[7] = TE;
    segs.noff[7] = TN;

    // ---- workspace layout ----
    size_t off = 0;
    auto alloc = [&](size_t bytes) { size_t q = off; off += (bytes + 255) & ~(size_t)255; return q; };
    size_t o_a[3], o_b[3], o_hs[3], o_aS[3];
    for (int tpe = 0; tpe < 3; tpe++) o_a[tpe]  = alloc((size_t)N_of[tpe] * 64 * 2);
    for (int tpe = 0; tpe < 3; tpe++) o_b[tpe]  = alloc((size_t)N_of[tpe] * 64 * 2);
    for (int tpe = 0; tpe < 3; tpe++) o_hs[tpe] = alloc((size_t)N_of[tpe] * 64 * 2);
    for (int tpe = 0; tpe < 3; tpe++) o_aS[tpe] = alloc((size_t)N_of[tpe] * 4 * 4);
    size_t o_aD[3];
    for (int jj = 0; jj < 3; jj++) o_aD[jj] = alloc((size_t)NT * 4 * 4);
    size_t o_rp   = alloc(((size_t)TN + 1) * 4);
    size_t o_col  = alloc((size_t)TE * 4);
    size_t o_alw  = alloc((size_t)TE * 4 * 4);
    size_t o_cnt  = alloc((size_t)TN * 4);
    size_t o_bsum = alloc((size_t)8192 * 4);
    size_t o_wa   = alloc((size_t)2 * 7 * 64 * 8 * 4);
    size_t o_wt   = alloc((size_t)14 * 8192 * 2);
    if (off > ws_size) return;  // fail cleanly (absmax will read ~0.31)

    char* base = (char*)d_ws;
    bf16* A[3], *B[3], *hsS[3];
    float* aSS[3];
    for (int tpe = 0; tpe < 3; tpe++) {
        A[tpe] = (bf16*)(base + o_a[tpe]);
        B[tpe] = (bf16*)(base + o_b[tpe]);
        hsS[tpe] = (bf16*)(base + o_hs[tpe]);
        aSS[tpe] = (float*)(base + o_aS[tpe]);
    }
    float* aDS[3];
    for (int jj = 0; jj < 3; jj++) aDS[jj] = (float*)(base + o_aD[jj]);
    int* rp_all   = (int*)(base + o_rp);
    int* col_all  = (int*)(base + o_col);
    float* alw    = (float*)(base + o_alw);
    int* cnt      = (int*)(base + o_cnt);
    int* bsum     = (int*)(base + o_bsum);
    float* wa     = (float*)(base + o_wa);
    bf16* wt      = (bf16*)(base + o_wt);

    // ---- fused CSR build over all 7 relations ----
    int nb = (TN + 256) / 256;  // covers TN+1 scan outputs
    k_zero_i<<<(TN + 255) / 256, 256, 0, stream>>>(cnt, TN);
    k_hist_all<<<(TE + 255) / 256, 256, 0, stream>>>(segs, TE, cnt);
    k_scan1<<<nb, 256, 0, stream>>>(cnt, TN, bsum);
    k_scan2<<<1, 256, 0, stream>>>(bsum, nb);
    k_scan3<<<nb, 256, 0, stream>>>(cnt, TN, bsum, rp_all);
    k_zero_i<<<(TN + 255) / 256, 256, 0, stream>>>(cnt, TN);
    k_fill_all<<<(TE + 255) / 256, 256, 0, stream>>>(segs, TE, rp_all, cnt, col_all);

    k_wa<<<(7168 + 255) / 256, 256, 0, stream>>>(lin_w, att_src, att_dst, wa);
    k_wt<<<(14 * 4096 + 255) / 256, 256, 0, stream>>>(lin_w, wt);
    k_proj<<<(NU + 31) / 32, 256, 0, stream>>>(x_user, Win_user, bin_user, A[0], NU, 32);
    k_proj<<<(NT + 31) / 32, 256, 0, stream>>>(x_tx, Win_tx, bin_tx, A[1], NT, 64);
    k_proj<<<(NM + 31) / 32, 256, 0, stream>>>(x_merch, Win_merch, bin_merch, A[2], NM, 16);

    const int grp_dst[3]     = {1, 0, 2};
    const int grp_rels[3][3] = {{0, 2, 6}, {1, 4, -1}, {3, 5, -1}};

    for (int l = 0; l < 2; l++) {
        bf16** cur = (l == 0) ? A : B;
        bf16** nxt = (l == 0) ? B : A;
        const float* cb = conv_bias + (size_t)l * 7 * 64;
        for (int g = 0; g < 3; g++) {
            int dt = grp_dst[g];
            int Nd = N_of[dt];
            const int* grp = grp_rels[g];
            int nrel = (grp[2] >= 0) ? 3 : 2;
            // projections (+fused src alpha; dst alpha for self-relations)
            const float* crossWa[2] = {nullptr, nullptr};
            float* crossAD[2] = {nullptr, nullptr};
            int ncross = 0;
            for (int jj = 0; jj < nrel; jj++) {
                int r = grp[jj];
                int st = src_type[r];
                int lr = l * 7 + r;
                const bf16* wtp  = wt + (size_t)lr * 8192;
                const float* avs = att_src + (size_t)lr * 64;
                const float* avd = att_dst + (size_t)lr * 64;
                if (st == dt) {
                    k_pmfma<<<(N_of[st] + 63) / 64, 256, 0, stream>>>(
                        cur[st], wtp, avs, avd, hsS[st], aSS[st], aDS[jj], N_of[st]);
                } else {
                    k_pmfma<<<(N_of[st] + 63) / 64, 256, 0, stream>>>(
                        cur[st], wtp, avs, nullptr, hsS[st], aSS[st], nullptr, N_of[st]);
                    crossWa[ncross] = wa + (size_t)lr * 512;
                    crossAD[ncross] = aDS[jj];
                    ncross++;
                }
            }
            if (ncross > 0) {
                k_alpha2<<<(Nd + 31) / 32, 256, 0, stream>>>(
                    cur[dt], crossWa[0], ncross > 1 ? crossWa[1] : nullptr,
                    crossAD[0], ncross > 1 ? crossAD[1] : nullptr, Nd);
            }
            // batched softmax over the group's relations
            const int* rpr[3] = {nullptr, nullptr, nullptr};
            const float* aSr[3] = {nullptr, nullptr, nullptr};
            for (int jj = 0; jj < nrel; jj++) {
                rpr[jj] = rp_all + segs.noff[grp[jj]];
                aSr[jj] = aSS[src_type[grp[jj]]];
            }
            k_smw3<<<((size_t)nrel * Nd * 4 + 255) / 256, 256, 0, stream>>>(
                rpr[0], aSr[0], aDS[0],
                rpr[1], aSr[1], aDS[1],
                rpr[2], aSr[2], aDS[2],
                col_all, alw, Nd, nrel);
            // aggregation
            int r0 = grp[0], r1 = grp[1], r2 = grp[2];
            k_agg<<<(Nd + 15) / 16, 256, 0, stream>>>(
                rpr[0], aDS[0], hsS[src_type[r0]],
                rpr[1], aDS[1], r1 >= 0 ? hsS[src_type[r1]] : nullptr,
                rpr[2], aDS[2], r2 >= 0 ? hsS[src_type[r2]] : nullptr,
                col_all, alw, cb, r0, r1, r2, nxt[dt], Nd);
        }
    }
    k_cls<<<NT / 8, 256, 0, stream>>>(A[1], cls_w1, cls_b1, cls_w2, cls_b2, (float*)d_out);
}

// Round 8
// 1855.265 us; speedup vs baseline: 1.0866x; 1.0667x over previous
//
#include <hip/hip_runtime.h>
#include <hip/hip_bf16.h>

#define NU 100000
#define NT 300000
#define NM 10000

typedef __hip_bfloat16 bf16;
typedef __attribute__((ext_vector_type(8))) short bf16x8;
typedef __attribute__((ext_vector_type(4))) float f32x4;

__device__ __forceinline__ float toF(float v) { return v; }
__device__ __forceinline__ float toF(bf16 v)  { return __bfloat162float(v); }

struct Segs {
    const int* ei[7];
    int eoff[8];
    int noff[8];
};

struct FA {
    const int* rp[3];
    const float* aS[3];
    const float* aD[3];
    const bf16* hs[3];
};

// ================= fused CSR build =================
__global__ void k_zero_i(int* __restrict__ p, int n) {
    int i = blockIdx.x * 256 + threadIdx.x;
    if (i < n) p[i] = 0;
}

__global__ void k_hist_all(Segs s, int TE, int* __restrict__ cnt) {
    int g = blockIdx.x * 256 + threadIdx.x;
    if (g >= TE) return;
    int r = 0;
    while (g >= s.eoff[r + 1]) r++;
    int e = g - s.eoff[r];
    int E = s.eoff[r + 1] - s.eoff[r];
    int d = s.ei[r][E + e];
    atomicAdd(&cnt[s.noff[r] + d], 1);
}

__global__ void k_scan1(const int* __restrict__ cnt, int n, int* __restrict__ bsum) {
    __shared__ int sh[256];
    int i = blockIdx.x * 256 + threadIdx.x;
    sh[threadIdx.x] = (i < n) ? cnt[i] : 0;
    __syncthreads();
    for (int o = 128; o; o >>= 1) {
        if (threadIdx.x < o) sh[threadIdx.x] += sh[threadIdx.x + o];
        __syncthreads();
    }
    if (threadIdx.x == 0) bsum[blockIdx.x] = sh[0];
}

__global__ void k_scan2(int* __restrict__ bsum, int nb) {  // 1 block
    __shared__ int sh[256];
    __shared__ int carry;
    if (threadIdx.x == 0) carry = 0;
    __syncthreads();
    for (int base = 0; base < nb; base += 256) {
        int i = base + threadIdx.x;
        int v = (i < nb) ? bsum[i] : 0;
        sh[threadIdx.x] = v;
        __syncthreads();
        for (int o = 1; o < 256; o <<= 1) {
            int t = (threadIdx.x >= o) ? sh[threadIdx.x - o] : 0;
            __syncthreads();
            sh[threadIdx.x] += t;
            __syncthreads();
        }
        if (i < nb) bsum[i] = carry + sh[threadIdx.x] - v;  // exclusive
        __syncthreads();
        if (threadIdx.x == 255) carry += sh[255];
        __syncthreads();
    }
}

__global__ void k_scan3(const int* __restrict__ cnt, int n, const int* __restrict__ bsum,
                        int* __restrict__ out) {
    __shared__ int sh[256];
    int i = blockIdx.x * 256 + threadIdx.x;
    int v = (i < n) ? cnt[i] : 0;
    sh[threadIdx.x] = v;
    __syncthreads();
    for (int o = 1; o < 256; o <<= 1) {
        int t = (threadIdx.x >= o) ? sh[threadIdx.x - o] : 0;
        __syncthreads();
        sh[threadIdx.x] += t;
        __syncthreads();
    }
    if (i <= n) out[i] = bsum[blockIdx.x] + sh[threadIdx.x] - v;
}

__global__ void k_fill_all(Segs s, int TE, const int* __restrict__ rp_all,
                           int* __restrict__ cnt, int* __restrict__ col) {
    int g = blockIdx.x * 256 + threadIdx.x;
    if (g >= TE) return;
    int r = 0;
    while (g >= s.eoff[r + 1]) r++;
    int e = g - s.eoff[r];
    int E = s.eoff[r + 1] - s.eoff[r];
    int d = s.ei[r][E + e];
    int idx = s.noff[r] + d;
    int pos = rp_all[idx] + atomicAdd(&cnt[idx], 1);
    col[pos] = s.ei[r][e];
}

// ================= weight prep =================
// wa[lr*512 + k*8 + j]; j 0..3 src head j, 4..7 dst head j-4
__global__ void k_wa(const float* __restrict__ lin_w, const float* __restrict__ att_s,
                     const float* __restrict__ att_d, float* __restrict__ wa) {
    int i = blockIdx.x * 256 + threadIdx.x;
    if (i >= 2 * 7 * 64 * 8) return;
    int j = i & 7;
    int k = (i >> 3) & 63;
    int lr = i >> 9;
    int h = j & 3;
    const float* a = (j < 4 ? att_s : att_d) + lr * 64 + h * 16;
    const float* Wp = lin_w + (size_t)lr * 4096 + k * 64 + h * 16;
    float s = 0.f;
#pragma unroll
    for (int c = 0; c < 16; c++) s += Wp[c] * a[c];
    wa[i] = s;
}

// wt: per (l,r): [2][64][64] bf16, transposed (Wt[c][k]), hi + lo split
__global__ void k_wt(const float* __restrict__ lin_w, bf16* __restrict__ wt) {
    int i = blockIdx.x * 256 + threadIdx.x;
    if (i >= 14 * 4096) return;
    int lr = i >> 12;
    int kc = i & 4095;
    int k = kc >> 6, c = kc & 63;
    float v = lin_w[(size_t)lr * 4096 + k * 64 + c];
    bf16 hi = __float2bfloat16(v);
    float rem = v - __bfloat162float(hi);
    wt[(size_t)lr * 8192 + c * 64 + k] = hi;
    wt[(size_t)lr * 8192 + 4096 + c * 64 + k] = __float2bfloat16(rem);
}

// ================= input projection (fp32 VALU, runs once) =================
__global__ void k_proj(const float* __restrict__ x, const float* __restrict__ W,
                       const float* __restrict__ bias, bf16* __restrict__ out,
                       int N, int K) {
    __shared__ float Ws[64 * 64];
    __shared__ float xs[32 * 64];
    int tid = threadIdx.x;
    int r0 = blockIdx.x << 5;
    for (int i = tid; i < K * 64; i += 256) Ws[i] = W[i];
    for (int i = tid; i < 32 * K; i += 256) {
        int row = i / K, col = i - row * K;
        int n = r0 + row;
        xs[(row << 6) + col] = (n < N) ? x[(size_t)n * K + col] : 0.f;
    }
    __syncthreads();
    int c = tid & 63;
    float bv = bias[c];
    for (int rr = tid >> 6; rr < 32; rr += 4) {
        int n = r0 + rr;
        if (n >= N) return;
        float acc = bv;
#pragma unroll 16
        for (int k = 0; k < K; k++) acc = fmaf(xs[(rr << 6) + k], Ws[(k << 6) + c], acc);
        out[(size_t)n * 64 + c] = __float2bfloat16(acc);
    }
}

// ================= MFMA projection + fused alphas =================
__global__ void k_pmfma(const bf16* __restrict__ x, const bf16* __restrict__ wt,
                        const float* __restrict__ avs_p, const float* __restrict__ avd_p,
                        bf16* __restrict__ hs, float* __restrict__ aS, float* __restrict__ aD,
                        int N) {
    int w = threadIdx.x >> 6, lane = threadIdx.x & 63;
    int m = lane & 15, kq = lane >> 4;
    int r0 = blockIdx.x * 64 + w * 16;
    bf16x8 a0 = {}, a1 = {};
    int row = r0 + m;
    if (row < N) {
        a0 = *(const bf16x8*)(x + (size_t)row * 64 + kq * 8);
        a1 = *(const bf16x8*)(x + (size_t)row * 64 + 32 + kq * 8);
    }
#pragma unroll
    for (int nt = 0; nt < 4; nt++) {
        const bf16* wb  = wt + (nt * 16 + m) * 64 + kq * 8;
        const bf16* wbl = wb + 4096;
        bf16x8 bh0 = *(const bf16x8*)(wb);
        bf16x8 bh1 = *(const bf16x8*)(wb + 32);
        bf16x8 bl0 = *(const bf16x8*)(wbl);
        bf16x8 bl1 = *(const bf16x8*)(wbl + 32);
        f32x4 acc = {};
        acc = __builtin_amdgcn_mfma_f32_16x16x32_bf16(a0, bh0, acc, 0, 0, 0);
        acc = __builtin_amdgcn_mfma_f32_16x16x32_bf16(a0, bl0, acc, 0, 0, 0);
        acc = __builtin_amdgcn_mfma_f32_16x16x32_bf16(a1, bh1, acc, 0, 0, 0);
        acc = __builtin_amdgcn_mfma_f32_16x16x32_bf16(a1, bl1, acc, 0, 0, 0);
        float avsv = avs_p ? avs_p[nt * 16 + m] : 0.f;
        float avdv = avd_p ? avd_p[nt * 16 + m] : 0.f;
#pragma unroll
        for (int i = 0; i < 4; i++) {
            int rr = r0 + kq * 4 + i;
            if (rr < N) hs[(size_t)rr * 64 + nt * 16 + m] = __float2bfloat16(acc[i]);
            if (avs_p) {
                float ps = acc[i] * avsv;
                ps += __shfl_xor(ps, 1); ps += __shfl_xor(ps, 2);
                ps += __shfl_xor(ps, 4); ps += __shfl_xor(ps, 8);
                if (m == 0 && rr < N) aS[rr * 4 + nt] = ps;
            }
            if (avd_p) {
                float pd = acc[i] * avdv;
                pd += __shfl_xor(pd, 1); pd += __shfl_xor(pd, 2);
                pd += __shfl_xor(pd, 4); pd += __shfl_xor(pd, 8);
                if (m == 0 && rr < N) aD[rr * 4 + nt] = pd;
            }
        }
    }
}

// ================= batched dst-alpha GEMV (up to 2 cross relations) =================
__global__ void k_alpha2(const bf16* __restrict__ x, const float* __restrict__ waA,
                         const float* __restrict__ waB, float* __restrict__ aDA,
                         float* __restrict__ aDB, int N) {
    __shared__ float xs[32 * 64];
    __shared__ float wsA[256], wsB[256];
    int tid = threadIdx.x;
    {
        int k = tid >> 2, h = tid & 3;
        wsA[tid] = waA[(k << 3) + 4 + h];
        wsB[tid] = waB ? waB[(k << 3) + 4 + h] : 0.f;
    }
    int r0 = blockIdx.x << 5;
    for (int i = tid; i < 2048; i += 256) {
        int row = i >> 6, c = i & 63;
        int n = r0 + row;
        xs[i] = (n < N) ? toF(x[(size_t)n * 64 + c]) : 0.f;
    }
    __syncthreads();
    int row = tid >> 3, j = tid & 7;
    int n = r0 + row;
    if (n >= N) return;
    int h = j & 3;
    bool sB = j >= 4;
    if (sB && !waB) return;
    const float* ws = sB ? wsB : wsA;
    float acc = 0.f;
#pragma unroll
    for (int k = 0; k < 64; k++) acc = fmaf(xs[(row << 6) + k], ws[(k << 2) + h], acc);
    (sB ? aDB : aDA)[n * 4 + h] = acc;
}

// ================= fused softmax+aggregation: wave per node, issue-all loads ==========
// out[n] = relu( bias + sum_r (sum_e ex*hs) / (sum_e ex + eps) ), ex = exp(lrelu(aS+aD))
template <int NREL, int EPR>
__global__ void k_fagg(FA fa, const int* __restrict__ col, const float* __restrict__ cb,
                       int b0i, int b1i, int b2i, bf16* __restrict__ out, int Nd) {
    int node = blockIdx.x * 4 + (threadIdx.x >> 6);
    if (node >= Nd) return;
    int lane = threadIdx.x & 63;
    int hcl = lane >> 4;
    int beg[NREL], deg[NREL];
    float ad[NREL], dn[NREL], acc[NREL];
#pragma unroll
    for (int r = 0; r < NREL; r++) {
        beg[r] = fa.rp[r][node];
        deg[r] = fa.rp[r][node + 1] - beg[r];
    }
#pragma unroll
    for (int r = 0; r < NREL; r++) {
        ad[r] = fa.aD[r][node * 4 + hcl];
        dn[r] = 0.f;
        acc[r] = 0.f;
    }
    // ---- first chunk: all relations' loads issued together ----
    {
        int cv[NREL][EPR];
#pragma unroll
        for (int r = 0; r < NREL; r++)
#pragma unroll
            for (int j = 0; j < EPR; j++) cv[r][j] = (j < deg[r]) ? col[beg[r] + j] : 0;
        float as[NREL][EPR];
#pragma unroll
        for (int r = 0; r < NREL; r++)
#pragma unroll
            for (int j = 0; j < EPR; j++) as[r][j] = (j < deg[r]) ? fa.aS[r][cv[r][j] * 4 + hcl] : 0.f;
        float hv[NREL][EPR];
#pragma unroll
        for (int r = 0; r < NREL; r++)
#pragma unroll
            for (int j = 0; j < EPR; j++)
                hv[r][j] = (j < deg[r]) ? toF(fa.hs[r][(size_t)cv[r][j] * 64 + lane]) : 0.f;
#pragma unroll
        for (int r = 0; r < NREL; r++)
#pragma unroll
            for (int j = 0; j < EPR; j++) if (j < deg[r]) {
                float a = as[r][j] + ad[r];
                a = (a >= 0.f) ? a : 0.2f * a;
                float ex = __expf(a);
                dn[r] += ex;
                acc[r] = fmaf(ex, hv[r][j], acc[r]);
            }
    }
    // ---- remainders (deg > EPR), chunked issue-all per relation ----
#pragma unroll
    for (int r = 0; r < NREL; r++) {
        int e = beg[r] + deg[r];
        for (int i0 = beg[r] + EPR; i0 < e; i0 += EPR) {
            int mrem = e - i0;
            int cw[EPR];
#pragma unroll
            for (int j = 0; j < EPR; j++) cw[j] = (j < mrem) ? col[i0 + j] : 0;
            float aw[EPR];
#pragma unroll
            for (int j = 0; j < EPR; j++) aw[j] = (j < mrem) ? fa.aS[r][cw[j] * 4 + hcl] : 0.f;
            float hw[EPR];
#pragma unroll
            for (int j = 0; j < EPR; j++)
                hw[j] = (j < mrem) ? toF(fa.hs[r][(size_t)cw[j] * 64 + lane]) : 0.f;
#pragma unroll
            for (int j = 0; j < EPR; j++) if (j < mrem) {
                float a = aw[j] + ad[r];
                a = (a >= 0.f) ? a : 0.2f * a;
                float ex = __expf(a);
                dn[r] += ex;
                acc[r] = fmaf(ex, hw[j], acc[r]);
            }
        }
    }
    // ---- epilogue ----
    float o = cb[b0i * 64 + lane];
    if (b1i >= 0) o += cb[b1i * 64 + lane];
    if (b2i >= 0) o += cb[b2i * 64 + lane];
#pragma unroll
    for (int r = 0; r < NREL; r++) o += acc[r] / (dn[r] + 1e-16f);
    out[(size_t)node * 64 + lane] = __float2bfloat16(o > 0.f ? o : 0.f);
}

// ================= classifier =================
__global__ void k_cls(const bf16* __restrict__ t, const float* __restrict__ w1,
                      const float* __restrict__ b1, const float* __restrict__ w2,
                      const float* __restrict__ b2, float* __restrict__ out) {
    __shared__ float w1s[64 * 32];
    __shared__ float w2s[64];
    __shared__ float b1s[32];
    __shared__ float b2s[2];
    __shared__ float ts[8 * 64];
    int tid = threadIdx.x;
    for (int i = tid; i < 2048; i += 256) w1s[i] = w1[i];
    if (tid < 64) w2s[tid] = w2[tid];
    if (tid < 32) b1s[tid] = b1[tid];
    if (tid < 2) b2s[tid] = b2[tid];
    int n0 = blockIdx.x << 3;
    for (int i = tid; i < 512; i += 256) {
        int row = i >> 6, col = i & 63;
        ts[i] = toF(t[(size_t)(n0 + row) * 64 + col]);
    }
    __syncthreads();
    int lane = tid & 31;
    int row = tid >> 5;
    float h = b1s[lane];
#pragma unroll 8
    for (int k = 0; k < 64; k++) h = fmaf(ts[(row << 6) + k], w1s[(k << 5) + lane], h);
    h = h > 0.f ? h : 0.f;
    float o0 = h * w2s[lane * 2 + 0];
    float o1 = h * w2s[lane * 2 + 1];
#pragma unroll
    for (int off = 16; off; off >>= 1) {
        o0 += __shfl_down(o0, off, 32);
        o1 += __shfl_down(o1, off, 32);
    }
    if (lane == 0) {
        int n = n0 + row;
        out[(size_t)n * 2 + 0] = o0 + b2s[0];
        out[(size_t)n * 2 + 1] = o1 + b2s[1];
    }
}

extern "C" void kernel_launch(void* const* d_in, const int* in_sizes, int n_in,
                              void* d_out, int out_size, void* d_ws, size_t ws_size,
                              hipStream_t stream) {
    (void)n_in; (void)out_size;
    const float* x_user  = (const float*)d_in[0];
    const float* x_tx    = (const float*)d_in[1];
    const float* x_merch = (const float*)d_in[2];
    const int* ei[7];
    int E[7];
    for (int r = 0; r < 7; r++) { ei[r] = (const int*)d_in[3 + r]; E[r] = in_sizes[3 + r] / 2; }
    const float* Win_user  = (const float*)d_in[10];
    const float* bin_user  = (const float*)d_in[11];
    const float* Win_tx    = (const float*)d_in[12];
    const float* bin_tx    = (const float*)d_in[13];
    const float* Win_merch = (const float*)d_in[14];
    const float* bin_merch = (const float*)d_in[15];
    const float* lin_w     = (const float*)d_in[16];
    const float* att_src   = (const float*)d_in[17];
    const float* att_dst   = (const float*)d_in[18];
    const float* conv_bias = (const float*)d_in[19];
    const float* cls_w1    = (const float*)d_in[20];
    const float* cls_b1    = (const float*)d_in[21];
    const float* cls_w2    = (const float*)d_in[22];
    const float* cls_b2    = (const float*)d_in[23];

    const int src_type[7] = {0, 1, 2, 1, 0, 2, 1};
    const int dst_type[7] = {1, 0, 1, 2, 0, 2, 1};
    const int N_of[3] = {NU, NT, NM};

    // segment offsets
    Segs segs;
    int TE = 0, TN = 0;
    for (int r = 0; r < 7; r++) {
        segs.ei[r] = ei[r];
        segs.eoff[r] = TE; TE += E[r];
        segs.noff[r] = TN; TN += N_of[dst_type[r]];
    }
    segs.eoff[7] = TE;
    segs.noff[7] = TN;

    // ---- workspace layout ----
    size_t off = 0;
    auto alloc = [&](size_t bytes) { size_t q = off; off += (bytes + 255) & ~(size_t)255; return q; };
    size_t o_a[3], o_b[3], o_hs[3], o_aS[3];
    for (int tpe = 0; tpe < 3; tpe++) o_a[tpe]  = alloc((size_t)N_of[tpe] * 64 * 2);
    for (int tpe = 0; tpe < 3; tpe++) o_b[tpe]  = alloc((size_t)N_of[tpe] * 64 * 2);
    for (int tpe = 0; tpe < 3; tpe++) o_hs[tpe] = alloc((size_t)N_of[tpe] * 64 * 2);
    for (int tpe = 0; tpe < 3; tpe++) o_aS[tpe] = alloc((size_t)N_of[tpe] * 4 * 4);
    size_t o_aD[3];
    for (int jj = 0; jj < 3; jj++) o_aD[jj] = alloc((size_t)NT * 4 * 4);
    size_t o_rp   = alloc(((size_t)TN + 1) * 4);
    size_t o_col  = alloc((size_t)TE * 4);
    size_t o_cnt  = alloc((size_t)TN * 4);
    size_t o_bsum = alloc((size_t)8192 * 4);
    size_t o_wa   = alloc((size_t)2 * 7 * 64 * 8 * 4);
    size_t o_wt   = alloc((size_t)14 * 8192 * 2);
    if (off > ws_size) return;  // fail cleanly (absmax will read ~0.31)

    char* base = (char*)d_ws;
    bf16* A[3], *B[3], *hsS[3];
    float* aSS[3];
    for (int tpe = 0; tpe < 3; tpe++) {
        A[tpe] = (bf16*)(base + o_a[tpe]);
        B[tpe] = (bf16*)(base + o_b[tpe]);
        hsS[tpe] = (bf16*)(base + o_hs[tpe]);
        aSS[tpe] = (float*)(base + o_aS[tpe]);
    }
    float* aDS[3];
    for (int jj = 0; jj < 3; jj++) aDS[jj] = (float*)(base + o_aD[jj]);
    int* rp_all   = (int*)(base + o_rp);
    int* col_all  = (int*)(base + o_col);
    int* cnt      = (int*)(base + o_cnt);
    int* bsum     = (int*)(base + o_bsum);
    float* wa     = (float*)(base + o_wa);
    bf16* wt      = (bf16*)(base + o_wt);

    // ---- fused CSR build over all 7 relations ----
    int nb = (TN + 256) / 256;  // covers TN+1 scan outputs
    k_zero_i<<<(TN + 255) / 256, 256, 0, stream>>>(cnt, TN);
    k_hist_all<<<(TE + 255) / 256, 256, 0, stream>>>(segs, TE, cnt);
    k_scan1<<<nb, 256, 0, stream>>>(cnt, TN, bsum);
    k_scan2<<<1, 256, 0, stream>>>(bsum, nb);
    k_scan3<<<nb, 256, 0, stream>>>(cnt, TN, bsum, rp_all);
    k_zero_i<<<(TN + 255) / 256, 256, 0, stream>>>(cnt, TN);
    k_fill_all<<<(TE + 255) / 256, 256, 0, stream>>>(segs, TE, rp_all, cnt, col_all);

    k_wa<<<(7168 + 255) / 256, 256, 0, stream>>>(lin_w, att_src, att_dst, wa);
    k_wt<<<(14 * 4096 + 255) / 256, 256, 0, stream>>>(lin_w, wt);
    k_proj<<<(NU + 31) / 32, 256, 0, stream>>>(x_user, Win_user, bin_user, A[0], NU, 32);
    k_proj<<<(NT + 31) / 32, 256, 0, stream>>>(x_tx, Win_tx, bin_tx, A[1], NT, 64);
    k_proj<<<(NM + 31) / 32, 256, 0, stream>>>(x_merch, Win_merch, bin_merch, A[2], NM, 16);

    const int grp_dst[3]     = {1, 0, 2};
    const int grp_rels[3][3] = {{0, 2, 6}, {1, 4, -1}, {3, 5, -1}};

    for (int l = 0; l < 2; l++) {
        bf16** cur = (l == 0) ? A : B;
        bf16** nxt = (l == 0) ? B : A;
        const float* cb = conv_bias + (size_t)l * 7 * 64;
        for (int g = 0; g < 3; g++) {
            int dt = grp_dst[g];
            int Nd = N_of[dt];
            const int* grp = grp_rels[g];
            int nrel = (grp[2] >= 0) ? 3 : 2;
            // projections (+fused src alpha; dst alpha for self-relations)
            const float* crossWa[2] = {nullptr, nullptr};
            float* crossAD[2] = {nullptr, nullptr};
            int ncross = 0;
            for (int jj = 0; jj < nrel; jj++) {
                int r = grp[jj];
                int st = src_type[r];
                int lr = l * 7 + r;
                const bf16* wtp  = wt + (size_t)lr * 8192;
                const float* avs = att_src + (size_t)lr * 64;
                const float* avd = att_dst + (size_t)lr * 64;
                if (st == dt) {
                    k_pmfma<<<(N_of[st] + 63) / 64, 256, 0, stream>>>(
                        cur[st], wtp, avs, avd, hsS[st], aSS[st], aDS[jj], N_of[st]);
                } else {
                    k_pmfma<<<(N_of[st] + 63) / 64, 256, 0, stream>>>(
                        cur[st], wtp, avs, nullptr, hsS[st], aSS[st], nullptr, N_of[st]);
                    crossWa[ncross] = wa + (size_t)lr * 512;
                    crossAD[ncross] = aDS[jj];
                    ncross++;
                }
            }
            if (ncross > 0) {
                k_alpha2<<<(Nd + 31) / 32, 256, 0, stream>>>(
                    cur[dt], crossWa[0], ncross > 1 ? crossWa[1] : nullptr,
                    crossAD[0], ncross > 1 ? crossAD[1] : nullptr, Nd);
            }
            // fused softmax + aggregation
            FA fa;
            for (int jj = 0; jj < 3; jj++) {
                int r = grp[jj] >= 0 ? grp[jj] : grp[0];
                fa.rp[jj] = rp_all + segs.noff[r];
                fa.aS[jj] = aSS[src_type[r]];
                fa.aD[jj] = aDS[grp[jj] >= 0 ? jj : 0];
                fa.hs[jj] = hsS[src_type[r]];
            }
            int r0 = grp[0], r1 = grp[1], r2 = grp[2];
            if (nrel == 3) {
                k_fagg<3, 4><<<(Nd + 3) / 4, 256, 0, stream>>>(
                    fa, col_all, cb, r0, r1, r2, nxt[dt], Nd);
            } else {
                k_fagg<2, 8><<<(Nd + 3) / 4, 256, 0, stream>>>(
                    fa, col_all, cb, r0, r1, -1, nxt[dt], Nd);
            }
        }
    }
    k_cls<<<NT / 8, 256, 0, stream>>>(A[1], cls_w1, cls_b1, cls_w2, cls_b2, (float*)d_out);
}

// Round 10
// 1432.262 us; speedup vs baseline: 1.4075x; 1.2953x over previous
//
#include <hip/hip_runtime.h>
#include <hip/hip_bf16.h>

#define NU 100000
#define NT 300000
#define NM 10000

typedef __hip_bfloat16 bf16;
typedef __attribute__((ext_vector_type(8))) short bf16x8;
typedef __attribute__((ext_vector_type(4))) float f32x4;

__device__ __forceinline__ float toF(float v) { return v; }
__device__ __forceinline__ float toF(bf16 v)  { return __bfloat162float(v); }
__device__ __forceinline__ float bitsLo(unsigned u) { return __uint_as_float(u << 16); }
__device__ __forceinline__ float bitsHi(unsigned u) { return __uint_as_float(u & 0xffff0000u); }
__device__ __forceinline__ float shortBF(short s) { return __uint_as_float(((unsigned)(unsigned short)s) << 16); }

struct Segs {
    const int* ei[7];
    int eoff[8];
    int noff[8];
};

struct FA {
    const int* rp[3];
    const float* aS[3];
    const float* aD[3];
    const bf16* hs[3];
};

// ================= fused CSR build =================
__global__ void k_zero_i(int* __restrict__ p, int n) {
    int i = blockIdx.x * 256 + threadIdx.x;
    if (i < n) p[i] = 0;
}

__global__ void k_hist_all(Segs s, int TE, int* __restrict__ cnt) {
    int g = blockIdx.x * 256 + threadIdx.x;
    if (g >= TE) return;
    int r = 0;
    while (g >= s.eoff[r + 1]) r++;
    int e = g - s.eoff[r];
    int E = s.eoff[r + 1] - s.eoff[r];
    int d = s.ei[r][E + e];
    atomicAdd(&cnt[s.noff[r] + d], 1);
}

__global__ void k_scan1(const int* __restrict__ cnt, int n, int* __restrict__ bsum) {
    __shared__ int sh[256];
    int i = blockIdx.x * 256 + threadIdx.x;
    sh[threadIdx.x] = (i < n) ? cnt[i] : 0;
    __syncthreads();
    for (int o = 128; o; o >>= 1) {
        if (threadIdx.x < o) sh[threadIdx.x] += sh[threadIdx.x + o];
        __syncthreads();
    }
    if (threadIdx.x == 0) bsum[blockIdx.x] = sh[0];
}

__global__ void k_scan2(int* __restrict__ bsum, int nb) {  // 1 block
    __shared__ int sh[256];
    __shared__ int carry;
    if (threadIdx.x == 0) carry = 0;
    __syncthreads();
    for (int base = 0; base < nb; base += 256) {
        int i = base + threadIdx.x;
        int v = (i < nb) ? bsum[i] : 0;
        sh[threadIdx.x] = v;
        __syncthreads();
        for (int o = 1; o < 256; o <<= 1) {
            int t = (threadIdx.x >= o) ? sh[threadIdx.x - o] : 0;
            __syncthreads();
            sh[threadIdx.x] += t;
            __syncthreads();
        }
        if (i < nb) bsum[i] = carry + sh[threadIdx.x] - v;  // exclusive
        __syncthreads();
        if (threadIdx.x == 255) carry += sh[255];
        __syncthreads();
    }
}

__global__ void k_scan3(const int* __restrict__ cnt, int n, const int* __restrict__ bsum,
                        int* __restrict__ out) {
    __shared__ int sh[256];
    int i = blockIdx.x * 256 + threadIdx.x;
    int v = (i < n) ? cnt[i] : 0;
    sh[threadIdx.x] = v;
    __syncthreads();
    for (int o = 1; o < 256; o <<= 1) {
        int t = (threadIdx.x >= o) ? sh[threadIdx.x - o] : 0;
        __syncthreads();
        sh[threadIdx.x] += t;
        __syncthreads();
    }
    if (i <= n) out[i] = bsum[blockIdx.x] + sh[threadIdx.x] - v;
}

__global__ void k_fill_all(Segs s, int TE, const int* __restrict__ rp_all,
                           int* __restrict__ cnt, int* __restrict__ col) {
    int g = blockIdx.x * 256 + threadIdx.x;
    if (g >= TE) return;
    int r = 0;
    while (g >= s.eoff[r + 1]) r++;
    int e = g - s.eoff[r];
    int E = s.eoff[r + 1] - s.eoff[r];
    int d = s.ei[r][E + e];
    int idx = s.noff[r] + d;
    int pos = rp_all[idx] + atomicAdd(&cnt[idx], 1);
    col[pos] = s.ei[r][e];
}

// ================= weight prep =================
// wa[lr*512 + k*8 + j]; j 0..3 src head j, 4..7 dst head j-4
// wad[lr*256 + k*4 + h] = dst part, compact (for fused cross-aD in k_pmfma)
__global__ void k_wa(const float* __restrict__ lin_w, const float* __restrict__ att_s,
                     const float* __restrict__ att_d, float* __restrict__ wa,
                     float* __restrict__ wad) {
    int i = blockIdx.x * 256 + threadIdx.x;
    if (i >= 2 * 7 * 64 * 8) return;
    int j = i & 7;
    int k = (i >> 3) & 63;
    int lr = i >> 9;
    int h = j & 3;
    const float* a = (j < 4 ? att_s : att_d) + lr * 64 + h * 16;
    const float* Wp = lin_w + (size_t)lr * 4096 + k * 64 + h * 16;
    float s = 0.f;
#pragma unroll
    for (int c = 0; c < 16; c++) s += Wp[c] * a[c];
    wa[i] = s;
    if (j >= 4) wad[lr * 256 + k * 4 + h] = s;
}

// wt: per (l,r): [2][64][64] bf16, transposed (Wt[c][k]), hi + lo split
__global__ void k_wt(const float* __restrict__ lin_w, bf16* __restrict__ wt) {
    int i = blockIdx.x * 256 + threadIdx.x;
    if (i >= 14 * 4096) return;
    int lr = i >> 12;
    int kc = i & 4095;
    int k = kc >> 6, c = kc & 63;
    float v = lin_w[(size_t)lr * 4096 + k * 64 + c];
    bf16 hi = __float2bfloat16(v);
    float rem = v - __bfloat162float(hi);
    wt[(size_t)lr * 8192 + c * 64 + k] = hi;
    wt[(size_t)lr * 8192 + 4096 + c * 64 + k] = __float2bfloat16(rem);
}

// ================= input projection (fp32 VALU, runs once) =================
__global__ void k_proj(const float* __restrict__ x, const float* __restrict__ W,
                       const float* __restrict__ bias, bf16* __restrict__ out,
                       int N, int K) {
    __shared__ float Ws[64 * 64];
    __shared__ float xs[32 * 64];
    int tid = threadIdx.x;
    int r0 = blockIdx.x << 5;
    for (int i = tid; i < K * 64; i += 256) Ws[i] = W[i];
    for (int i = tid; i < 32 * K; i += 256) {
        int row = i / K, col = i - row * K;
        int n = r0 + row;
        xs[(row << 6) + col] = (n < N) ? x[(size_t)n * K + col] : 0.f;
    }
    __syncthreads();
    int c = tid & 63;
    float bv = bias[c];
    for (int rr = tid >> 6; rr < 32; rr += 4) {
        int n = r0 + rr;
        if (n >= N) return;
        float acc = bv;
#pragma unroll 16
        for (int k = 0; k < K; k++) acc = fmaf(xs[(rr << 6) + k], Ws[(k << 6) + c], acc);
        out[(size_t)n * 64 + c] = __float2bfloat16(acc);
    }
}

// ================= MFMA projection + fused alphas (+ optional cross-rel dst alphas) ====
__global__ void k_pmfma(const bf16* __restrict__ x, const bf16* __restrict__ wt,
                        const float* __restrict__ avs_p, const float* __restrict__ avd_p,
                        bf16* __restrict__ hs, float* __restrict__ aS, float* __restrict__ aD,
                        const float4* __restrict__ wadA, float* __restrict__ aDA,
                        const float4* __restrict__ wadB, float* __restrict__ aDB,
                        int N) {
    int w = threadIdx.x >> 6, lane = threadIdx.x & 63;
    int m = lane & 15, kq = lane >> 4;
    int r0 = blockIdx.x * 64 + w * 16;
    bf16x8 a0 = {}, a1 = {};
    int row = r0 + m;
    if (row < N) {
        a0 = *(const bf16x8*)(x + (size_t)row * 64 + kq * 8);
        a1 = *(const bf16x8*)(x + (size_t)row * 64 + 32 + kq * 8);
    }
#pragma unroll
    for (int nt = 0; nt < 4; nt++) {
        const bf16* wb  = wt + (nt * 16 + m) * 64 + kq * 8;
        const bf16* wbl = wb + 4096;
        bf16x8 bh0 = *(const bf16x8*)(wb);
        bf16x8 bh1 = *(const bf16x8*)(wb + 32);
        bf16x8 bl0 = *(const bf16x8*)(wbl);
        bf16x8 bl1 = *(const bf16x8*)(wbl + 32);
        f32x4 acc = {};
        acc = __builtin_amdgcn_mfma_f32_16x16x32_bf16(a0, bh0, acc, 0, 0, 0);
        acc = __builtin_amdgcn_mfma_f32_16x16x32_bf16(a0, bl0, acc, 0, 0, 0);
        acc = __builtin_amdgcn_mfma_f32_16x16x32_bf16(a1, bh1, acc, 0, 0, 0);
        acc = __builtin_amdgcn_mfma_f32_16x16x32_bf16(a1, bl1, acc, 0, 0, 0);
        float avsv = avs_p ? avs_p[nt * 16 + m] : 0.f;
        float avdv = avd_p ? avd_p[nt * 16 + m] : 0.f;
#pragma unroll
        for (int i = 0; i < 4; i++) {
            int rr = r0 + kq * 4 + i;
            if (rr < N) hs[(size_t)rr * 64 + nt * 16 + m] = __float2bfloat16(acc[i]);
            if (avs_p) {
                float ps = acc[i] * avsv;
                ps += __shfl_xor(ps, 1); ps += __shfl_xor(ps, 2);
                ps += __shfl_xor(ps, 4); ps += __shfl_xor(ps, 8);
                if (m == 0 && rr < N) aS[rr * 4 + nt] = ps;
            }
            if (avd_p) {
                float pd = acc[i] * avdv;
                pd += __shfl_xor(pd, 1); pd += __shfl_xor(pd, 2);
                pd += __shfl_xor(pd, 4); pd += __shfl_xor(pd, 8);
                if (m == 0 && rr < N) aD[rr * 4 + nt] = pd;
            }
        }
    }
    // ---- fused cross-relation dst alphas: aD_r[row,h] = sum_k x[row,k] * wad_r[k,h] ----
    if (wadA) {
        float xv[16];
#pragma unroll
        for (int kk = 0; kk < 8; kk++) { xv[kk] = shortBF(a0[kk]); xv[8 + kk] = shortBF(a1[kk]); }
#pragma unroll
        for (int cr = 0; cr < 2; cr++) {
            const float4* wad = (cr == 0) ? wadA : wadB;
            float* aDo = (cr == 0) ? aDA : aDB;
            if (!wad) break;
            float p0 = 0.f, p1 = 0.f, p2 = 0.f, p3 = 0.f;
#pragma unroll
            for (int kk = 0; kk < 8; kk++) {
                float4 w4 = wad[kq * 8 + kk];
                p0 = fmaf(xv[kk], w4.x, p0); p1 = fmaf(xv[kk], w4.y, p1);
                p2 = fmaf(xv[kk], w4.z, p2); p3 = fmaf(xv[kk], w4.w, p3);
                float4 w4b = wad[32 + kq * 8 + kk];
                p0 = fmaf(xv[8 + kk], w4b.x, p0); p1 = fmaf(xv[8 + kk], w4b.y, p1);
                p2 = fmaf(xv[8 + kk], w4b.z, p2); p3 = fmaf(xv[8 + kk], w4b.w, p3);
            }
            p0 += __shfl_xor(p0, 16); p0 += __shfl_xor(p0, 32);
            p1 += __shfl_xor(p1, 16); p1 += __shfl_xor(p1, 32);
            p2 += __shfl_xor(p2, 16); p2 += __shfl_xor(p2, 32);
            p3 += __shfl_xor(p3, 16); p3 += __shfl_xor(p3, 32);
            if (kq == 0 && row < N) {
                float4 o; o.x = p0; o.y = p1; o.z = p2; o.w = p3;
                *(float4*)(aDo + (size_t)row * 4) = o;
            }
        }
    }
}

// ===== fused softmax+aggregation: 2 nodes/wave, 32 lanes/node, 2 ch/lane ==========
// out[n] = relu( bias + sum_r (sum_e ex*hs) / (sum_e ex + eps) ), ex = exp(lrelu(aS+aD))
template <int NREL, int EPR>
__global__ void k_fagg2(FA fa, const int* __restrict__ col, const float* __restrict__ cb,
                        int b0i, int b1i, int b2i, bf16* __restrict__ out, int Nd) {
    int tid = threadIdx.x;
    int wv = tid >> 6, lane = tid & 63;
    int half = lane >> 5, l32 = lane & 31;
    int node = blockIdx.x * 8 + wv * 2 + half;
    bool alive = node < Nd;
    int nc = alive ? node : (Nd - 1);   // clamped for safe loads
    int hcl = l32 >> 3;                  // head of this lane's channel pair
    int beg[NREL], deg[NREL];
    float ad[NREL], dn[NREL], ax[NREL], ay[NREL];
#pragma unroll
    for (int r = 0; r < NREL; r++) {
        beg[r] = fa.rp[r][nc];
        deg[r] = fa.rp[r][nc + 1] - beg[r];
    }
#pragma unroll
    for (int r = 0; r < NREL; r++) {
        ad[r] = fa.aD[r][nc * 4 + hcl];
        dn[r] = 0.f; ax[r] = 0.f; ay[r] = 0.f;
    }
    // ---- first chunk: all relations' loads issued together ----
    {
        int cv[NREL][EPR];
#pragma unroll
        for (int r = 0; r < NREL; r++)
#pragma unroll
            for (int j = 0; j < EPR; j++) cv[r][j] = (j < deg[r]) ? col[beg[r] + j] : 0;
        float as[NREL][EPR];
#pragma unroll
        for (int r = 0; r < NREL; r++)
#pragma unroll
            for (int j = 0; j < EPR; j++) as[r][j] = (j < deg[r]) ? fa.aS[r][cv[r][j] * 4 + hcl] : 0.f;
        unsigned hv[NREL][EPR];
#pragma unroll
        for (int r = 0; r < NREL; r++)
#pragma unroll
            for (int j = 0; j < EPR; j++)
                hv[r][j] = (j < deg[r]) ? *(const unsigned*)(fa.hs[r] + (size_t)cv[r][j] * 64 + 2 * l32) : 0u;
#pragma unroll
        for (int r = 0; r < NREL; r++)
#pragma unroll
            for (int j = 0; j < EPR; j++) if (j < deg[r]) {
                float a = as[r][j] + ad[r];
                a = (a >= 0.f) ? a : 0.2f * a;
                float ex = __expf(a);
                dn[r] += ex;
                ax[r] = fmaf(ex, bitsLo(hv[r][j]), ax[r]);
                ay[r] = fmaf(ex, bitsHi(hv[r][j]), ay[r]);
            }
    }
    // ---- remainders (deg > EPR), chunked issue-all per relation ----
#pragma unroll
    for (int r = 0; r < NREL; r++) {
        int e = beg[r] + deg[r];
        for (int i0 = beg[r] + EPR; i0 < e; i0 += EPR) {
            int mrem = e - i0;
            int cw[EPR];
#pragma unroll
            for (int j = 0; j < EPR; j++) cw[j] = (j < mrem) ? col[i0 + j] : 0;
            float aw[EPR];
#pragma unroll
            for (int j = 0; j < EPR; j++) aw[j] = (j < mrem) ? fa.aS[r][cw[j] * 4 + hcl] : 0.f;
            unsigned hw[EPR];
#pragma unroll
            for (int j = 0; j < EPR; j++)
                hw[j] = (j < mrem) ? *(const unsigned*)(fa.hs[r] + (size_t)cw[j] * 64 + 2 * l32) : 0u;
#pragma unroll
            for (int j = 0; j < EPR; j++) if (j < mrem) {
                float a = aw[j] + ad[r];
                a = (a >= 0.f) ? a : 0.2f * a;
                float ex = __expf(a);
                dn[r] += ex;
                ax[r] = fmaf(ex, bitsLo(hw[j]), ax[r]);
                ay[r] = fmaf(ex, bitsHi(hw[j]), ay[r]);
            }
        }
    }
    // ---- epilogue ----
    float2 bb = *(const float2*)(cb + b0i * 64 + 2 * l32);
    float ox = bb.x, oy = bb.y;
    if (b1i >= 0) { float2 t = *(const float2*)(cb + b1i * 64 + 2 * l32); ox += t.x; oy += t.y; }
    if (b2i >= 0) { float2 t = *(const float2*)(cb + b2i * 64 + 2 * l32); ox += t.x; oy += t.y; }
#pragma unroll
    for (int r = 0; r < NREL; r++) {
        float rd = 1.f / (dn[r] + 1e-16f);
        ox = fmaf(ax[r], rd, ox);
        oy = fmaf(ay[r], rd, oy);
    }
    ox = ox > 0.f ? ox : 0.f;
    oy = oy > 0.f ? oy : 0.f;
    if (alive) {
        bf16 p0 = __float2bfloat16(ox), p1 = __float2bfloat16(oy);
        unsigned pk = ((unsigned)(*(unsigned short*)&p1) << 16) | (unsigned)(*(unsigned short*)&p0);
        ((unsigned*)out)[(size_t)node * 32 + l32] = pk;
    }
}

// ================= classifier =================
__global__ void k_cls(const bf16* __restrict__ t, const float* __restrict__ w1,
                      const float* __restrict__ b1, const float* __restrict__ w2,
                      const float* __restrict__ b2, float* __restrict__ out) {
    __shared__ float w1s[64 * 32];
    __shared__ float w2s[64];
    __shared__ float b1s[32];
    __shared__ float b2s[2];
    __shared__ float ts[8 * 64];
    int tid = threadIdx.x;
    for (int i = tid; i < 2048; i += 256) w1s[i] = w1[i];
    if (tid < 64) w2s[tid] = w2[tid];
    if (tid < 32) b1s[tid] = b1[tid];
    if (tid < 2) b2s[tid] = b2[tid];
    int n0 = blockIdx.x << 3;
    for (int i = tid; i < 512; i += 256) {
        int row = i >> 6, col = i & 63;
        ts[i] = toF(t[(size_t)(n0 + row) * 64 + col]);
    }
    __syncthreads();
    int lane = tid & 31;
    int row = tid >> 5;
    float h = b1s[lane];
#pragma unroll 8
    for (int k = 0; k < 64; k++) h = fmaf(ts[(row << 6) + k], w1s[(k << 5) + lane], h);
    h = h > 0.f ? h : 0.f;
    float o0 = h * w2s[lane * 2 + 0];
    float o1 = h * w2s[lane * 2 + 1];
#pragma unroll
    for (int off = 16; off; off >>= 1) {
        o0 += __shfl_down(o0, off, 32);
        o1 += __shfl_down(o1, off, 32);
    }
    if (lane == 0) {
        int n = n0 + row;
        out[(size_t)n * 2 + 0] = o0 + b2s[0];
        out[(size_t)n * 2 + 1] = o1 + b2s[1];
    }
}

extern "C" void kernel_launch(void* const* d_in, const int* in_sizes, int n_in,
                              void* d_out, int out_size, void* d_ws, size_t ws_size,
                              hipStream_t stream) {
    (void)n_in; (void)out_size;
    const float* x_user  = (const float*)d_in[0];
    const float* x_tx    = (const float*)d_in[1];
    const float* x_merch = (const float*)d_in[2];
    const int* ei[7];
    int E[7];
    for (int r = 0; r < 7; r++) { ei[r] = (const int*)d_in[3 + r]; E[r] = in_sizes[3 + r] / 2; }
    const float* Win_user  = (const float*)d_in[10];
    const float* bin_user  = (const float*)d_in[11];
    const float* Win_tx    = (const float*)d_in[12];
    const float* bin_tx    = (const float*)d_in[13];
    const float* Win_merch = (const float*)d_in[14];
    const float* bin_merch = (const float*)d_in[15];
    const float* lin_w     = (const float*)d_in[16];
    const float* att_src   = (const float*)d_in[17];
    const float* att_dst   = (const float*)d_in[18];
    const float* conv_bias = (const float*)d_in[19];
    const float* cls_w1    = (const float*)d_in[20];
    const float* cls_b1    = (const float*)d_in[21];
    const float* cls_w2    = (const float*)d_in[22];
    const float* cls_b2    = (const float*)d_in[23];

    const int src_type[7] = {0, 1, 2, 1, 0, 2, 1};
    const int dst_type[7] = {1, 0, 1, 2, 0, 2, 1};
    const int N_of[3] = {NU, NT, NM};

    // segment offsets
    Segs segs;
    int TE = 0, TN = 0;
    for (int r = 0; r < 7; r++) {
        segs.ei[r] = ei[r];
        segs.eoff[r] = TE; TE += E[r];
        segs.noff[r] = TN; TN += N_of[dst_type[r]];
    }
    segs.eoff[7] = TE;
    segs.noff[7] = TN;

    // ---- workspace layout ----
    size_t off = 0;
    auto alloc = [&](size_t bytes) { size_t q = off; off += (bytes + 255) & ~(size_t)255; return q; };
    size_t o_a[3], o_b[3], o_hs[3], o_aS[3];
    for (int tpe = 0; tpe < 3; tpe++) o_a[tpe]  = alloc((size_t)N_of[tpe] * 64 * 2);
    for (int tpe = 0; tpe < 3; tpe++) o_b[tpe]  = alloc((size_t)N_of[tpe] * 64 * 2);
    for (int tpe = 0; tpe < 3; tpe++) o_hs[tpe] = alloc((size_t)N_of[tpe] * 64 * 2);
    for (int tpe = 0; tpe < 3; tpe++) o_aS[tpe] = alloc((size_t)N_of[tpe] * 4 * 4);
    size_t o_aD[3];
    for (int jj = 0; jj < 3; jj++) o_aD[jj] = alloc((size_t)NT * 4 * 4);
    size_t o_rp   = alloc(((size_t)TN + 1) * 4);
    size_t o_col  = alloc((size_t)TE * 4);
    size_t o_cnt  = alloc((size_t)TN * 4);
    size_t o_bsum = alloc((size_t)8192 * 4);
    size_t o_wa   = alloc((size_t)2 * 7 * 64 * 8 * 4);
    size_t o_wad  = alloc((size_t)14 * 256 * 4);
    size_t o_wt   = alloc((size_t)14 * 8192 * 2);
    if (off > ws_size) return;  // fail cleanly (absmax will read ~0.31)

    char* base = (char*)d_ws;
    bf16* A[3], *B[3], *hsS[3];
    float* aSS[3];
    for (int tpe = 0; tpe < 3; tpe++) {
        A[tpe] = (bf16*)(base + o_a[tpe]);
        B[tpe] = (bf16*)(base + o_b[tpe]);
        hsS[tpe] = (bf16*)(base + o_hs[tpe]);
        aSS[tpe] = (float*)(base + o_aS[tpe]);
    }
    float* aDS[3];
    for (int jj = 0; jj < 3; jj++) aDS[jj] = (float*)(base + o_aD[jj]);
    int* rp_all   = (int*)(base + o_rp);
    int* col_all  = (int*)(base + o_col);
    int* cnt      = (int*)(base + o_cnt);
    int* bsum     = (int*)(base + o_bsum);
    float* wa     = (float*)(base + o_wa);
    float* wad    = (float*)(base + o_wad);
    bf16* wt      = (bf16*)(base + o_wt);

    // ---- fused CSR build over all 7 relations ----
    int nb = (TN + 256) / 256;  // covers TN+1 scan outputs
    k_zero_i<<<(TN + 255) / 256, 256, 0, stream>>>(cnt, TN);
    k_hist_all<<<(TE + 255) / 256, 256, 0, stream>>>(segs, TE, cnt);
    k_scan1<<<nb, 256, 0, stream>>>(cnt, TN, bsum);
    k_scan2<<<1, 256, 0, stream>>>(bsum, nb);
    k_scan3<<<nb, 256, 0, stream>>>(cnt, TN, bsum, rp_all);
    k_zero_i<<<(TN + 255) / 256, 256, 0, stream>>>(cnt, TN);
    k_fill_all<<<(TE + 255) / 256, 256, 0, stream>>>(segs, TE, rp_all, cnt, col_all);

    k_wa<<<(7168 + 255) / 256, 256, 0, stream>>>(lin_w, att_src, att_dst, wa, wad);
    k_wt<<<(14 * 4096 + 255) / 256, 256, 0, stream>>>(lin_w, wt);
    k_proj<<<(NU + 31) / 32, 256, 0, stream>>>(x_user, Win_user, bin_user, A[0], NU, 32);
    k_proj<<<(NT + 31) / 32, 256, 0, stream>>>(x_tx, Win_tx, bin_tx, A[1], NT, 64);
    k_proj<<<(NM + 31) / 32, 256, 0, stream>>>(x_merch, Win_merch, bin_merch, A[2], NM, 16);

    const int grp_dst[3]     = {1, 0, 2};
    const int grp_rels[3][3] = {{0, 2, 6}, {1, 4, -1}, {3, 5, -1}};

    for (int l = 0; l < 2; l++) {
        bf16** cur = (l == 0) ? A : B;
        bf16** nxt = (l == 0) ? B : A;
        const float* cb = conv_bias + (size_t)l * 7 * 64;
        for (int g = 0; g < 3; g++) {
            int dt = grp_dst[g];
            int Nd = N_of[dt];
            const int* grp = grp_rels[g];
            int nrel = (grp[2] >= 0) ? 3 : 2;
            // projections: cross relations first (collect their dst-alpha GEMVs),
            // self relation last (fused cross dst-alphas ride on it)
            const float4* crossWad[2] = {nullptr, nullptr};
            float* crossAD[2] = {nullptr, nullptr};
            int ncross = 0;
            for (int jj = 0; jj < nrel; jj++) {
                int r = grp[jj];
                int st = src_type[r];
                int lr = l * 7 + r;
                const bf16* wtp  = wt + (size_t)lr * 8192;
                const float* avs = att_src + (size_t)lr * 64;
                const float* avd = att_dst + (size_t)lr * 64;
                if (st == dt) {
                    k_pmfma<<<(N_of[st] + 63) / 64, 256, 0, stream>>>(
                        cur[st], wtp, avs, avd, hsS[st], aSS[st], aDS[jj],
                        crossWad[0], crossAD[0], crossWad[1], crossAD[1], N_of[st]);
                } else {
                    k_pmfma<<<(N_of[st] + 63) / 64, 256, 0, stream>>>(
                        cur[st], wtp, avs, nullptr, hsS[st], aSS[st], nullptr,
                        nullptr, nullptr, nullptr, nullptr, N_of[st]);
                    crossWad[ncross] = (const float4*)(wad + (size_t)lr * 256);
                    crossAD[ncross] = aDS[jj];
                    ncross++;
                }
            }
            // fused softmax + aggregation
            FA fa;
            for (int jj = 0; jj < 3; jj++) {
                int r = grp[jj] >= 0 ? grp[jj] : grp[0];
                fa.rp[jj] = rp_all + segs.noff[r];
                fa.aS[jj] = aSS[src_type[r]];
                fa.aD[jj] = aDS[grp[jj] >= 0 ? jj : 0];
                fa.hs[jj] = hsS[src_type[r]];
            }
            int r0 = grp[0], r1 = grp[1], r2 = grp[2];
            if (nrel == 3) {
                k_fagg2<3, 4><<<(Nd + 7) / 8, 256, 0, stream>>>(
                    fa, col_all, cb, r0, r1, r2, nxt[dt], Nd);
            } else {
                k_fagg2<2, 8><<<(Nd + 7) / 8, 256, 0, stream>>>(
                    fa, col_all, cb, r0, r1, -1, nxt[dt], Nd);
            }
        }
    }
    k_cls<<<NT / 8, 256, 0, stream>>>(A[1], cls_w1, cls_b1, cls_w2, cls_b2, (float*)d_out);
}

// Round 11
// 1372.150 us; speedup vs baseline: 1.4691x; 1.0438x over previous
//
#include <hip/hip_runtime.h>
#include <hip/hip_bf16.h>

#define NU 100000
#define NT 300000
#define NM 10000

typedef __hip_bfloat16 bf16;
typedef __attribute__((ext_vector_type(8))) short bf16x8;
typedef __attribute__((ext_vector_type(4))) float f32x4;

__device__ __forceinline__ float toF(float v) { return v; }
__device__ __forceinline__ float toF(bf16 v)  { return __bfloat162float(v); }
__device__ __forceinline__ float bitsLo(unsigned u) { return __uint_as_float(u << 16); }
__device__ __forceinline__ float bitsHi(unsigned u) { return __uint_as_float(u & 0xffff0000u); }
__device__ __forceinline__ float shortBF(short s) { return __uint_as_float(((unsigned)(unsigned short)s) << 16); }
__device__ __forceinline__ short bfBits(float v) { bf16 b = __float2bfloat16(v); return *(short*)&b; }

struct Segs {
    const int* ei[7];
    int eoff[8];
    int noff[8];
};

struct FA {
    const int* rp[3];
    const float* aS[3];
    const float* aD[3];
    const bf16* hs[3];
};

// ================= fused CSR build =================
__global__ void k_zero_i(int* __restrict__ p, int n) {
    int i = blockIdx.x * 256 + threadIdx.x;
    if (i < n) p[i] = 0;
}

__global__ void k_hist_all(Segs s, int TE, int* __restrict__ cnt) {
    int g = blockIdx.x * 256 + threadIdx.x;
    if (g >= TE) return;
    int r = 0;
    while (g >= s.eoff[r + 1]) r++;
    int e = g - s.eoff[r];
    int E = s.eoff[r + 1] - s.eoff[r];
    int d = s.ei[r][E + e];
    atomicAdd(&cnt[s.noff[r] + d], 1);
}

__global__ void k_scan1(const int* __restrict__ cnt, int n, int* __restrict__ bsum) {
    __shared__ int sh[256];
    int i = blockIdx.x * 256 + threadIdx.x;
    sh[threadIdx.x] = (i < n) ? cnt[i] : 0;
    __syncthreads();
    for (int o = 128; o; o >>= 1) {
        if (threadIdx.x < o) sh[threadIdx.x] += sh[threadIdx.x + o];
        __syncthreads();
    }
    if (threadIdx.x == 0) bsum[blockIdx.x] = sh[0];
}

__global__ void k_scan2(int* __restrict__ bsum, int nb) {  // 1 block
    __shared__ int sh[256];
    __shared__ int carry;
    if (threadIdx.x == 0) carry = 0;
    __syncthreads();
    for (int base = 0; base < nb; base += 256) {
        int i = base + threadIdx.x;
        int v = (i < nb) ? bsum[i] : 0;
        sh[threadIdx.x] = v;
        __syncthreads();
        for (int o = 1; o < 256; o <<= 1) {
            int t = (threadIdx.x >= o) ? sh[threadIdx.x - o] : 0;
            __syncthreads();
            sh[threadIdx.x] += t;
            __syncthreads();
        }
        if (i < nb) bsum[i] = carry + sh[threadIdx.x] - v;  // exclusive
        __syncthreads();
        if (threadIdx.x == 255) carry += sh[255];
        __syncthreads();
    }
}

__global__ void k_scan3(const int* __restrict__ cnt, int n, const int* __restrict__ bsum,
                        int* __restrict__ out) {
    __shared__ int sh[256];
    int i = blockIdx.x * 256 + threadIdx.x;
    int v = (i < n) ? cnt[i] : 0;
    sh[threadIdx.x] = v;
    __syncthreads();
    for (int o = 1; o < 256; o <<= 1) {
        int t = (threadIdx.x >= o) ? sh[threadIdx.x - o] : 0;
        __syncthreads();
        sh[threadIdx.x] += t;
        __syncthreads();
    }
    if (i <= n) out[i] = bsum[blockIdx.x] + sh[threadIdx.x] - v;
}

__global__ void k_fill_all(Segs s, int TE, const int* __restrict__ rp_all,
                           int* __restrict__ cnt, int* __restrict__ col) {
    int g = blockIdx.x * 256 + threadIdx.x;
    if (g >= TE) return;
    int r = 0;
    while (g >= s.eoff[r + 1]) r++;
    int e = g - s.eoff[r];
    int E = s.eoff[r + 1] - s.eoff[r];
    int d = s.ei[r][E + e];
    int idx = s.noff[r] + d;
    int pos = rp_all[idx] + atomicAdd(&cnt[idx], 1);
    col[pos] = s.ei[r][e];
}

// ================= weight prep =================
// wa[lr*512 + k*8 + j]; j 0..3 src head j, 4..7 dst head j-4
// wad[lr*256 + k*4 + h] = dst part, compact (for fused cross-aD in k_pmfma)
__global__ void k_wa(const float* __restrict__ lin_w, const float* __restrict__ att_s,
                     const float* __restrict__ att_d, float* __restrict__ wa,
                     float* __restrict__ wad) {
    int i = blockIdx.x * 256 + threadIdx.x;
    if (i >= 2 * 7 * 64 * 8) return;
    int j = i & 7;
    int k = (i >> 3) & 63;
    int lr = i >> 9;
    int h = j & 3;
    const float* a = (j < 4 ? att_s : att_d) + lr * 64 + h * 16;
    const float* Wp = lin_w + (size_t)lr * 4096 + k * 64 + h * 16;
    float s = 0.f;
#pragma unroll
    for (int c = 0; c < 16; c++) s += Wp[c] * a[c];
    wa[i] = s;
    if (j >= 4) wad[lr * 256 + k * 4 + h] = s;
}

// wt: per (l,r): [2][64][64] bf16, transposed (Wt[c][k]), hi + lo split
__global__ void k_wt(const float* __restrict__ lin_w, bf16* __restrict__ wt) {
    int i = blockIdx.x * 256 + threadIdx.x;
    if (i >= 14 * 4096) return;
    int lr = i >> 12;
    int kc = i & 4095;
    int k = kc >> 6, c = kc & 63;
    float v = lin_w[(size_t)lr * 4096 + k * 64 + c];
    bf16 hi = __float2bfloat16(v);
    float rem = v - __bfloat162float(hi);
    wt[(size_t)lr * 8192 + c * 64 + k] = hi;
    wt[(size_t)lr * 8192 + 4096 + c * 64 + k] = __float2bfloat16(rem);
}

// input-proj weights: u(K=32,KP=32)@0, t(K=64,KP=64)@4096, m(K=16,KP=32)@12288
// layout per seg: hi [64][KP], lo [64][KP] (transposed: [c][k])
__global__ void k_wtin(const float* __restrict__ Wu, const float* __restrict__ Wt,
                       const float* __restrict__ Wm, bf16* __restrict__ out) {
    int i = blockIdx.x * 256 + threadIdx.x;
    if (i >= 8192) return;
    const float* W; int K, KP, base, j;
    if (i < 2048)      { W = Wu; K = 32; KP = 32; base = 0;     j = i; }
    else if (i < 6144) { W = Wt; K = 64; KP = 64; base = 4096;  j = i - 2048; }
    else               { W = Wm; K = 16; KP = 32; base = 12288; j = i - 6144; }
    int c = j / KP, k = j - c * KP;
    float v = (k < K) ? W[k * 64 + c] : 0.f;
    bf16 hb = __float2bfloat16(v);
    float rem = v - __bfloat162float(hb);
    out[base + c * KP + k] = hb;
    out[base + 64 * KP + c * KP + k] = __float2bfloat16(rem);
}

// ================= MFMA input projection (fp32 in, hi/lo split in-kernel) ==========
template <int K>
__global__ void k_projm(const float* __restrict__ x, const bf16* __restrict__ wt,
                        const float* __restrict__ bias, bf16* __restrict__ out, int N) {
    constexpr int KP = (K > 32) ? 64 : 32;
    int w = threadIdx.x >> 6, lane = threadIdx.x & 63;
    int m = lane & 15, kq = lane >> 4;
    int r0 = blockIdx.x * 64 + w * 16;
    int row = r0 + m;
    bf16x8 ah0 = {}, al0 = {}, ah1 = {}, al1 = {};
    if (row < N) {
#pragma unroll
        for (int j = 0; j < 8; j++) {
            int k = kq * 8 + j;
            float v = (k < K) ? x[(size_t)row * K + k] : 0.f;
            short hb = bfBits(v);
            ah0[j] = hb;
            al0[j] = bfBits(v - shortBF(hb));
        }
        if (KP == 64) {
#pragma unroll
            for (int j = 0; j < 8; j++) {
                float v = x[(size_t)row * K + 32 + kq * 8 + j];
                short hb = bfBits(v);
                ah1[j] = hb;
                al1[j] = bfBits(v - shortBF(hb));
            }
        }
    }
#pragma unroll
    for (int nt = 0; nt < 4; nt++) {
        int c = nt * 16 + m;
        f32x4 acc = {};
        const bf16* bh = wt + c * KP + kq * 8;
        const bf16* bl = wt + 64 * KP + c * KP + kq * 8;
        bf16x8 bh0 = *(const bf16x8*)(bh);
        bf16x8 bl0 = *(const bf16x8*)(bl);
        acc = __builtin_amdgcn_mfma_f32_16x16x32_bf16(ah0, bh0, acc, 0, 0, 0);
        acc = __builtin_amdgcn_mfma_f32_16x16x32_bf16(al0, bh0, acc, 0, 0, 0);
        acc = __builtin_amdgcn_mfma_f32_16x16x32_bf16(ah0, bl0, acc, 0, 0, 0);
        if (KP == 64) {
            bf16x8 bh1 = *(const bf16x8*)(bh + 32);
            bf16x8 bl1 = *(const bf16x8*)(bl + 32);
            acc = __builtin_amdgcn_mfma_f32_16x16x32_bf16(ah1, bh1, acc, 0, 0, 0);
            acc = __builtin_amdgcn_mfma_f32_16x16x32_bf16(al1, bh1, acc, 0, 0, 0);
            acc = __builtin_amdgcn_mfma_f32_16x16x32_bf16(ah1, bl1, acc, 0, 0, 0);
        }
        float bv = bias[c];
#pragma unroll
        for (int i = 0; i < 4; i++) {
            int rr = r0 + kq * 4 + i;
            if (rr < N) out[(size_t)rr * 64 + c] = __float2bfloat16(acc[i] + bv);
        }
    }
}

// ================= MFMA projection + fused alphas (+ optional cross-rel dst alphas) ====
__global__ void k_pmfma(const bf16* __restrict__ x, const bf16* __restrict__ wt,
                        const float* __restrict__ avs_p, const float* __restrict__ avd_p,
                        bf16* __restrict__ hs, float* __restrict__ aS, float* __restrict__ aD,
                        const float4* __restrict__ wadA, float* __restrict__ aDA,
                        const float4* __restrict__ wadB, float* __restrict__ aDB,
                        int N) {
    int w = threadIdx.x >> 6, lane = threadIdx.x & 63;
    int m = lane & 15, kq = lane >> 4;
    int r0 = blockIdx.x * 64 + w * 16;
    bf16x8 a0 = {}, a1 = {};
    int row = r0 + m;
    if (row < N) {
        a0 = *(const bf16x8*)(x + (size_t)row * 64 + kq * 8);
        a1 = *(const bf16x8*)(x + (size_t)row * 64 + 32 + kq * 8);
    }
#pragma unroll
    for (int nt = 0; nt < 4; nt++) {
        const bf16* wb  = wt + (nt * 16 + m) * 64 + kq * 8;
        const bf16* wbl = wb + 4096;
        bf16x8 bh0 = *(const bf16x8*)(wb);
        bf16x8 bh1 = *(const bf16x8*)(wb + 32);
        bf16x8 bl0 = *(const bf16x8*)(wbl);
        bf16x8 bl1 = *(const bf16x8*)(wbl + 32);
        f32x4 acc = {};
        acc = __builtin_amdgcn_mfma_f32_16x16x32_bf16(a0, bh0, acc, 0, 0, 0);
        acc = __builtin_amdgcn_mfma_f32_16x16x32_bf16(a0, bl0, acc, 0, 0, 0);
        acc = __builtin_amdgcn_mfma_f32_16x16x32_bf16(a1, bh1, acc, 0, 0, 0);
        acc = __builtin_amdgcn_mfma_f32_16x16x32_bf16(a1, bl1, acc, 0, 0, 0);
        float avsv = avs_p ? avs_p[nt * 16 + m] : 0.f;
        float avdv = avd_p ? avd_p[nt * 16 + m] : 0.f;
#pragma unroll
        for (int i = 0; i < 4; i++) {
            int rr = r0 + kq * 4 + i;
            if (rr < N) hs[(size_t)rr * 64 + nt * 16 + m] = __float2bfloat16(acc[i]);
            if (avs_p) {
                float ps = acc[i] * avsv;
                ps += __shfl_xor(ps, 1); ps += __shfl_xor(ps, 2);
                ps += __shfl_xor(ps, 4); ps += __shfl_xor(ps, 8);
                if (m == 0 && rr < N) aS[rr * 4 + nt] = ps;
            }
            if (avd_p) {
                float pd = acc[i] * avdv;
                pd += __shfl_xor(pd, 1); pd += __shfl_xor(pd, 2);
                pd += __shfl_xor(pd, 4); pd += __shfl_xor(pd, 8);
                if (m == 0 && rr < N) aD[rr * 4 + nt] = pd;
            }
        }
    }
    // ---- fused cross-relation dst alphas: aD_r[row,h] = sum_k x[row,k] * wad_r[k,h] ----
    if (wadA) {
        float xv[16];
#pragma unroll
        for (int kk = 0; kk < 8; kk++) { xv[kk] = shortBF(a0[kk]); xv[8 + kk] = shortBF(a1[kk]); }
#pragma unroll
        for (int cr = 0; cr < 2; cr++) {
            const float4* wad = (cr == 0) ? wadA : wadB;
            float* aDo = (cr == 0) ? aDA : aDB;
            if (!wad) break;
            float p0 = 0.f, p1 = 0.f, p2 = 0.f, p3 = 0.f;
#pragma unroll
            for (int kk = 0; kk < 8; kk++) {
                float4 w4 = wad[kq * 8 + kk];
                p0 = fmaf(xv[kk], w4.x, p0); p1 = fmaf(xv[kk], w4.y, p1);
                p2 = fmaf(xv[kk], w4.z, p2); p3 = fmaf(xv[kk], w4.w, p3);
                float4 w4b = wad[32 + kq * 8 + kk];
                p0 = fmaf(xv[8 + kk], w4b.x, p0); p1 = fmaf(xv[8 + kk], w4b.y, p1);
                p2 = fmaf(xv[8 + kk], w4b.z, p2); p3 = fmaf(xv[8 + kk], w4b.w, p3);
            }
            p0 += __shfl_xor(p0, 16); p0 += __shfl_xor(p0, 32);
            p1 += __shfl_xor(p1, 16); p1 += __shfl_xor(p1, 32);
            p2 += __shfl_xor(p2, 16); p2 += __shfl_xor(p2, 32);
            p3 += __shfl_xor(p3, 16); p3 += __shfl_xor(p3, 32);
            if (kq == 0 && row < N) {
                float4 o; o.x = p0; o.y = p1; o.z = p2; o.w = p3;
                *(float4*)(aDo + (size_t)row * 4) = o;
            }
        }
    }
}

// ===== fused softmax+aggregation: 2 nodes/wave, 32 lanes/node, 2 ch/lane ==========
// out[n] = relu( bias + sum_r (sum_e ex*hs) / (sum_e ex + eps) ), ex = exp(lrelu(aS+aD))
template <int NREL, int EPR>
__global__ void k_fagg2(FA fa, const int* __restrict__ col, const float* __restrict__ cb,
                        int b0i, int b1i, int b2i, bf16* __restrict__ out, int Nd) {
    int tid = threadIdx.x;
    int wv = tid >> 6, lane = tid & 63;
    int half = lane >> 5, l32 = lane & 31;
    int node = blockIdx.x * 8 + wv * 2 + half;
    bool alive = node < Nd;
    int nc = alive ? node : (Nd - 1);   // clamped for safe loads
    int hcl = l32 >> 3;                  // head of this lane's channel pair
    int beg[NREL], deg[NREL];
    float ad[NREL], dn[NREL], ax[NREL], ay[NREL];
#pragma unroll
    for (int r = 0; r < NREL; r++) {
        beg[r] = fa.rp[r][nc];
        deg[r] = fa.rp[r][nc + 1] - beg[r];
    }
#pragma unroll
    for (int r = 0; r < NREL; r++) {
        ad[r] = fa.aD[r][nc * 4 + hcl];
        dn[r] = 0.f; ax[r] = 0.f; ay[r] = 0.f;
    }
    // ---- first chunk: all relations' loads issued together ----
    {
        int cv[NREL][EPR];
#pragma unroll
        for (int r = 0; r < NREL; r++)
#pragma unroll
            for (int j = 0; j < EPR; j++) cv[r][j] = (j < deg[r]) ? col[beg[r] + j] : 0;
        float as[NREL][EPR];
#pragma unroll
        for (int r = 0; r < NREL; r++)
#pragma unroll
            for (int j = 0; j < EPR; j++) as[r][j] = (j < deg[r]) ? fa.aS[r][cv[r][j] * 4 + hcl] : 0.f;
        unsigned hv[NREL][EPR];
#pragma unroll
        for (int r = 0; r < NREL; r++)
#pragma unroll
            for (int j = 0; j < EPR; j++)
                hv[r][j] = (j < deg[r]) ? *(const unsigned*)(fa.hs[r] + (size_t)cv[r][j] * 64 + 2 * l32) : 0u;
#pragma unroll
        for (int r = 0; r < NREL; r++)
#pragma unroll
            for (int j = 0; j < EPR; j++) if (j < deg[r]) {
                float a = as[r][j] + ad[r];
                a = (a >= 0.f) ? a : 0.2f * a;
                float ex = __expf(a);
                dn[r] += ex;
                ax[r] = fmaf(ex, bitsLo(hv[r][j]), ax[r]);
                ay[r] = fmaf(ex, bitsHi(hv[r][j]), ay[r]);
            }
    }
    // ---- remainders (deg > EPR), chunked issue-all per relation ----
#pragma unroll
    for (int r = 0; r < NREL; r++) {
        int e = beg[r] + deg[r];
        for (int i0 = beg[r] + EPR; i0 < e; i0 += EPR) {
            int mrem = e - i0;
            int cw[EPR];
#pragma unroll
            for (int j = 0; j < EPR; j++) cw[j] = (j < mrem) ? col[i0 + j] : 0;
            float aw[EPR];
#pragma unroll
            for (int j = 0; j < EPR; j++) aw[j] = (j < mrem) ? fa.aS[r][cw[j] * 4 + hcl] : 0.f;
            unsigned hw[EPR];
#pragma unroll
            for (int j = 0; j < EPR; j++)
                hw[j] = (j < mrem) ? *(const unsigned*)(fa.hs[r] + (size_t)cw[j] * 64 + 2 * l32) : 0u;
#pragma unroll
            for (int j = 0; j < EPR; j++) if (j < mrem) {
                float a = aw[j] + ad[r];
                a = (a >= 0.f) ? a : 0.2f * a;
                float ex = __expf(a);
                dn[r] += ex;
                ax[r] = fmaf(ex, bitsLo(hw[j]), ax[r]);
                ay[r] = fmaf(ex, bitsHi(hw[j]), ay[r]);
            }
        }
    }
    // ---- epilogue ----
    float2 bb = *(const float2*)(cb + b0i * 64 + 2 * l32);
    float ox = bb.x, oy = bb.y;
    if (b1i >= 0) { float2 t = *(const float2*)(cb + b1i * 64 + 2 * l32); ox += t.x; oy += t.y; }
    if (b2i >= 0) { float2 t = *(const float2*)(cb + b2i * 64 + 2 * l32); ox += t.x; oy += t.y; }
#pragma unroll
    for (int r = 0; r < NREL; r++) {
        float rd = 1.f / (dn[r] + 1e-16f);
        ox = fmaf(ax[r], rd, ox);
        oy = fmaf(ay[r], rd, oy);
    }
    ox = ox > 0.f ? ox : 0.f;
    oy = oy > 0.f ? oy : 0.f;
    if (alive) {
        bf16 p0 = __float2bfloat16(ox), p1 = __float2bfloat16(oy);
        unsigned pk = ((unsigned)(*(unsigned short*)&p1) << 16) | (unsigned)(*(unsigned short*)&p0);
        ((unsigned*)out)[(size_t)node * 32 + l32] = pk;
    }
}

// ================= classifier =================
__global__ void k_cls(const bf16* __restrict__ t, const float* __restrict__ w1,
                      const float* __restrict__ b1, const float* __restrict__ w2,
                      const float* __restrict__ b2, float* __restrict__ out) {
    __shared__ float w1s[64 * 32];
    __shared__ float w2s[64];
    __shared__ float b1s[32];
    __shared__ float b2s[2];
    __shared__ float ts[8 * 64];
    int tid = threadIdx.x;
    for (int i = tid; i < 2048; i += 256) w1s[i] = w1[i];
    if (tid < 64) w2s[tid] = w2[tid];
    if (tid < 32) b1s[tid] = b1[tid];
    if (tid < 2) b2s[tid] = b2[tid];
    int n0 = blockIdx.x << 3;
    for (int i = tid; i < 512; i += 256) {
        int row = i >> 6, col = i & 63;
        ts[i] = toF(t[(size_t)(n0 + row) * 64 + col]);
    }
    __syncthreads();
    int lane = tid & 31;
    int row = tid >> 5;
    float h = b1s[lane];
#pragma unroll 8
    for (int k = 0; k < 64; k++) h = fmaf(ts[(row << 6) + k], w1s[(k << 5) + lane], h);
    h = h > 0.f ? h : 0.f;
    float o0 = h * w2s[lane * 2 + 0];
    float o1 = h * w2s[lane * 2 + 1];
#pragma unroll
    for (int off = 16; off; off >>= 1) {
        o0 += __shfl_down(o0, off, 32);
        o1 += __shfl_down(o1, off, 32);
    }
    if (lane == 0) {
        int n = n0 + row;
        out[(size_t)n * 2 + 0] = o0 + b2s[0];
        out[(size_t)n * 2 + 1] = o1 + b2s[1];
    }
}

extern "C" void kernel_launch(void* const* d_in, const int* in_sizes, int n_in,
                              void* d_out, int out_size, void* d_ws, size_t ws_size,
                              hipStream_t stream) {
    (void)n_in; (void)out_size;
    const float* x_user  = (const float*)d_in[0];
    const float* x_tx    = (const float*)d_in[1];
    const float* x_merch = (const float*)d_in[2];
    const int* ei[7];
    int E[7];
    for (int r = 0; r < 7; r++) { ei[r] = (const int*)d_in[3 + r]; E[r] = in_sizes[3 + r] / 2; }
    const float* Win_user  = (const float*)d_in[10];
    const float* bin_user  = (const float*)d_in[11];
    const float* Win_tx    = (const float*)d_in[12];
    const float* bin_tx    = (const float*)d_in[13];
    const float* Win_merch = (const float*)d_in[14];
    const float* bin_merch = (const float*)d_in[15];
    const float* lin_w     = (const float*)d_in[16];
    const float* att_src   = (const float*)d_in[17];
    const float* att_dst   = (const float*)d_in[18];
    const float* conv_bias = (const float*)d_in[19];
    const float* cls_w1    = (const float*)d_in[20];
    const float* cls_b1    = (const float*)d_in[21];
    const float* cls_w2    = (const float*)d_in[22];
    const float* cls_b2    = (const float*)d_in[23];

    const int src_type[7] = {0, 1, 2, 1, 0, 2, 1};
    const int dst_type[7] = {1, 0, 1, 2, 0, 2, 1};
    const int N_of[3] = {NU, NT, NM};

    // segment offsets
    Segs segs;
    int TE = 0, TN = 0;
    for (int r = 0; r < 7; r++) {
        segs.ei[r] = ei[r];
        segs.eoff[r] = TE; TE += E[r];
        segs.noff[r] = TN; TN += N_of[dst_type[r]];
    }
    segs.eoff[7] = TE;
    segs.noff[7] = TN;

    // ---- workspace layout ----
    size_t off = 0;
    auto alloc = [&](size_t bytes) { size_t q = off; off += (bytes + 255) & ~(size_t)255; return q; };
    size_t o_a[3], o_b[3], o_hs[3], o_aS[3];
    for (int tpe = 0; tpe < 3; tpe++) o_a[tpe]  = alloc((size_t)N_of[tpe] * 64 * 2);
    for (int tpe = 0; tpe < 3; tpe++) o_b[tpe]  = alloc((size_t)N_of[tpe] * 64 * 2);
    for (int tpe = 0; tpe < 3; tpe++) o_hs[tpe] = alloc((size_t)N_of[tpe] * 64 * 2);
    for (int tpe = 0; tpe < 3; tpe++) o_aS[tpe] = alloc((size_t)N_of[tpe] * 4 * 4);
    size_t o_aD[3];
    for (int jj = 0; jj < 3; jj++) o_aD[jj] = alloc((size_t)NT * 4 * 4);
    size_t o_rp   = alloc(((size_t)TN + 1) * 4);
    size_t o_col  = alloc((size_t)TE * 4);
    size_t o_cnt  = alloc((size_t)TN * 4);
    size_t o_bsum = alloc((size_t)8192 * 4);
    size_t o_wa   = alloc((size_t)2 * 7 * 64 * 8 * 4);
    size_t o_wad  = alloc((size_t)14 * 256 * 4);
    size_t o_wt   = alloc((size_t)14 * 8192 * 2);
    size_t o_wtin = alloc((size_t)16384 * 2);
    if (off > ws_size) return;  // fail cleanly (absmax will read ~0.31)

    char* base = (char*)d_ws;
    bf16* A[3], *B[3], *hsS[3];
    float* aSS[3];
    for (int tpe = 0; tpe < 3; tpe++) {
        A[tpe] = (bf16*)(base + o_a[tpe]);
        B[tpe] = (bf16*)(base + o_b[tpe]);
        hsS[tpe] = (bf16*)(base + o_hs[tpe]);
        aSS[tpe] = (float*)(base + o_aS[tpe]);
    }
    float* aDS[3];
    for (int jj = 0; jj < 3; jj++) aDS[jj] = (float*)(base + o_aD[jj]);
    int* rp_all   = (int*)(base + o_rp);
    int* col_all  = (int*)(base + o_col);
    int* cnt      = (int*)(base + o_cnt);
    int* bsum     = (int*)(base + o_bsum);
    float* wa     = (float*)(base + o_wa);
    float* wad    = (float*)(base + o_wad);
    bf16* wt      = (bf16*)(base + o_wt);
    bf16* wtin    = (bf16*)(base + o_wtin);

    // ---- fused CSR build over all 7 relations ----
    int nb = (TN + 256) / 256;  // covers TN+1 scan outputs
    k_zero_i<<<(TN + 255) / 256, 256, 0, stream>>>(cnt, TN);
    k_hist_all<<<(TE + 255) / 256, 256, 0, stream>>>(segs, TE, cnt);
    k_scan1<<<nb, 256, 0, stream>>>(cnt, TN, bsum);
    k_scan2<<<1, 256, 0, stream>>>(bsum, nb);
    k_scan3<<<nb, 256, 0, stream>>>(cnt, TN, bsum, rp_all);
    k_zero_i<<<(TN + 255) / 256, 256, 0, stream>>>(cnt, TN);
    k_fill_all<<<(TE + 255) / 256, 256, 0, stream>>>(segs, TE, rp_all, cnt, col_all);

    k_wa<<<(7168 + 255) / 256, 256, 0, stream>>>(lin_w, att_src, att_dst, wa, wad);
    k_wt<<<(14 * 4096 + 255) / 256, 256, 0, stream>>>(lin_w, wt);
    k_wtin<<<32, 256, 0, stream>>>(Win_user, Win_tx, Win_merch, wtin);
    k_projm<32><<<(NU + 63) / 64, 256, 0, stream>>>(x_user, wtin, bin_user, A[0], NU);
    k_projm<64><<<(NT + 63) / 64, 256, 0, stream>>>(x_tx, wtin + 4096, bin_tx, A[1], NT);
    k_projm<16><<<(NM + 63) / 64, 256, 0, stream>>>(x_merch, wtin + 12288, bin_merch, A[2], NM);

    const int grp_dst[3]     = {1, 0, 2};
    const int grp_rels[3][3] = {{0, 2, 6}, {1, 4, -1}, {3, 5, -1}};

    for (int l = 0; l < 2; l++) {
        bf16** cur = (l == 0) ? A : B;
        bf16** nxt = (l == 0) ? B : A;
        const float* cb = conv_bias + (size_t)l * 7 * 64;
        for (int g = 0; g < 3; g++) {
            int dt = grp_dst[g];
            int Nd = N_of[dt];
            const int* grp = grp_rels[g];
            int nrel = (grp[2] >= 0) ? 3 : 2;
            // projections: cross relations first (collect their dst-alpha GEMVs),
            // self relation last (fused cross dst-alphas ride on it)
            const float4* crossWad[2] = {nullptr, nullptr};
            float* crossAD[2] = {nullptr, nullptr};
            int ncross = 0;
            for (int jj = 0; jj < nrel; jj++) {
                int r = grp[jj];
                int st = src_type[r];
                int lr = l * 7 + r;
                const bf16* wtp  = wt + (size_t)lr * 8192;
                const float* avs = att_src + (size_t)lr * 64;
                const float* avd = att_dst + (size_t)lr * 64;
                if (st == dt) {
                    k_pmfma<<<(N_of[st] + 63) / 64, 256, 0, stream>>>(
                        cur[st], wtp, avs, avd, hsS[st], aSS[st], aDS[jj],
                        crossWad[0], crossAD[0], crossWad[1], crossAD[1], N_of[st]);
                } else {
                    k_pmfma<<<(N_of[st] + 63) / 64, 256, 0, stream>>>(
                        cur[st], wtp, avs, nullptr, hsS[st], aSS[st], nullptr,
                        nullptr, nullptr, nullptr, nullptr, N_of[st]);
                    crossWad[ncross] = (const float4*)(wad + (size_t)lr * 256);
                    crossAD[ncross] = aDS[jj];
                    ncross++;
                }
            }
            // fused softmax + aggregation
            FA fa;
            for (int jj = 0; jj < 3; jj++) {
                int r = grp[jj] >= 0 ? grp[jj] : grp[0];
                fa.rp[jj] = rp_all + segs.noff[r];
                fa.aS[jj] = aSS[src_type[r]];
                fa.aD[jj] = aDS[grp[jj] >= 0 ? jj : 0];
                fa.hs[jj] = hsS[src_type[r]];
            }
            int r0 = grp[0], r1 = grp[1], r2 = grp[2];
            if (nrel == 3) {
                k_fagg2<3, 4><<<(Nd + 7) / 8, 256, 0, stream>>>(
                    fa, col_all, cb, r0, r1, r2, nxt[dt], Nd);
            } else {
                k_fagg2<2, 8><<<(Nd + 7) / 8, 256, 0, stream>>>(
                    fa, col_all, cb, r0, r1, -1, nxt[dt], Nd);
            }
        }
    }
    k_cls<<<NT / 8, 256, 0, stream>>>(A[1], cls_w1, cls_b1, cls_w2, cls_b2, (float*)d_out);
}

// Round 12
// 1188.814 us; speedup vs baseline: 1.6957x; 1.1542x over previous
//
#include <hip/hip_runtime.h>
#include <hip/hip_bf16.h>

#define NU 100000
#define NT 300000
#define NM 10000

typedef __hip_bfloat16 bf16;
typedef __attribute__((ext_vector_type(8))) short bf16x8;
typedef __attribute__((ext_vector_type(4))) float f32x4;

__device__ __forceinline__ float toF(float v) { return v; }
__device__ __forceinline__ float toF(bf16 v)  { return __bfloat162float(v); }
__device__ __forceinline__ float bitsLo(unsigned u) { return __uint_as_float(u << 16); }
__device__ __forceinline__ float bitsHi(unsigned u) { return __uint_as_float(u & 0xffff0000u); }
__device__ __forceinline__ float shortBF(short s) { return __uint_as_float(((unsigned)(unsigned short)s) << 16); }
__device__ __forceinline__ short bfBits(float v) { bf16 b = __float2bfloat16(v); return *(short*)&b; }

struct Segs {
    const int* ei[7];
    int eoff[8];
    int noff[8];
};

struct FA {
    const int* rp[3];
    const float* aS[3];
    const float* aD[3];
    const bf16* hs[3];
};

struct P3 {
    const bf16* wt[3];
    const float* avs[3];
    bf16* hs[3];
    float* aS[3];
    const float* avdL;  // self relation (always last slot)
    float* aDL;
    const float4* wadA; float* aDA;
    const float4* wadB; float* aDB;
};

// ================= fused CSR build =================
__global__ void k_zero_i(int* __restrict__ p, int n) {
    int i = blockIdx.x * 256 + threadIdx.x;
    if (i < n) p[i] = 0;
}

__global__ void k_hist_all(Segs s, int TE, int* __restrict__ cnt, int* __restrict__ rank) {
    int g = blockIdx.x * 256 + threadIdx.x;
    if (g >= TE) return;
    int r = 0;
    while (g >= s.eoff[r + 1]) r++;
    int e = g - s.eoff[r];
    int E = s.eoff[r + 1] - s.eoff[r];
    int d = s.ei[r][E + e];
    rank[g] = atomicAdd(&cnt[s.noff[r] + d], 1);
}

__global__ void k_scan1(const int* __restrict__ cnt, int n, int* __restrict__ bsum) {
    __shared__ int sh[256];
    int i = blockIdx.x * 256 + threadIdx.x;
    sh[threadIdx.x] = (i < n) ? cnt[i] : 0;
    __syncthreads();
    for (int o = 128; o; o >>= 1) {
        if (threadIdx.x < o) sh[threadIdx.x] += sh[threadIdx.x + o];
        __syncthreads();
    }
    if (threadIdx.x == 0) bsum[blockIdx.x] = sh[0];
}

__global__ void k_scan2(int* __restrict__ bsum, int nb) {  // 1 block
    __shared__ int sh[256];
    __shared__ int carry;
    if (threadIdx.x == 0) carry = 0;
    __syncthreads();
    for (int base = 0; base < nb; base += 256) {
        int i = base + threadIdx.x;
        int v = (i < nb) ? bsum[i] : 0;
        sh[threadIdx.x] = v;
        __syncthreads();
        for (int o = 1; o < 256; o <<= 1) {
            int t = (threadIdx.x >= o) ? sh[threadIdx.x - o] : 0;
            __syncthreads();
            sh[threadIdx.x] += t;
            __syncthreads();
        }
        if (i < nb) bsum[i] = carry + sh[threadIdx.x] - v;  // exclusive
        __syncthreads();
        if (threadIdx.x == 255) carry += sh[255];
        __syncthreads();
    }
}

__global__ void k_scan3(const int* __restrict__ cnt, int n, const int* __restrict__ bsum,
                        int* __restrict__ out) {
    __shared__ int sh[256];
    int i = blockIdx.x * 256 + threadIdx.x;
    int v = (i < n) ? cnt[i] : 0;
    sh[threadIdx.x] = v;
    __syncthreads();
    for (int o = 1; o < 256; o <<= 1) {
        int t = (threadIdx.x >= o) ? sh[threadIdx.x - o] : 0;
        __syncthreads();
        sh[threadIdx.x] += t;
        __syncthreads();
    }
    if (i <= n) out[i] = bsum[blockIdx.x] + sh[threadIdx.x] - v;
}

__global__ void k_fill_all(Segs s, int TE, const int* __restrict__ rp_all,
                           const int* __restrict__ rank, int* __restrict__ col) {
    int g = blockIdx.x * 256 + threadIdx.x;
    if (g >= TE) return;
    int r = 0;
    while (g >= s.eoff[r + 1]) r++;
    int e = g - s.eoff[r];
    int E = s.eoff[r + 1] - s.eoff[r];
    int d = s.ei[r][E + e];
    col[rp_all[s.noff[r] + d] + rank[g]] = s.ei[r][e];
}

// ================= weight prep =================
__global__ void k_wa(const float* __restrict__ lin_w, const float* __restrict__ att_s,
                     const float* __restrict__ att_d, float* __restrict__ wa,
                     float* __restrict__ wad) {
    int i = blockIdx.x * 256 + threadIdx.x;
    if (i >= 2 * 7 * 64 * 8) return;
    int j = i & 7;
    int k = (i >> 3) & 63;
    int lr = i >> 9;
    int h = j & 3;
    const float* a = (j < 4 ? att_s : att_d) + lr * 64 + h * 16;
    const float* Wp = lin_w + (size_t)lr * 4096 + k * 64 + h * 16;
    float s = 0.f;
#pragma unroll
    for (int c = 0; c < 16; c++) s += Wp[c] * a[c];
    wa[i] = s;
    if (j >= 4) wad[lr * 256 + k * 4 + h] = s;
}

__global__ void k_wt(const float* __restrict__ lin_w, bf16* __restrict__ wt) {
    int i = blockIdx.x * 256 + threadIdx.x;
    if (i >= 14 * 4096) return;
    int lr = i >> 12;
    int kc = i & 4095;
    int k = kc >> 6, c = kc & 63;
    float v = lin_w[(size_t)lr * 4096 + k * 64 + c];
    bf16 hi = __float2bfloat16(v);
    float rem = v - __bfloat162float(hi);
    wt[(size_t)lr * 8192 + c * 64 + k] = hi;
    wt[(size_t)lr * 8192 + 4096 + c * 64 + k] = __float2bfloat16(rem);
}

__global__ void k_wtin(const float* __restrict__ Wu, const float* __restrict__ Wt,
                       const float* __restrict__ Wm, bf16* __restrict__ out) {
    int i = blockIdx.x * 256 + threadIdx.x;
    if (i >= 8192) return;
    const float* W; int K, KP, base, j;
    if (i < 2048)      { W = Wu; K = 32; KP = 32; base = 0;     j = i; }
    else if (i < 6144) { W = Wt; K = 64; KP = 64; base = 4096;  j = i - 2048; }
    else               { W = Wm; K = 16; KP = 32; base = 12288; j = i - 6144; }
    int c = j / KP, k = j - c * KP;
    float v = (k < K) ? W[k * 64 + c] : 0.f;
    bf16 hb = __float2bfloat16(v);
    float rem = v - __bfloat162float(hb);
    out[base + c * KP + k] = hb;
    out[base + 64 * KP + c * KP + k] = __float2bfloat16(rem);
}

// ================= MFMA input projection =================
template <int K>
__global__ void k_projm(const float* __restrict__ x, const bf16* __restrict__ wt,
                        const float* __restrict__ bias, bf16* __restrict__ out, int N) {
    constexpr int KP = (K > 32) ? 64 : 32;
    int w = threadIdx.x >> 6, lane = threadIdx.x & 63;
    int m = lane & 15, kq = lane >> 4;
    int r0 = blockIdx.x * 64 + w * 16;
    int row = r0 + m;
    bf16x8 ah0 = {}, al0 = {}, ah1 = {}, al1 = {};
    if (row < N) {
#pragma unroll
        for (int j = 0; j < 8; j++) {
            int k = kq * 8 + j;
            float v = (k < K) ? x[(size_t)row * K + k] : 0.f;
            short hb = bfBits(v);
            ah0[j] = hb;
            al0[j] = bfBits(v - shortBF(hb));
        }
        if (KP == 64) {
#pragma unroll
            for (int j = 0; j < 8; j++) {
                float v = x[(size_t)row * K + 32 + kq * 8 + j];
                short hb = bfBits(v);
                ah1[j] = hb;
                al1[j] = bfBits(v - shortBF(hb));
            }
        }
    }
#pragma unroll
    for (int nt = 0; nt < 4; nt++) {
        int c = nt * 16 + m;
        f32x4 acc = {};
        const bf16* bh = wt + c * KP + kq * 8;
        const bf16* bl = wt + 64 * KP + c * KP + kq * 8;
        bf16x8 bh0 = *(const bf16x8*)(bh);
        bf16x8 bl0 = *(const bf16x8*)(bl);
        acc = __builtin_amdgcn_mfma_f32_16x16x32_bf16(ah0, bh0, acc, 0, 0, 0);
        acc = __builtin_amdgcn_mfma_f32_16x16x32_bf16(al0, bh0, acc, 0, 0, 0);
        acc = __builtin_amdgcn_mfma_f32_16x16x32_bf16(ah0, bl0, acc, 0, 0, 0);
        if (KP == 64) {
            bf16x8 bh1 = *(const bf16x8*)(bh + 32);
            bf16x8 bl1 = *(const bf16x8*)(bl + 32);
            acc = __builtin_amdgcn_mfma_f32_16x16x32_bf16(ah1, bh1, acc, 0, 0, 0);
            acc = __builtin_amdgcn_mfma_f32_16x16x32_bf16(al1, bh1, acc, 0, 0, 0);
            acc = __builtin_amdgcn_mfma_f32_16x16x32_bf16(ah1, bl1, acc, 0, 0, 0);
        }
        float bv = bias[c];
#pragma unroll
        for (int i = 0; i < 4; i++) {
            int rr = r0 + kq * 4 + i;
            if (rr < N) out[(size_t)rr * 64 + c] = __float2bfloat16(acc[i] + bv);
        }
    }
}

// ===== batched MFMA projections (NREL relations sharing one x), self rel last ======
template <int NREL>
__global__ void k_pmfma3(const bf16* __restrict__ x, P3 p, int N) {
    int w = threadIdx.x >> 6, lane = threadIdx.x & 63;
    int m = lane & 15, kq = lane >> 4;
    int r0 = blockIdx.x * 64 + w * 16;
    bf16x8 a0 = {}, a1 = {};
    int row = r0 + m;
    if (row < N) {
        a0 = *(const bf16x8*)(x + (size_t)row * 64 + kq * 8);
        a1 = *(const bf16x8*)(x + (size_t)row * 64 + 32 + kq * 8);
    }
#pragma unroll
    for (int rl = 0; rl < NREL; rl++) {
        const bf16* wtp = p.wt[rl];
        const float* avs = p.avs[rl];
        bf16* hs = p.hs[rl];
        float* aS = p.aS[rl];
        const bool self = (rl == NREL - 1);
#pragma unroll
        for (int nt = 0; nt < 4; nt++) {
            const bf16* wb  = wtp + (nt * 16 + m) * 64 + kq * 8;
            const bf16* wbl = wb + 4096;
            bf16x8 bh0 = *(const bf16x8*)(wb);
            bf16x8 bh1 = *(const bf16x8*)(wb + 32);
            bf16x8 bl0 = *(const bf16x8*)(wbl);
            bf16x8 bl1 = *(const bf16x8*)(wbl + 32);
            f32x4 acc = {};
            acc = __builtin_amdgcn_mfma_f32_16x16x32_bf16(a0, bh0, acc, 0, 0, 0);
            acc = __builtin_amdgcn_mfma_f32_16x16x32_bf16(a0, bl0, acc, 0, 0, 0);
            acc = __builtin_amdgcn_mfma_f32_16x16x32_bf16(a1, bh1, acc, 0, 0, 0);
            acc = __builtin_amdgcn_mfma_f32_16x16x32_bf16(a1, bl1, acc, 0, 0, 0);
            float avsv = avs[nt * 16 + m];
            float avdv = self ? p.avdL[nt * 16 + m] : 0.f;
#pragma unroll
            for (int i = 0; i < 4; i++) {
                int rr = r0 + kq * 4 + i;
                if (rr < N) hs[(size_t)rr * 64 + nt * 16 + m] = __float2bfloat16(acc[i]);
                float ps = acc[i] * avsv;
                ps += __shfl_xor(ps, 1); ps += __shfl_xor(ps, 2);
                ps += __shfl_xor(ps, 4); ps += __shfl_xor(ps, 8);
                if (m == 0 && rr < N) aS[rr * 4 + nt] = ps;
                if (self) {
                    float pd = acc[i] * avdv;
                    pd += __shfl_xor(pd, 1); pd += __shfl_xor(pd, 2);
                    pd += __shfl_xor(pd, 4); pd += __shfl_xor(pd, 8);
                    if (m == 0 && rr < N) p.aDL[rr * 4 + nt] = pd;
                }
            }
        }
    }
    if (p.wadA) {
        float xv[16];
#pragma unroll
        for (int kk = 0; kk < 8; kk++) { xv[kk] = shortBF(a0[kk]); xv[8 + kk] = shortBF(a1[kk]); }
#pragma unroll
        for (int cr = 0; cr < 2; cr++) {
            const float4* wad = (cr == 0) ? p.wadA : p.wadB;
            float* aDo = (cr == 0) ? p.aDA : p.aDB;
            if (!wad) break;
            float p0 = 0.f, p1 = 0.f, p2 = 0.f, p3 = 0.f;
#pragma unroll
            for (int kk = 0; kk < 8; kk++) {
                float4 w4 = wad[kq * 8 + kk];
                p0 = fmaf(xv[kk], w4.x, p0); p1 = fmaf(xv[kk], w4.y, p1);
                p2 = fmaf(xv[kk], w4.z, p2); p3 = fmaf(xv[kk], w4.w, p3);
                float4 w4b = wad[32 + kq * 8 + kk];
                p0 = fmaf(xv[8 + kk], w4b.x, p0); p1 = fmaf(xv[8 + kk], w4b.y, p1);
                p2 = fmaf(xv[8 + kk], w4b.z, p2); p3 = fmaf(xv[8 + kk], w4b.w, p3);
            }
            p0 += __shfl_xor(p0, 16); p0 += __shfl_xor(p0, 32);
            p1 += __shfl_xor(p1, 16); p1 += __shfl_xor(p1, 32);
            p2 += __shfl_xor(p2, 16); p2 += __shfl_xor(p2, 32);
            p3 += __shfl_xor(p3, 16); p3 += __shfl_xor(p3, 32);
            if (kq == 0 && row < N) {
                float4 o; o.x = p0; o.y = p1; o.z = p2; o.w = p3;
                *(float4*)(aDo + (size_t)row * 4) = o;
            }
        }
    }
}

// ============ single-relation projection (fallback path) ============
__global__ void k_pmfma(const bf16* __restrict__ x, const bf16* __restrict__ wt,
                        const float* __restrict__ avs_p, const float* __restrict__ avd_p,
                        bf16* __restrict__ hs, float* __restrict__ aS, float* __restrict__ aD,
                        const float4* __restrict__ wadA, float* __restrict__ aDA,
                        const float4* __restrict__ wadB, float* __restrict__ aDB,
                        int N) {
    int w = threadIdx.x >> 6, lane = threadIdx.x & 63;
    int m = lane & 15, kq = lane >> 4;
    int r0 = blockIdx.x * 64 + w * 16;
    bf16x8 a0 = {}, a1 = {};
    int row = r0 + m;
    if (row < N) {
        a0 = *(const bf16x8*)(x + (size_t)row * 64 + kq * 8);
        a1 = *(const bf16x8*)(x + (size_t)row * 64 + 32 + kq * 8);
    }
#pragma unroll
    for (int nt = 0; nt < 4; nt++) {
        const bf16* wb  = wt + (nt * 16 + m) * 64 + kq * 8;
        const bf16* wbl = wb + 4096;
        bf16x8 bh0 = *(const bf16x8*)(wb);
        bf16x8 bh1 = *(const bf16x8*)(wb + 32);
        bf16x8 bl0 = *(const bf16x8*)(wbl);
        bf16x8 bl1 = *(const bf16x8*)(wbl + 32);
        f32x4 acc = {};
        acc = __builtin_amdgcn_mfma_f32_16x16x32_bf16(a0, bh0, acc, 0, 0, 0);
        acc = __builtin_amdgcn_mfma_f32_16x16x32_bf16(a0, bl0, acc, 0, 0, 0);
        acc = __builtin_amdgcn_mfma_f32_16x16x32_bf16(a1, bh1, acc, 0, 0, 0);
        acc = __builtin_amdgcn_mfma_f32_16x16x32_bf16(a1, bl1, acc, 0, 0, 0);
        float avsv = avs_p ? avs_p[nt * 16 + m] : 0.f;
        float avdv = avd_p ? avd_p[nt * 16 + m] : 0.f;
#pragma unroll
        for (int i = 0; i < 4; i++) {
            int rr = r0 + kq * 4 + i;
            if (rr < N) hs[(size_t)rr * 64 + nt * 16 + m] = __float2bfloat16(acc[i]);
            if (avs_p) {
                float ps = acc[i] * avsv;
                ps += __shfl_xor(ps, 1); ps += __shfl_xor(ps, 2);
                ps += __shfl_xor(ps, 4); ps += __shfl_xor(ps, 8);
                if (m == 0 && rr < N) aS[rr * 4 + nt] = ps;
            }
            if (avd_p) {
                float pd = acc[i] * avdv;
                pd += __shfl_xor(pd, 1); pd += __shfl_xor(pd, 2);
                pd += __shfl_xor(pd, 4); pd += __shfl_xor(pd, 8);
                if (m == 0 && rr < N) aD[rr * 4 + nt] = pd;
            }
        }
    }
    if (wadA) {
        float xv[16];
#pragma unroll
        for (int kk = 0; kk < 8; kk++) { xv[kk] = shortBF(a0[kk]); xv[8 + kk] = shortBF(a1[kk]); }
#pragma unroll
        for (int cr = 0; cr < 2; cr++) {
            const float4* wad = (cr == 0) ? wadA : wadB;
            float* aDo = (cr == 0) ? aDA : aDB;
            if (!wad) break;
            float p0 = 0.f, p1 = 0.f, p2 = 0.f, p3 = 0.f;
#pragma unroll
            for (int kk = 0; kk < 8; kk++) {
                float4 w4 = wad[kq * 8 + kk];
                p0 = fmaf(xv[kk], w4.x, p0); p1 = fmaf(xv[kk], w4.y, p1);
                p2 = fmaf(xv[kk], w4.z, p2); p3 = fmaf(xv[kk], w4.w, p3);
                float4 w4b = wad[32 + kq * 8 + kk];
                p0 = fmaf(xv[8 + kk], w4b.x, p0); p1 = fmaf(xv[8 + kk], w4b.y, p1);
                p2 = fmaf(xv[8 + kk], w4b.z, p2); p3 = fmaf(xv[8 + kk], w4b.w, p3);
            }
            p0 += __shfl_xor(p0, 16); p0 += __shfl_xor(p0, 32);
            p1 += __shfl_xor(p1, 16); p1 += __shfl_xor(p1, 32);
            p2 += __shfl_xor(p2, 16); p2 += __shfl_xor(p2, 32);
            p3 += __shfl_xor(p3, 16); p3 += __shfl_xor(p3, 32);
            if (kq == 0 && row < N) {
                float4 o; o.x = p0; o.y = p1; o.z = p2; o.w = p3;
                *(float4*)(aDo + (size_t)row * 4) = o;
            }
        }
    }
}

// ===== fused softmax+aggregation =====
template <int NREL, int EPR>
__global__ void k_fagg2(FA fa, const int* __restrict__ col, const float* __restrict__ cb,
                        int b0i, int b1i, int b2i, bf16* __restrict__ out, int Nd) {
    int tid = threadIdx.x;
    int wv = tid >> 6, lane = tid & 63;
    int half = lane >> 5, l32 = lane & 31;
    int node = blockIdx.x * 8 + wv * 2 + half;
    bool alive = node < Nd;
    int nc = alive ? node : (Nd - 1);
    int hcl = l32 >> 3;
    int beg[NREL], deg[NREL];
    float ad[NREL], dn[NREL], ax[NREL], ay[NREL];
#pragma unroll
    for (int r = 0; r < NREL; r++) {
        beg[r] = fa.rp[r][nc];
        deg[r] = fa.rp[r][nc + 1] - beg[r];
    }
#pragma unroll
    for (int r = 0; r < NREL; r++) {
        ad[r] = fa.aD[r][nc * 4 + hcl];
        dn[r] = 0.f; ax[r] = 0.f; ay[r] = 0.f;
    }
    {
        int cv[NREL][EPR];
#pragma unroll
        for (int r = 0; r < NREL; r++)
#pragma unroll
            for (int j = 0; j < EPR; j++) cv[r][j] = (j < deg[r]) ? col[beg[r] + j] : 0;
        float as[NREL][EPR];
#pragma unroll
        for (int r = 0; r < NREL; r++)
#pragma unroll
            for (int j = 0; j < EPR; j++) as[r][j] = (j < deg[r]) ? fa.aS[r][cv[r][j] * 4 + hcl] : 0.f;
        unsigned hv[NREL][EPR];
#pragma unroll
        for (int r = 0; r < NREL; r++)
#pragma unroll
            for (int j = 0; j < EPR; j++)
                hv[r][j] = (j < deg[r]) ? *(const unsigned*)(fa.hs[r] + (size_t)cv[r][j] * 64 + 2 * l32) : 0u;
#pragma unroll
        for (int r = 0; r < NREL; r++)
#pragma unroll
            for (int j = 0; j < EPR; j++) if (j < deg[r]) {
                float a = as[r][j] + ad[r];
                a = (a >= 0.f) ? a : 0.2f * a;
                float ex = __expf(a);
                dn[r] += ex;
                ax[r] = fmaf(ex, bitsLo(hv[r][j]), ax[r]);
                ay[r] = fmaf(ex, bitsHi(hv[r][j]), ay[r]);
            }
    }
#pragma unroll
    for (int r = 0; r < NREL; r++) {
        int e = beg[r] + deg[r];
        for (int i0 = beg[r] + EPR; i0 < e; i0 += EPR) {
            int mrem = e - i0;
            int cw[EPR];
#pragma unroll
            for (int j = 0; j < EPR; j++) cw[j] = (j < mrem) ? col[i0 + j] : 0;
            float aw[EPR];
#pragma unroll
            for (int j = 0; j < EPR; j++) aw[j] = (j < mrem) ? fa.aS[r][cw[j] * 4 + hcl] : 0.f;
            unsigned hw[EPR];
#pragma unroll
            for (int j = 0; j < EPR; j++)
                hw[j] = (j < mrem) ? *(const unsigned*)(fa.hs[r] + (size_t)cw[j] * 64 + 2 * l32) : 0u;
#pragma unroll
            for (int j = 0; j < EPR; j++) if (j < mrem) {
                float a = aw[j] + ad[r];
                a = (a >= 0.f) ? a : 0.2f * a;
                float ex = __expf(a);
                dn[r] += ex;
                ax[r] = fmaf(ex, bitsLo(hw[j]), ax[r]);
                ay[r] = fmaf(ex, bitsHi(hw[j]), ay[r]);
            }
        }
    }
    float2 bb = *(const float2*)(cb + b0i * 64 + 2 * l32);
    float ox = bb.x, oy = bb.y;
    if (b1i >= 0) { float2 t = *(const float2*)(cb + b1i * 64 + 2 * l32); ox += t.x; oy += t.y; }
    if (b2i >= 0) { float2 t = *(const float2*)(cb + b2i * 64 + 2 * l32); ox += t.x; oy += t.y; }
#pragma unroll
    for (int r = 0; r < NREL; r++) {
        float rd = 1.f / (dn[r] + 1e-16f);
        ox = fmaf(ax[r], rd, ox);
        oy = fmaf(ay[r], rd, oy);
    }
    ox = ox > 0.f ? ox : 0.f;
    oy = oy > 0.f ? oy : 0.f;
    if (alive) {
        bf16 p0 = __float2bfloat16(ox), p1 = __float2bfloat16(oy);
        unsigned pk = ((unsigned)(*(unsigned short*)&p1) << 16) | (unsigned)(*(unsigned short*)&p0);
        ((unsigned*)out)[(size_t)node * 32 + l32] = pk;
    }
}

// ================= classifier =================
__global__ void k_cls(const bf16* __restrict__ t, const float* __restrict__ w1,
                      const float* __restrict__ b1, const float* __restrict__ w2,
                      const float* __restrict__ b2, float* __restrict__ out) {
    __shared__ float w1s[64 * 32];
    __shared__ float w2s[64];
    __shared__ float b1s[32];
    __shared__ float b2s[2];
    __shared__ float ts[8 * 64];
    int tid = threadIdx.x;
    for (int i = tid; i < 2048; i += 256) w1s[i] = w1[i];
    if (tid < 64) w2s[tid] = w2[tid];
    if (tid < 32) b1s[tid] = b1[tid];
    if (tid < 2) b2s[tid] = b2[tid];
    int n0 = blockIdx.x << 3;
    for (int i = tid; i < 512; i += 256) {
        int row = i >> 6, col = i & 63;
        ts[i] = toF(t[(size_t)(n0 + row) * 64 + col]);
    }
    __syncthreads();
    int lane = tid & 31;
    int row = tid >> 5;
    float h = b1s[lane];
#pragma unroll 8
    for (int k = 0; k < 64; k++) h = fmaf(ts[(row << 6) + k], w1s[(k << 5) + lane], h);
    h = h > 0.f ? h : 0.f;
    float o0 = h * w2s[lane * 2 + 0];
    float o1 = h * w2s[lane * 2 + 1];
#pragma unroll
    for (int off = 16; off; off >>= 1) {
        o0 += __shfl_down(o0, off, 32);
        o1 += __shfl_down(o1, off, 32);
    }
    if (lane == 0) {
        int n = n0 + row;
        out[(size_t)n * 2 + 0] = o0 + b2s[0];
        out[(size_t)n * 2 + 1] = o1 + b2s[1];
    }
}

extern "C" void kernel_launch(void* const* d_in, const int* in_sizes, int n_in,
                              void* d_out, int out_size, void* d_ws, size_t ws_size,
                              hipStream_t stream) {
    (void)n_in; (void)out_size;
    const float* x_user  = (const float*)d_in[0];
    const float* x_tx    = (const float*)d_in[1];
    const float* x_merch = (const float*)d_in[2];
    const int* ei[7];
    int E[7];
    for (int r = 0; r < 7; r++) { ei[r] = (const int*)d_in[3 + r]; E[r] = in_sizes[3 + r] / 2; }
    const float* Win_user  = (const float*)d_in[10];
    const float* bin_user  = (const float*)d_in[11];
    const float* Win_tx    = (const float*)d_in[12];
    const float* bin_tx    = (const float*)d_in[13];
    const float* Win_merch = (const float*)d_in[14];
    const float* bin_merch = (const float*)d_in[15];
    const float* lin_w     = (const float*)d_in[16];
    const float* att_src   = (const float*)d_in[17];
    const float* att_dst   = (const float*)d_in[18];
    const float* conv_bias = (const float*)d_in[19];
    const float* cls_w1    = (const float*)d_in[20];
    const float* cls_b1    = (const float*)d_in[21];
    const float* cls_w2    = (const float*)d_in[22];
    const float* cls_b2    = (const float*)d_in[23];

    const int src_type[7] = {0, 1, 2, 1, 0, 2, 1};
    const int dst_type[7] = {1, 0, 1, 2, 0, 2, 1};
    const int N_of[3] = {NU, NT, NM};

    Segs segs;
    int TE = 0, TN = 0;
    for (int r = 0; r < 7; r++) {
        segs.ei[r] = ei[r];
        segs.eoff[r] = TE; TE += E[r];
        segs.noff[r] = TN; TN += N_of[dst_type[r]];
    }
    segs.eoff[7] = TE;
    segs.noff[7] = TN;

    // ---- adaptive workspace layout ----
    bf16* A[3]; bf16* B[3] = {nullptr, nullptr, nullptr}; bf16* hsArr[7];
    float* aS7[7]; float* aD7[7];
    int *rp_all, *col_all, *cnt, *rank, *bsum;
    float *wa, *wad; bf16 *wt, *wtin;
    char* base = (char*)d_ws;
    size_t off;
    auto alloc = [&](size_t bytes) { size_t q = off; off += (bytes + 255) & ~(size_t)255; return q; };

    auto layout = [&](bool wantBig) -> bool {
        off = 0;
        for (int t = 0; t < 3; t++) A[t] = (bf16*)(base + alloc((size_t)N_of[t] * 128));
        if (!wantBig) for (int t = 0; t < 3; t++) B[t] = (bf16*)(base + alloc((size_t)N_of[t] * 128));
        size_t hs_first = (size_t)-1;
        if (wantBig) {
            for (int r = 0; r < 7; r++) {
                size_t o = alloc((size_t)N_of[src_type[r]] * 128);
                if (hs_first == (size_t)-1) hs_first = o;
                hsArr[r] = (bf16*)(base + o);
            }
        } else {
            bf16* hsT[3];
            for (int t = 0; t < 3; t++) {
                size_t o = alloc((size_t)N_of[t] * 128);
                if (hs_first == (size_t)-1) hs_first = o;
                hsT[t] = (bf16*)(base + o);
            }
            for (int r = 0; r < 7; r++) hsArr[r] = hsT[src_type[r]];
        }
        for (int r = 0; r < 7; r++) aS7[r] = (float*)(base + alloc((size_t)N_of[src_type[r]] * 16));
        for (int r = 0; r < 7; r++) aD7[r] = (float*)(base + alloc((size_t)N_of[dst_type[r]] * 16));
        rp_all  = (int*)(base + alloc(((size_t)TN + 1) * 4));
        col_all = (int*)(base + alloc((size_t)TE * 4));
        bsum    = (int*)(base + alloc((size_t)8192 * 4));
        wa      = (float*)(base + alloc((size_t)2 * 7 * 64 * 8 * 4));
        wad     = (float*)(base + alloc((size_t)14 * 256 * 4));
        wt      = (bf16*)(base + alloc((size_t)14 * 8192 * 2));
        wtin    = (bf16*)(base + alloc((size_t)16384 * 2));
        cnt  = (int*)(base + hs_first);  // aliases hs region (dead before hs writes)
        rank = (int*)(base + hs_first + (((size_t)TN * 4 + 255) & ~(size_t)255));
        return off <= ws_size;
    };
    bool big = layout(true);
    if (!big && !layout(false)) return;  // scratch too small: fail cleanly

    // ---- fused CSR build ----
    int nb = (TN + 256) / 256;
    k_zero_i<<<(TN + 255) / 256, 256, 0, stream>>>(cnt, TN);
    k_hist_all<<<(TE + 255) / 256, 256, 0, stream>>>(segs, TE, cnt, rank);
    k_scan1<<<nb, 256, 0, stream>>>(cnt, TN, bsum);
    k_scan2<<<1, 256, 0, stream>>>(bsum, nb);
    k_scan3<<<nb, 256, 0, stream>>>(cnt, TN, bsum, rp_all);
    k_fill_all<<<(TE + 255) / 256, 256, 0, stream>>>(segs, TE, rp_all, rank, col_all);

    k_wa<<<(7168 + 255) / 256, 256, 0, stream>>>(lin_w, att_src, att_dst, wa, wad);
    k_wt<<<(14 * 4096 + 255) / 256, 256, 0, stream>>>(lin_w, wt);
    k_wtin<<<32, 256, 0, stream>>>(Win_user, Win_tx, Win_merch, wtin);
    k_projm<32><<<(NU + 63) / 64, 256, 0, stream>>>(x_user, wtin, bin_user, A[0], NU);
    k_projm<64><<<(NT + 63) / 64, 256, 0, stream>>>(x_tx, wtin + 4096, bin_tx, A[1], NT);
    k_projm<16><<<(NM + 63) / 64, 256, 0, stream>>>(x_merch, wtin + 12288, bin_merch, A[2], NM);

    const int grp_dst[3]     = {1, 0, 2};
    const int grp_rels[3][3] = {{0, 2, 6}, {1, 4, -1}, {3, 5, -1}};
    const int bat_src[3]     = {1, 0, 2};
    const int bat_rels[3][3] = {{1, 3, 6}, {0, 4, -1}, {2, 5, -1}};
    const int bat_wad[3][2]  = {{0, 2}, {1, -1}, {3, -1}};

    for (int l = 0; l < 2; l++) {
        bf16** cur = big ? A : ((l == 0) ? A : B);
        bf16** nxt = big ? A : ((l == 0) ? B : A);
        const float* cb = conv_bias + (size_t)l * 7 * 64;

        if (big) {
            // all projections first (batched by src type), then all aggregations
            for (int b = 0; b < 3; b++) {
                int st = bat_src[b];
                int nrel = (bat_rels[b][2] >= 0) ? 3 : 2;
                P3 p;
                for (int jj = 0; jj < 3; jj++) {
                    int r = bat_rels[b][jj] >= 0 ? bat_rels[b][jj] : bat_rels[b][0];
                    int lr = l * 7 + r;
                    p.wt[jj]  = wt + (size_t)lr * 8192;
                    p.avs[jj] = att_src + (size_t)lr * 64;
                    p.hs[jj]  = hsArr[r];
                    p.aS[jj]  = aS7[r];
                }
                int selfR = bat_rels[b][nrel - 1];
                p.avdL = att_dst + (size_t)(l * 7 + selfR) * 64;
                p.aDL  = aD7[selfR];
                int wr0 = bat_wad[b][0], wr1 = bat_wad[b][1];
                p.wadA = (const float4*)(wad + (size_t)(l * 7 + wr0) * 256);
                p.aDA  = aD7[wr0];
                p.wadB = (wr1 >= 0) ? (const float4*)(wad + (size_t)(l * 7 + wr1) * 256) : nullptr;
                p.aDB  = (wr1 >= 0) ? aD7[wr1] : nullptr;
                if (nrel == 3)
                    k_pmfma3<3><<<(N_of[st] + 63) / 64, 256, 0, stream>>>(cur[st], p, N_of[st]);
                else
                    k_pmfma3<2><<<(N_of[st] + 63) / 64, 256, 0, stream>>>(cur[st], p, N_of[st]);
            }
            for (int g = 0; g < 3; g++) {
                int dt = grp_dst[g];
                int Nd = N_of[dt];
                const int* grp = grp_rels[g];
                int nrel = (grp[2] >= 0) ? 3 : 2;
                FA fa;
                for (int jj = 0; jj < 3; jj++) {
                    int r = grp[jj] >= 0 ? grp[jj] : grp[0];
                    fa.rp[jj] = rp_all + segs.noff[r];
                    fa.aS[jj] = aS7[r];
                    fa.aD[jj] = aD7[r];
                    fa.hs[jj] = hsArr[r];
                }
                int r0 = grp[0], r1 = grp[1], r2 = grp[2];
                if (nrel == 3)
                    k_fagg2<3, 4><<<(Nd + 7) / 8, 256, 0, stream>>>(fa, col_all, cb, r0, r1, r2, nxt[dt], Nd);
                else
                    k_fagg2<2, 8><<<(Nd + 7) / 8, 256, 0, stream>>>(fa, col_all, cb, r0, r1, -1, nxt[dt], Nd);
            }
        } else {
            for (int g = 0; g < 3; g++) {
                int dt = grp_dst[g];
                int Nd = N_of[dt];
                const int* grp = grp_rels[g];
                int nrel = (grp[2] >= 0) ? 3 : 2;
                const float4* crossWad[2] = {nullptr, nullptr};
                float* crossAD[2] = {nullptr, nullptr};
                int ncross = 0;
                for (int jj = 0; jj < nrel; jj++) {
                    int r = grp[jj];
                    int st = src_type[r];
                    int lr = l * 7 + r;
                    const bf16* wtp  = wt + (size_t)lr * 8192;
                    const float* avs = att_src + (size_t)lr * 64;
                    const float* avd = att_dst + (size_t)lr * 64;
                    if (st == dt) {
                        k_pmfma<<<(N_of[st] + 63) / 64, 256, 0, stream>>>(
                            cur[st], wtp, avs, avd, hsArr[r], aS7[r], aD7[r],
                            crossWad[0], crossAD[0], crossWad[1], crossAD[1], N_of[st]);
                    } else {
                        k_pmfma<<<(N_of[st] + 63) / 64, 256, 0, stream>>>(
                            cur[st], wtp, avs, nullptr, hsArr[r], aS7[r], nullptr,
                            nullptr, nullptr, nullptr, nullptr, N_of[st]);
                        crossWad[ncross] = (const float4*)(wad + (size_t)lr * 256);
                        crossAD[ncross] = aD7[r];
                        ncross++;
                    }
                }
                FA fa;
                for (int jj = 0; jj < 3; jj++) {
                    int r = grp[jj] >= 0 ? grp[jj] : grp[0];
                    fa.rp[jj] = rp_all + segs.noff[r];
                    fa.aS[jj] = aS7[r];
                    fa.aD[jj] = aD7[r];
                    fa.hs[jj] = hsArr[r];
                }
                int r0 = grp[0], r1 = grp[1], r2 = grp[2];
                if (nrel == 3)
                    k_fagg2<3, 4><<<(Nd + 7) / 8, 256, 0, stream>>>(fa, col_all, cb, r0, r1, r2, nxt[dt], Nd);
                else
                    k_fagg2<2, 8><<<(Nd + 7) / 8, 256, 0, stream>>>(fa, col_all, cb, r0, r1, -1, nxt[dt], Nd);
            }
        }
    }
    k_cls<<<NT / 8, 256, 0, stream>>>(A[1], cls_w1, cls_b1, cls_w2, cls_b2, (float*)d_out);
}

// Round 13
// 1172.375 us; speedup vs baseline: 1.7195x; 1.0140x over previous
//
#include <hip/hip_runtime.h>
#include <hip/hip_bf16.h>

#define NU 100000
#define NT 300000
#define NM 10000

typedef __hip_bfloat16 bf16;
typedef __attribute__((ext_vector_type(8))) short bf16x8;
typedef __attribute__((ext_vector_type(4))) float f32x4;

__device__ __forceinline__ float toF(float v) { return v; }
__device__ __forceinline__ float toF(bf16 v)  { return __bfloat162float(v); }
__device__ __forceinline__ float bitsLo(unsigned u) { return __uint_as_float(u << 16); }
__device__ __forceinline__ float bitsHi(unsigned u) { return __uint_as_float(u & 0xffff0000u); }
__device__ __forceinline__ float shortBF(short s) { return __uint_as_float(((unsigned)(unsigned short)s) << 16); }
__device__ __forceinline__ short bfBits(float v) { bf16 b = __float2bfloat16(v); return *(short*)&b; }

struct Segs {
    const int* ei[7];
    int eoff[8];
    int noff[8];
};

struct FA {
    const int* rp[3];
    const float* aS[3];
    const float* aD[3];
    const bf16* hs[3];
};

struct P3 {
    const bf16* wt[3];
    const float* avs[3];
    bf16* hs[3];
    float* aS[3];
    const float* avdL;  // self relation (always last slot)
    float* aDL;
    const float4* wadA; float* aDA;
    const float4* wadB; float* aDB;
};

// ================= fused CSR build =================
__global__ void k_zero_i(int* __restrict__ p, int n) {
    int i = blockIdx.x * 256 + threadIdx.x;
    if (i < n) p[i] = 0;
}

__global__ void k_hist_all(Segs s, int TE, int* __restrict__ cnt, int* __restrict__ rank) {
    int g = blockIdx.x * 256 + threadIdx.x;
    if (g >= TE) return;
    int r = 0;
    while (g >= s.eoff[r + 1]) r++;
    int e = g - s.eoff[r];
    int E = s.eoff[r + 1] - s.eoff[r];
    int d = s.ei[r][E + e];
    rank[g] = atomicAdd(&cnt[s.noff[r] + d], 1);
}

__global__ void k_scan1(const int* __restrict__ cnt, int n, int* __restrict__ bsum) {
    __shared__ int sh[256];
    int i = blockIdx.x * 256 + threadIdx.x;
    sh[threadIdx.x] = (i < n) ? cnt[i] : 0;
    __syncthreads();
    for (int o = 128; o; o >>= 1) {
        if (threadIdx.x < o) sh[threadIdx.x] += sh[threadIdx.x + o];
        __syncthreads();
    }
    if (threadIdx.x == 0) bsum[blockIdx.x] = sh[0];
}

__global__ void k_scan2(int* __restrict__ bsum, int nb) {  // 1 block
    __shared__ int sh[256];
    __shared__ int carry;
    if (threadIdx.x == 0) carry = 0;
    __syncthreads();
    for (int base = 0; base < nb; base += 256) {
        int i = base + threadIdx.x;
        int v = (i < nb) ? bsum[i] : 0;
        sh[threadIdx.x] = v;
        __syncthreads();
        for (int o = 1; o < 256; o <<= 1) {
            int t = (threadIdx.x >= o) ? sh[threadIdx.x - o] : 0;
            __syncthreads();
            sh[threadIdx.x] += t;
            __syncthreads();
        }
        if (i < nb) bsum[i] = carry + sh[threadIdx.x] - v;  // exclusive
        __syncthreads();
        if (threadIdx.x == 255) carry += sh[255];
        __syncthreads();
    }
}

__global__ void k_scan3(const int* __restrict__ cnt, int n, const int* __restrict__ bsum,
                        int* __restrict__ out) {
    __shared__ int sh[256];
    int i = blockIdx.x * 256 + threadIdx.x;
    int v = (i < n) ? cnt[i] : 0;
    sh[threadIdx.x] = v;
    __syncthreads();
    for (int o = 1; o < 256; o <<= 1) {
        int t = (threadIdx.x >= o) ? sh[threadIdx.x - o] : 0;
        __syncthreads();
        sh[threadIdx.x] += t;
        __syncthreads();
    }
    if (i <= n) out[i] = bsum[blockIdx.x] + sh[threadIdx.x] - v;
}

__global__ void k_fill_all(Segs s, int TE, const int* __restrict__ rp_all,
                           const int* __restrict__ rank, int* __restrict__ col) {
    int g = blockIdx.x * 256 + threadIdx.x;
    if (g >= TE) return;
    int r = 0;
    while (g >= s.eoff[r + 1]) r++;
    int e = g - s.eoff[r];
    int E = s.eoff[r + 1] - s.eoff[r];
    int d = s.ei[r][E + e];
    col[rp_all[s.noff[r] + d] + rank[g]] = s.ei[r][e];
}

// ================= weight prep =================
__global__ void k_wa(const float* __restrict__ lin_w, const float* __restrict__ att_s,
                     const float* __restrict__ att_d, float* __restrict__ wa,
                     float* __restrict__ wad) {
    int i = blockIdx.x * 256 + threadIdx.x;
    if (i >= 2 * 7 * 64 * 8) return;
    int j = i & 7;
    int k = (i >> 3) & 63;
    int lr = i >> 9;
    int h = j & 3;
    const float* a = (j < 4 ? att_s : att_d) + lr * 64 + h * 16;
    const float* Wp = lin_w + (size_t)lr * 4096 + k * 64 + h * 16;
    float s = 0.f;
#pragma unroll
    for (int c = 0; c < 16; c++) s += Wp[c] * a[c];
    wa[i] = s;
    if (j >= 4) wad[lr * 256 + k * 4 + h] = s;
}

__global__ void k_wt(const float* __restrict__ lin_w, bf16* __restrict__ wt) {
    int i = blockIdx.x * 256 + threadIdx.x;
    if (i >= 14 * 4096) return;
    int lr = i >> 12;
    int kc = i & 4095;
    int k = kc >> 6, c = kc & 63;
    float v = lin_w[(size_t)lr * 4096 + k * 64 + c];
    bf16 hi = __float2bfloat16(v);
    float rem = v - __bfloat162float(hi);
    wt[(size_t)lr * 8192 + c * 64 + k] = hi;
    wt[(size_t)lr * 8192 + 4096 + c * 64 + k] = __float2bfloat16(rem);
}

__global__ void k_wtin(const float* __restrict__ Wu, const float* __restrict__ Wt,
                       const float* __restrict__ Wm, bf16* __restrict__ out) {
    int i = blockIdx.x * 256 + threadIdx.x;
    if (i >= 8192) return;
    const float* W; int K, KP, base, j;
    if (i < 2048)      { W = Wu; K = 32; KP = 32; base = 0;     j = i; }
    else if (i < 6144) { W = Wt; K = 64; KP = 64; base = 4096;  j = i - 2048; }
    else               { W = Wm; K = 16; KP = 32; base = 12288; j = i - 6144; }
    int c = j / KP, k = j - c * KP;
    float v = (k < K) ? W[k * 64 + c] : 0.f;
    bf16 hb = __float2bfloat16(v);
    float rem = v - __bfloat162float(hb);
    out[base + c * KP + k] = hb;
    out[base + 64 * KP + c * KP + k] = __float2bfloat16(rem);
}

// ================= MFMA input projection =================
template <int K>
__global__ void k_projm(const float* __restrict__ x, const bf16* __restrict__ wt,
                        const float* __restrict__ bias, bf16* __restrict__ out, int N) {
    constexpr int KP = (K > 32) ? 64 : 32;
    int w = threadIdx.x >> 6, lane = threadIdx.x & 63;
    int m = lane & 15, kq = lane >> 4;
    int r0 = blockIdx.x * 64 + w * 16;
    int row = r0 + m;
    bf16x8 ah0 = {}, al0 = {}, ah1 = {}, al1 = {};
    if (row < N) {
#pragma unroll
        for (int j = 0; j < 8; j++) {
            int k = kq * 8 + j;
            float v = (k < K) ? x[(size_t)row * K + k] : 0.f;
            short hb = bfBits(v);
            ah0[j] = hb;
            al0[j] = bfBits(v - shortBF(hb));
        }
        if (KP == 64) {
#pragma unroll
            for (int j = 0; j < 8; j++) {
                float v = x[(size_t)row * K + 32 + kq * 8 + j];
                short hb = bfBits(v);
                ah1[j] = hb;
                al1[j] = bfBits(v - shortBF(hb));
            }
        }
    }
#pragma unroll
    for (int nt = 0; nt < 4; nt++) {
        int c = nt * 16 + m;
        f32x4 acc = {};
        const bf16* bh = wt + c * KP + kq * 8;
        const bf16* bl = wt + 64 * KP + c * KP + kq * 8;
        bf16x8 bh0 = *(const bf16x8*)(bh);
        bf16x8 bl0 = *(const bf16x8*)(bl);
        acc = __builtin_amdgcn_mfma_f32_16x16x32_bf16(ah0, bh0, acc, 0, 0, 0);
        acc = __builtin_amdgcn_mfma_f32_16x16x32_bf16(al0, bh0, acc, 0, 0, 0);
        acc = __builtin_amdgcn_mfma_f32_16x16x32_bf16(ah0, bl0, acc, 0, 0, 0);
        if (KP == 64) {
            bf16x8 bh1 = *(const bf16x8*)(bh + 32);
            bf16x8 bl1 = *(const bf16x8*)(bl + 32);
            acc = __builtin_amdgcn_mfma_f32_16x16x32_bf16(ah1, bh1, acc, 0, 0, 0);
            acc = __builtin_amdgcn_mfma_f32_16x16x32_bf16(al1, bh1, acc, 0, 0, 0);
            acc = __builtin_amdgcn_mfma_f32_16x16x32_bf16(ah1, bl1, acc, 0, 0, 0);
        }
        float bv = bias[c];
#pragma unroll
        for (int i = 0; i < 4; i++) {
            int rr = r0 + kq * 4 + i;
            if (rr < N) out[(size_t)rr * 64 + c] = __float2bfloat16(acc[i] + bv);
        }
    }
}

// ===== batched MFMA projections (NREL relations sharing one x), self rel last ======
// alpha stores deferred to per-row float4 writes (full-line, no write amplification)
template <int NREL>
__global__ void k_pmfma3(const bf16* __restrict__ x, P3 p, int N) {
    int w = threadIdx.x >> 6, lane = threadIdx.x & 63;
    int m = lane & 15, kq = lane >> 4;
    int r0 = blockIdx.x * 64 + w * 16;
    bf16x8 a0 = {}, a1 = {};
    int row = r0 + m;
    if (row < N) {
        a0 = *(const bf16x8*)(x + (size_t)row * 64 + kq * 8);
        a1 = *(const bf16x8*)(x + (size_t)row * 64 + 32 + kq * 8);
    }
#pragma unroll
    for (int rl = 0; rl < NREL; rl++) {
        const bf16* wtp = p.wt[rl];
        const float* avs = p.avs[rl];
        bf16* hs = p.hs[rl];
        float* aS = p.aS[rl];
        const bool self = (rl == NREL - 1);
        float psA[4][4];
        float pdA[4][4];
#pragma unroll
        for (int nt = 0; nt < 4; nt++) {
            const bf16* wb  = wtp + (nt * 16 + m) * 64 + kq * 8;
            const bf16* wbl = wb + 4096;
            bf16x8 bh0 = *(const bf16x8*)(wb);
            bf16x8 bh1 = *(const bf16x8*)(wb + 32);
            bf16x8 bl0 = *(const bf16x8*)(wbl);
            bf16x8 bl1 = *(const bf16x8*)(wbl + 32);
            f32x4 acc = {};
            acc = __builtin_amdgcn_mfma_f32_16x16x32_bf16(a0, bh0, acc, 0, 0, 0);
            acc = __builtin_amdgcn_mfma_f32_16x16x32_bf16(a0, bl0, acc, 0, 0, 0);
            acc = __builtin_amdgcn_mfma_f32_16x16x32_bf16(a1, bh1, acc, 0, 0, 0);
            acc = __builtin_amdgcn_mfma_f32_16x16x32_bf16(a1, bl1, acc, 0, 0, 0);
            float avsv = avs[nt * 16 + m];
            float avdv = self ? p.avdL[nt * 16 + m] : 0.f;
#pragma unroll
            for (int i = 0; i < 4; i++) {
                int rr = r0 + kq * 4 + i;
                if (rr < N) hs[(size_t)rr * 64 + nt * 16 + m] = __float2bfloat16(acc[i]);
                float ps = acc[i] * avsv;
                ps += __shfl_xor(ps, 1); ps += __shfl_xor(ps, 2);
                ps += __shfl_xor(ps, 4); ps += __shfl_xor(ps, 8);
                psA[i][nt] = ps;
                if (self) {
                    float pd = acc[i] * avdv;
                    pd += __shfl_xor(pd, 1); pd += __shfl_xor(pd, 2);
                    pd += __shfl_xor(pd, 4); pd += __shfl_xor(pd, 8);
                    pdA[i][nt] = pd;
                }
            }
        }
        if (m == 0) {
#pragma unroll
            for (int i = 0; i < 4; i++) {
                int rr = r0 + kq * 4 + i;
                if (rr < N) {
                    float4 o; o.x = psA[i][0]; o.y = psA[i][1]; o.z = psA[i][2]; o.w = psA[i][3];
                    *(float4*)(aS + (size_t)rr * 4) = o;
                    if (self) {
                        float4 od; od.x = pdA[i][0]; od.y = pdA[i][1]; od.z = pdA[i][2]; od.w = pdA[i][3];
                        *(float4*)(p.aDL + (size_t)rr * 4) = od;
                    }
                }
            }
        }
    }
    if (p.wadA) {
        float xv[16];
#pragma unroll
        for (int kk = 0; kk < 8; kk++) { xv[kk] = shortBF(a0[kk]); xv[8 + kk] = shortBF(a1[kk]); }
#pragma unroll
        for (int cr = 0; cr < 2; cr++) {
            const float4* wad = (cr == 0) ? p.wadA : p.wadB;
            float* aDo = (cr == 0) ? p.aDA : p.aDB;
            if (!wad) break;
            float p0 = 0.f, p1 = 0.f, p2 = 0.f, p3 = 0.f;
#pragma unroll
            for (int kk = 0; kk < 8; kk++) {
                float4 w4 = wad[kq * 8 + kk];
                p0 = fmaf(xv[kk], w4.x, p0); p1 = fmaf(xv[kk], w4.y, p1);
                p2 = fmaf(xv[kk], w4.z, p2); p3 = fmaf(xv[kk], w4.w, p3);
                float4 w4b = wad[32 + kq * 8 + kk];
                p0 = fmaf(xv[8 + kk], w4b.x, p0); p1 = fmaf(xv[8 + kk], w4b.y, p1);
                p2 = fmaf(xv[8 + kk], w4b.z, p2); p3 = fmaf(xv[8 + kk], w4b.w, p3);
            }
            p0 += __shfl_xor(p0, 16); p0 += __shfl_xor(p0, 32);
            p1 += __shfl_xor(p1, 16); p1 += __shfl_xor(p1, 32);
            p2 += __shfl_xor(p2, 16); p2 += __shfl_xor(p2, 32);
            p3 += __shfl_xor(p3, 16); p3 += __shfl_xor(p3, 32);
            if (kq == 0 && row < N) {
                float4 o; o.x = p0; o.y = p1; o.z = p2; o.w = p3;
                *(float4*)(aDo + (size_t)row * 4) = o;
            }
        }
    }
}

// ============ single-relation projection (fallback path) ============
__global__ void k_pmfma(const bf16* __restrict__ x, const bf16* __restrict__ wt,
                        const float* __restrict__ avs_p, const float* __restrict__ avd_p,
                        bf16* __restrict__ hs, float* __restrict__ aS, float* __restrict__ aD,
                        const float4* __restrict__ wadA, float* __restrict__ aDA,
                        const float4* __restrict__ wadB, float* __restrict__ aDB,
                        int N) {
    int w = threadIdx.x >> 6, lane = threadIdx.x & 63;
    int m = lane & 15, kq = lane >> 4;
    int r0 = blockIdx.x * 64 + w * 16;
    bf16x8 a0 = {}, a1 = {};
    int row = r0 + m;
    if (row < N) {
        a0 = *(const bf16x8*)(x + (size_t)row * 64 + kq * 8);
        a1 = *(const bf16x8*)(x + (size_t)row * 64 + 32 + kq * 8);
    }
    float psA[4][4];
    float pdA[4][4];
#pragma unroll
    for (int nt = 0; nt < 4; nt++) {
        const bf16* wb  = wt + (nt * 16 + m) * 64 + kq * 8;
        const bf16* wbl = wb + 4096;
        bf16x8 bh0 = *(const bf16x8*)(wb);
        bf16x8 bh1 = *(const bf16x8*)(wb + 32);
        bf16x8 bl0 = *(const bf16x8*)(wbl);
        bf16x8 bl1 = *(const bf16x8*)(wbl + 32);
        f32x4 acc = {};
        acc = __builtin_amdgcn_mfma_f32_16x16x32_bf16(a0, bh0, acc, 0, 0, 0);
        acc = __builtin_amdgcn_mfma_f32_16x16x32_bf16(a0, bl0, acc, 0, 0, 0);
        acc = __builtin_amdgcn_mfma_f32_16x16x32_bf16(a1, bh1, acc, 0, 0, 0);
        acc = __builtin_amdgcn_mfma_f32_16x16x32_bf16(a1, bl1, acc, 0, 0, 0);
        float avsv = avs_p ? avs_p[nt * 16 + m] : 0.f;
        float avdv = avd_p ? avd_p[nt * 16 + m] : 0.f;
#pragma unroll
        for (int i = 0; i < 4; i++) {
            int rr = r0 + kq * 4 + i;
            if (rr < N) hs[(size_t)rr * 64 + nt * 16 + m] = __float2bfloat16(acc[i]);
            float ps = acc[i] * avsv;
            ps += __shfl_xor(ps, 1); ps += __shfl_xor(ps, 2);
            ps += __shfl_xor(ps, 4); ps += __shfl_xor(ps, 8);
            psA[i][nt] = ps;
            float pd = acc[i] * avdv;
            pd += __shfl_xor(pd, 1); pd += __shfl_xor(pd, 2);
            pd += __shfl_xor(pd, 4); pd += __shfl_xor(pd, 8);
            pdA[i][nt] = pd;
        }
    }
    if (m == 0) {
#pragma unroll
        for (int i = 0; i < 4; i++) {
            int rr = r0 + kq * 4 + i;
            if (rr < N) {
                if (avs_p) {
                    float4 o; o.x = psA[i][0]; o.y = psA[i][1]; o.z = psA[i][2]; o.w = psA[i][3];
                    *(float4*)(aS + (size_t)rr * 4) = o;
                }
                if (avd_p) {
                    float4 od; od.x = pdA[i][0]; od.y = pdA[i][1]; od.z = pdA[i][2]; od.w = pdA[i][3];
                    *(float4*)(aD + (size_t)rr * 4) = od;
                }
            }
        }
    }
    if (wadA) {
        float xv[16];
#pragma unroll
        for (int kk = 0; kk < 8; kk++) { xv[kk] = shortBF(a0[kk]); xv[8 + kk] = shortBF(a1[kk]); }
#pragma unroll
        for (int cr = 0; cr < 2; cr++) {
            const float4* wad = (cr == 0) ? wadA : wadB;
            float* aDo = (cr == 0) ? aDA : aDB;
            if (!wad) break;
            float p0 = 0.f, p1 = 0.f, p2 = 0.f, p3 = 0.f;
#pragma unroll
            for (int kk = 0; kk < 8; kk++) {
                float4 w4 = wad[kq * 8 + kk];
                p0 = fmaf(xv[kk], w4.x, p0); p1 = fmaf(xv[kk], w4.y, p1);
                p2 = fmaf(xv[kk], w4.z, p2); p3 = fmaf(xv[kk], w4.w, p3);
                float4 w4b = wad[32 + kq * 8 + kk];
                p0 = fmaf(xv[8 + kk], w4b.x, p0); p1 = fmaf(xv[8 + kk], w4b.y, p1);
                p2 = fmaf(xv[8 + kk], w4b.z, p2); p3 = fmaf(xv[8 + kk], w4b.w, p3);
            }
            p0 += __shfl_xor(p0, 16); p0 += __shfl_xor(p0, 32);
            p1 += __shfl_xor(p1, 16); p1 += __shfl_xor(p1, 32);
            p2 += __shfl_xor(p2, 16); p2 += __shfl_xor(p2, 32);
            p3 += __shfl_xor(p3, 16); p3 += __shfl_xor(p3, 32);
            if (kq == 0 && row < N) {
                float4 o; o.x = p0; o.y = p1; o.z = p2; o.w = p3;
                *(float4*)(aDo + (size_t)row * 4) = o;
            }
        }
    }
}

// ===== fused softmax+aggregation =====
template <int NREL, int EPR>
__global__ void k_fagg2(FA fa, const int* __restrict__ col, const float* __restrict__ cb,
                        int b0i, int b1i, int b2i, bf16* __restrict__ out, int Nd) {
    int tid = threadIdx.x;
    int wv = tid >> 6, lane = tid & 63;
    int half = lane >> 5, l32 = lane & 31;
    int node = blockIdx.x * 8 + wv * 2 + half;
    bool alive = node < Nd;
    int nc = alive ? node : (Nd - 1);
    int hcl = l32 >> 3;
    int beg[NREL], deg[NREL];
    float ad[NREL], dn[NREL], ax[NREL], ay[NREL];
#pragma unroll
    for (int r = 0; r < NREL; r++) {
        beg[r] = fa.rp[r][nc];
        deg[r] = fa.rp[r][nc + 1] - beg[r];
    }
#pragma unroll
    for (int r = 0; r < NREL; r++) {
        ad[r] = fa.aD[r][nc * 4 + hcl];
        dn[r] = 0.f; ax[r] = 0.f; ay[r] = 0.f;
    }
    {
        int cv[NREL][EPR];
#pragma unroll
        for (int r = 0; r < NREL; r++)
#pragma unroll
            for (int j = 0; j < EPR; j++) cv[r][j] = (j < deg[r]) ? col[beg[r] + j] : 0;
        float as[NREL][EPR];
#pragma unroll
        for (int r = 0; r < NREL; r++)
#pragma unroll
            for (int j = 0; j < EPR; j++) as[r][j] = (j < deg[r]) ? fa.aS[r][cv[r][j] * 4 + hcl] : 0.f;
        unsigned hv[NREL][EPR];
#pragma unroll
        for (int r = 0; r < NREL; r++)
#pragma unroll
            for (int j = 0; j < EPR; j++)
                hv[r][j] = (j < deg[r]) ? *(const unsigned*)(fa.hs[r] + (size_t)cv[r][j] * 64 + 2 * l32) : 0u;
#pragma unroll
        for (int r = 0; r < NREL; r++)
#pragma unroll
            for (int j = 0; j < EPR; j++) if (j < deg[r]) {
                float a = as[r][j] + ad[r];
                a = (a >= 0.f) ? a : 0.2f * a;
                float ex = __expf(a);
                dn[r] += ex;
                ax[r] = fmaf(ex, bitsLo(hv[r][j]), ax[r]);
                ay[r] = fmaf(ex, bitsHi(hv[r][j]), ay[r]);
            }
    }
#pragma unroll
    for (int r = 0; r < NREL; r++) {
        int e = beg[r] + deg[r];
        for (int i0 = beg[r] + EPR; i0 < e; i0 += EPR) {
            int mrem = e - i0;
            int cw[EPR];
#pragma unroll
            for (int j = 0; j < EPR; j++) cw[j] = (j < mrem) ? col[i0 + j] : 0;
            float aw[EPR];
#pragma unroll
            for (int j = 0; j < EPR; j++) aw[j] = (j < mrem) ? fa.aS[r][cw[j] * 4 + hcl] : 0.f;
            unsigned hw[EPR];
#pragma unroll
            for (int j = 0; j < EPR; j++)
                hw[j] = (j < mrem) ? *(const unsigned*)(fa.hs[r] + (size_t)cw[j] * 64 + 2 * l32) : 0u;
#pragma unroll
            for (int j = 0; j < EPR; j++) if (j < mrem) {
                float a = aw[j] + ad[r];
                a = (a >= 0.f) ? a : 0.2f * a;
                float ex = __expf(a);
                dn[r] += ex;
                ax[r] = fmaf(ex, bitsLo(hw[j]), ax[r]);
                ay[r] = fmaf(ex, bitsHi(hw[j]), ay[r]);
            }
        }
    }
    float2 bb = *(const float2*)(cb + b0i * 64 + 2 * l32);
    float ox = bb.x, oy = bb.y;
    if (b1i >= 0) { float2 t = *(const float2*)(cb + b1i * 64 + 2 * l32); ox += t.x; oy += t.y; }
    if (b2i >= 0) { float2 t = *(const float2*)(cb + b2i * 64 + 2 * l32); ox += t.x; oy += t.y; }
#pragma unroll
    for (int r = 0; r < NREL; r++) {
        float rd = 1.f / (dn[r] + 1e-16f);
        ox = fmaf(ax[r], rd, ox);
        oy = fmaf(ay[r], rd, oy);
    }
    ox = ox > 0.f ? ox : 0.f;
    oy = oy > 0.f ? oy : 0.f;
    if (alive) {
        bf16 p0 = __float2bfloat16(ox), p1 = __float2bfloat16(oy);
        unsigned pk = ((unsigned)(*(unsigned short*)&p1) << 16) | (unsigned)(*(unsigned short*)&p0);
        ((unsigned*)out)[(size_t)node * 32 + l32] = pk;
    }
}

// ================= classifier =================
__global__ void k_cls(const bf16* __restrict__ t, const float* __restrict__ w1,
                      const float* __restrict__ b1, const float* __restrict__ w2,
                      const float* __restrict__ b2, float* __restrict__ out) {
    __shared__ float w1s[64 * 32];
    __shared__ float w2s[64];
    __shared__ float b1s[32];
    __shared__ float b2s[2];
    __shared__ float ts[8 * 64];
    int tid = threadIdx.x;
    for (int i = tid; i < 2048; i += 256) w1s[i] = w1[i];
    if (tid < 64) w2s[tid] = w2[tid];
    if (tid < 32) b1s[tid] = b1[tid];
    if (tid < 2) b2s[tid] = b2[tid];
    int n0 = blockIdx.x << 3;
    for (int i = tid; i < 512; i += 256) {
        int row = i >> 6, col = i & 63;
        ts[i] = toF(t[(size_t)(n0 + row) * 64 + col]);
    }
    __syncthreads();
    int lane = tid & 31;
    int row = tid >> 5;
    float h = b1s[lane];
#pragma unroll 8
    for (int k = 0; k < 64; k++) h = fmaf(ts[(row << 6) + k], w1s[(k << 5) + lane], h);
    h = h > 0.f ? h : 0.f;
    float o0 = h * w2s[lane * 2 + 0];
    float o1 = h * w2s[lane * 2 + 1];
#pragma unroll
    for (int off = 16; off; off >>= 1) {
        o0 += __shfl_down(o0, off, 32);
        o1 += __shfl_down(o1, off, 32);
    }
    if (lane == 0) {
        int n = n0 + row;
        out[(size_t)n * 2 + 0] = o0 + b2s[0];
        out[(size_t)n * 2 + 1] = o1 + b2s[1];
    }
}

extern "C" void kernel_launch(void* const* d_in, const int* in_sizes, int n_in,
                              void* d_out, int out_size, void* d_ws, size_t ws_size,
                              hipStream_t stream) {
    (void)n_in; (void)out_size;
    const float* x_user  = (const float*)d_in[0];
    const float* x_tx    = (const float*)d_in[1];
    const float* x_merch = (const float*)d_in[2];
    const int* ei[7];
    int E[7];
    for (int r = 0; r < 7; r++) { ei[r] = (const int*)d_in[3 + r]; E[r] = in_sizes[3 + r] / 2; }
    const float* Win_user  = (const float*)d_in[10];
    const float* bin_user  = (const float*)d_in[11];
    const float* Win_tx    = (const float*)d_in[12];
    const float* bin_tx    = (const float*)d_in[13];
    const float* Win_merch = (const float*)d_in[14];
    const float* bin_merch = (const float*)d_in[15];
    const float* lin_w     = (const float*)d_in[16];
    const float* att_src   = (const float*)d_in[17];
    const float* att_dst   = (const float*)d_in[18];
    const float* conv_bias = (const float*)d_in[19];
    const float* cls_w1    = (const float*)d_in[20];
    const float* cls_b1    = (const float*)d_in[21];
    const float* cls_w2    = (const float*)d_in[22];
    const float* cls_b2    = (const float*)d_in[23];

    const int src_type[7] = {0, 1, 2, 1, 0, 2, 1};
    const int dst_type[7] = {1, 0, 1, 2, 0, 2, 1};
    const int N_of[3] = {NU, NT, NM};

    Segs segs;
    int TE = 0, TN = 0;
    for (int r = 0; r < 7; r++) {
        segs.ei[r] = ei[r];
        segs.eoff[r] = TE; TE += E[r];
        segs.noff[r] = TN; TN += N_of[dst_type[r]];
    }
    segs.eoff[7] = TE;
    segs.noff[7] = TN;

    // ---- adaptive workspace layout ----
    bf16* A[3]; bf16* B[3] = {nullptr, nullptr, nullptr}; bf16* hsArr[7];
    float* aS7[7]; float* aD7[7];
    int *rp_all, *col_all, *cnt, *rank, *bsum;
    float *wa, *wad; bf16 *wt, *wtin;
    char* base = (char*)d_ws;
    size_t off;
    auto alloc = [&](size_t bytes) { size_t q = off; off += (bytes + 255) & ~(size_t)255; return q; };

    auto layout = [&](bool wantBig) -> bool {
        off = 0;
        for (int t = 0; t < 3; t++) A[t] = (bf16*)(base + alloc((size_t)N_of[t] * 128));
        if (!wantBig) for (int t = 0; t < 3; t++) B[t] = (bf16*)(base + alloc((size_t)N_of[t] * 128));
        size_t hs_first = (size_t)-1;
        if (wantBig) {
            for (int r = 0; r < 7; r++) {
                size_t o = alloc((size_t)N_of[src_type[r]] * 128);
                if (hs_first == (size_t)-1) hs_first = o;
                hsArr[r] = (bf16*)(base + o);
            }
        } else {
            bf16* hsT[3];
            for (int t = 0; t < 3; t++) {
                size_t o = alloc((size_t)N_of[t] * 128);
                if (hs_first == (size_t)-1) hs_first = o;
                hsT[t] = (bf16*)(base + o);
            }
            for (int r = 0; r < 7; r++) hsArr[r] = hsT[src_type[r]];
        }
        for (int r = 0; r < 7; r++) aS7[r] = (float*)(base + alloc((size_t)N_of[src_type[r]] * 16));
        for (int r = 0; r < 7; r++) aD7[r] = (float*)(base + alloc((size_t)N_of[dst_type[r]] * 16));
        rp_all  = (int*)(base + alloc(((size_t)TN + 1) * 4));
        col_all = (int*)(base + alloc((size_t)TE * 4));
        bsum    = (int*)(base + alloc((size_t)8192 * 4));
        wa      = (float*)(base + alloc((size_t)2 * 7 * 64 * 8 * 4));
        wad     = (float*)(base + alloc((size_t)14 * 256 * 4));
        wt      = (bf16*)(base + alloc((size_t)14 * 8192 * 2));
        wtin    = (bf16*)(base + alloc((size_t)16384 * 2));
        cnt  = (int*)(base + hs_first);  // aliases hs region (dead before hs writes)
        rank = (int*)(base + hs_first + (((size_t)TN * 4 + 255) & ~(size_t)255));
        return off <= ws_size;
    };
    bool big = layout(true);
    if (!big && !layout(false)) return;  // scratch too small: fail cleanly

    // ---- fused CSR build ----
    int nb = (TN + 256) / 256;
    k_zero_i<<<(TN + 255) / 256, 256, 0, stream>>>(cnt, TN);
    k_hist_all<<<(TE + 255) / 256, 256, 0, stream>>>(segs, TE, cnt, rank);
    k_scan1<<<nb, 256, 0, stream>>>(cnt, TN, bsum);
    k_scan2<<<1, 256, 0, stream>>>(bsum, nb);
    k_scan3<<<nb, 256, 0, stream>>>(cnt, TN, bsum, rp_all);
    k_fill_all<<<(TE + 255) / 256, 256, 0, stream>>>(segs, TE, rp_all, rank, col_all);

    k_wa<<<(7168 + 255) / 256, 256, 0, stream>>>(lin_w, att_src, att_dst, wa, wad);
    k_wt<<<(14 * 4096 + 255) / 256, 256, 0, stream>>>(lin_w, wt);
    k_wtin<<<32, 256, 0, stream>>>(Win_user, Win_tx, Win_merch, wtin);
    k_projm<32><<<(NU + 63) / 64, 256, 0, stream>>>(x_user, wtin, bin_user, A[0], NU);
    k_projm<64><<<(NT + 63) / 64, 256, 0, stream>>>(x_tx, wtin + 4096, bin_tx, A[1], NT);
    k_projm<16><<<(NM + 63) / 64, 256, 0, stream>>>(x_merch, wtin + 12288, bin_merch, A[2], NM);

    const int grp_dst[3]     = {1, 0, 2};
    const int grp_rels[3][3] = {{0, 2, 6}, {1, 4, -1}, {3, 5, -1}};
    const int bat_src[3]     = {1, 0, 2};
    const int bat_rels[3][3] = {{1, 3, 6}, {0, 4, -1}, {2, 5, -1}};
    const int bat_wad[3][2]  = {{0, 2}, {1, -1}, {3, -1}};

    for (int l = 0; l < 2; l++) {
        bf16** cur = big ? A : ((l == 0) ? A : B);
        bf16** nxt = big ? A : ((l == 0) ? B : A);
        const float* cb = conv_bias + (size_t)l * 7 * 64;

        if (big) {
            for (int b = 0; b < 3; b++) {
                int st = bat_src[b];
                int nrel = (bat_rels[b][2] >= 0) ? 3 : 2;
                P3 p;
                for (int jj = 0; jj < 3; jj++) {
                    int r = bat_rels[b][jj] >= 0 ? bat_rels[b][jj] : bat_rels[b][0];
                    int lr = l * 7 + r;
                    p.wt[jj]  = wt + (size_t)lr * 8192;
                    p.avs[jj] = att_src + (size_t)lr * 64;
                    p.hs[jj]  = hsArr[r];
                    p.aS[jj]  = aS7[r];
                }
                int selfR = bat_rels[b][nrel - 1];
                p.avdL = att_dst + (size_t)(l * 7 + selfR) * 64;
                p.aDL  = aD7[selfR];
                int wr0 = bat_wad[b][0], wr1 = bat_wad[b][1];
                p.wadA = (const float4*)(wad + (size_t)(l * 7 + wr0) * 256);
                p.aDA  = aD7[wr0];
                p.wadB = (wr1 >= 0) ? (const float4*)(wad + (size_t)(l * 7 + wr1) * 256) : nullptr;
                p.aDB  = (wr1 >= 0) ? aD7[wr1] : nullptr;
                if (nrel == 3)
                    k_pmfma3<3><<<(N_of[st] + 63) / 64, 256, 0, stream>>>(cur[st], p, N_of[st]);
                else
                    k_pmfma3<2><<<(N_of[st] + 63) / 64, 256, 0, stream>>>(cur[st], p, N_of[st]);
            }
            for (int g = 0; g < 3; g++) {
                int dt = grp_dst[g];
                int Nd = N_of[dt];
                const int* grp = grp_rels[g];
                int nrel = (grp[2] >= 0) ? 3 : 2;
                FA fa;
                for (int jj = 0; jj < 3; jj++) {
                    int r = grp[jj] >= 0 ? grp[jj] : grp[0];
                    fa.rp[jj] = rp_all + segs.noff[r];
                    fa.aS[jj] = aS7[r];
                    fa.aD[jj] = aD7[r];
                    fa.hs[jj] = hsArr[r];
                }
                int r0 = grp[0], r1 = grp[1], r2 = grp[2];
                if (nrel == 3)
                    k_fagg2<3, 4><<<(Nd + 7) / 8, 256, 0, stream>>>(fa, col_all, cb, r0, r1, r2, nxt[dt], Nd);
                else
                    k_fagg2<2, 8><<<(Nd + 7) / 8, 256, 0, stream>>>(fa, col_all, cb, r0, r1, -1, nxt[dt], Nd);
            }
        } else {
            for (int g = 0; g < 3; g++) {
                int dt = grp_dst[g];
                int Nd = N_of[dt];
                const int* grp = grp_rels[g];
                int nrel = (grp[2] >= 0) ? 3 : 2;
                const float4* crossWad[2] = {nullptr, nullptr};
                float* crossAD[2] = {nullptr, nullptr};
                int ncross = 0;
                for (int jj = 0; jj < nrel; jj++) {
                    int r = grp[jj];
                    int st = src_type[r];
                    int lr = l * 7 + r;
                    const bf16* wtp  = wt + (size_t)lr * 8192;
                    const float* avs = att_src + (size_t)lr * 64;
                    const float* avd = att_dst + (size_t)lr * 64;
                    if (st == dt) {
                        k_pmfma<<<(N_of[st] + 63) / 64, 256, 0, stream>>>(
                            cur[st], wtp, avs, avd, hsArr[r], aS7[r], aD7[r],
                            crossWad[0], crossAD[0], crossWad[1], crossAD[1], N_of[st]);
                    } else {
                        k_pmfma<<<(N_of[st] + 63) / 64, 256, 0, stream>>>(
                            cur[st], wtp, avs, nullptr, hsArr[r], aS7[r], nullptr,
                            nullptr, nullptr, nullptr, nullptr, N_of[st]);
                        crossWad[ncross] = (const float4*)(wad + (size_t)lr * 256);
                        crossAD[ncross] = aD7[r];
                        ncross++;
                    }
                }
                FA fa;
                for (int jj = 0; jj < 3; jj++) {
                    int r = grp[jj] >= 0 ? grp[jj] : grp[0];
                    fa.rp[jj] = rp_all + segs.noff[r];
                    fa.aS[jj] = aS7[r];
                    fa.aD[jj] = aD7[r];
                    fa.hs[jj] = hsArr[r];
                }
                int r0 = grp[0], r1 = grp[1], r2 = grp[2];
                if (nrel == 3)
                    k_fagg2<3, 4><<<(Nd + 7) / 8, 256, 0, stream>>>(fa, col_all, cb, r0, r1, r2, nxt[dt], Nd);
                else
                    k_fagg2<2, 8><<<(Nd + 7) / 8, 256, 0, stream>>>(fa, col_all, cb, r0, r1, -1, nxt[dt], Nd);
            }
        }
    }
    k_cls<<<NT / 8, 256, 0, stream>>>(A[1], cls_w1, cls_b1, cls_w2, cls_b2, (float*)d_out);
}